// Round 14
// baseline (816.381 us; speedup 1.0000x reference)
//
#include <hip/hip_runtime.h>
#include <math.h>

#define D    512
#define BQ   32
#define NH   8
#define MT   64
#define NT   1024  // threads per cand block (16 waves)

typedef _Float16 h2  __attribute__((ext_vector_type(2)));
typedef _Float16 h4v __attribute__((ext_vector_type(4)));
typedef _Float16 h8  __attribute__((ext_vector_type(8)));
typedef float    f4  __attribute__((ext_vector_type(4)));

__device__ __forceinline__ f4 MF(h8 a, h8 b, f4 c) {
  return __builtin_amdgcn_mfma_f32_16x16x32_f16(a, b, c, 0, 0, 0);
}

__device__ __forceinline__ float erf_fast(float x) {
    float ax = fabsf(x);
    float tt = 1.0f / fmaf(0.3275911f, ax, 1.0f);
    float poly = tt * fmaf(tt, fmaf(tt, fmaf(tt, fmaf(tt, 1.061405429f, -1.453152027f),
                          1.421413741f), -0.284496736f), 0.254829592f);
    float r = 1.0f - poly * __expf(-ax * ax);
    return copysignf(r, x);
}
__device__ __forceinline__ float gelu_fast(float x) {
    return 0.5f * x * (1.0f + erf_fast(x * 0.7071067811865475f));
}
__device__ __forceinline__ float gelu_exact(float x) {
    return 0.5f * x * (1.0f + erff(x * 0.7071067811865475f));
}

// --------------------------------------------------------------------------
// Kernel 1: query path. One block per query row (32 blocks, 256 threads).
// --------------------------------------------------------------------------
__global__ __launch_bounds__(256) void qproj_kernel(
    const float* __restrict__ xq,
    const float* __restrict__ W1, const float* __restrict__ b1,
    const float* __restrict__ lng, const float* __restrict__ lnb,
    const float* __restrict__ W2, const float* __restrict__ b2,
    const float* __restrict__ Wio, const float* __restrict__ bio,
    float* __restrict__ qp, float* __restrict__ qv,
    float* __restrict__ q2o, float* __restrict__ qinvo,
    _Float16* __restrict__ qph, _Float16* __restrict__ qpl)
{
    __shared__ float xs[D];
    __shared__ float hs[D];
    __shared__ float red[16];
    const int t = threadIdx.x;
    const int row = blockIdx.x;

    for (int i = t; i < D; i += 256) xs[i] = xq[row * D + i];
    __syncthreads();

    float a0 = 0.f, a1 = 0.f;
    for (int i = 0; i < D; i += 4) {
        float4 xv = *(const float4*)&xs[i];
        float4 w0 = *(const float4*)&W1[(size_t)t * D + i];
        float4 w1 = *(const float4*)&W1[(size_t)(t + 256) * D + i];
        a0 += xv.x*w0.x + xv.y*w0.y + xv.z*w0.z + xv.w*w0.w;
        a1 += xv.x*w1.x + xv.y*w1.y + xv.z*w1.z + xv.w*w1.w;
    }
    float h0 = a0 + b1[t], h1 = a1 + b1[t + 256];

    float s1 = h0 + h1, s2 = h0*h0 + h1*h1;
    for (int off = 32; off > 0; off >>= 1) { s1 += __shfl_down(s1, off); s2 += __shfl_down(s2, off); }
    if ((t & 63) == 0) { red[t >> 6] = s1; red[(t >> 6) + 4] = s2; }
    __syncthreads();
    if (t == 0) {
        float sa = red[0] + red[1] + red[2] + red[3];
        float sb = red[4] + red[5] + red[6] + red[7];
        float mu = sa / (float)D;
        red[8] = mu;
        red[9] = sb / (float)D - mu * mu;
    }
    __syncthreads();
    float mu = red[8];
    float isd = 1.0f / sqrtf(red[9] + 1e-5f);
    hs[t]       = gelu_exact((h0 - mu) * isd * lng[t]       + lnb[t]);
    hs[t + 256] = gelu_exact((h1 - mu) * isd * lng[t + 256] + lnb[t + 256]);
    __syncthreads();

    a0 = 0.f; a1 = 0.f;
    for (int i = 0; i < D; i += 4) {
        float4 gv = *(const float4*)&hs[i];
        float4 w0 = *(const float4*)&W2[(size_t)t * D + i];
        float4 w1 = *(const float4*)&W2[(size_t)(t + 256) * D + i];
        a0 += gv.x*w0.x + gv.y*w0.y + gv.z*w0.z + gv.w*w0.w;
        a1 += gv.x*w1.x + gv.y*w1.y + gv.z*w1.z + gv.w*w1.w;
    }
    float p0 = a0 + b2[t], p1 = a1 + b2[t + 256];
    qp[row * D + t] = p0;
    qp[row * D + t + 256] = p1;
    {
        float sc0 = p0 * 32.0f, sc1 = p1 * 32.0f;
        _Float16 hh0 = (_Float16)sc0, hh1 = (_Float16)sc1;
        qph[row * D + t]       = hh0;
        qpl[row * D + t]       = (_Float16)(sc0 - (float)hh0);
        qph[row * D + t + 256] = hh1;
        qpl[row * D + t + 256] = (_Float16)(sc1 - (float)hh1);
    }
    __syncthreads();
    xs[t] = p0; xs[t + 256] = p1;

    s1 = p0*p0 + p1*p1;
    for (int off = 32; off > 0; off >>= 1) s1 += __shfl_down(s1, off);
    if ((t & 63) == 0) red[t >> 6] = s1;
    __syncthreads();
    if (t == 0) {
        float sa = red[0] + red[1] + red[2] + red[3];
        q2o[row] = sa;
        qinvo[row] = 1.0f / sqrtf(sa);
    }
    __syncthreads();

    a0 = 0.f; a1 = 0.f;
    for (int i = 0; i < D; i += 4) {
        float4 pv = *(const float4*)&xs[i];
        float4 w0 = *(const float4*)&Wio[(size_t)t * D + i];
        float4 w1 = *(const float4*)&Wio[(size_t)(t + 256) * D + i];
        a0 += pv.x*w0.x + pv.y*w0.y + pv.z*w0.z + pv.w*w0.w;
        a1 += pv.x*w1.x + pv.y*w1.y + pv.z*w1.z + pv.w*w1.w;
    }
    qv[row * D + t]       = a0 + bio[t];
    qv[row * D + t + 256] = a1 + bio[t + 256];
}

// --------------------------------------------------------------------------
// Weight prep: fp16 hi/lo split of 32*W for W1, W2.
// --------------------------------------------------------------------------
__global__ __launch_bounds__(256) void wprep_kernel(
    const float* __restrict__ W1, const float* __restrict__ W2,
    _Float16* __restrict__ W1h, _Float16* __restrict__ W1l,
    _Float16* __restrict__ W2h, _Float16* __restrict__ W2l)
{
    int idx = blockIdx.x * 256 + threadIdx.x;
    if (idx >= D * D) return;
    float a = W1[idx] * 32.0f;
    _Float16 hi = (_Float16)a;
    W1h[idx] = hi; W1l[idx] = (_Float16)(a - (float)hi);
    float b = W2[idx] * 32.0f;
    hi = (_Float16)b;
    W2h[idx] = hi; W2l[idx] = (_Float16)(b - (float)hi);
}

// --------------------------------------------------------------------------
// W-tilde prep: Wt[b,h,:] = (1/8) * sum_d qv[b, h*64+d] * Wk[h*64+d, :]
// --------------------------------------------------------------------------
__global__ __launch_bounds__(256) void wtld_kernel(
    const float* __restrict__ qv, const float* __restrict__ Wio,
    _Float16* __restrict__ Wt)
{
    __shared__ float qs[64];
    const int bh = blockIdx.x, b = bh >> 3, h = bh & 7;
    const int t = threadIdx.x;
    if (t < 64) qs[t] = qv[b * D + h * 64 + t] * 0.125f;
    __syncthreads();
    const float* Wk = Wio + (size_t)D * D + (size_t)(h * 64) * D;
    float a0 = 0.f, a1 = 0.f;
    #pragma unroll 4
    for (int d = 0; d < 64; ++d) {
        float q = qs[d];
        a0 += q * Wk[(size_t)d * D + t];
        a1 += q * Wk[(size_t)d * D + t + 256];
    }
    Wt[(size_t)bh * D + t]       = (_Float16)a0;
    Wt[(size_t)bh * D + t + 256] = (_Float16)a1;
}

// --------------------------------------------------------------------------
// Tiny helpers.
// --------------------------------------------------------------------------
__global__ __launch_bounds__(256) void zero256_kernel(float* __restrict__ p)
{
    p[threadIdx.x] = 0.0f;
}
__global__ __launch_bounds__(256) void inv256_kernel(
    float* __restrict__ sinv, const float* __restrict__ sums)
{
    sinv[threadIdx.x] = 1.0f / sums[threadIdx.x];
}

// --------------------------------------------------------------------------
// Kernel 2: candidate path. 64 rows/block, 1024 threads (16 waves = 4/SIMD).
// GEMMs: 2 row-halves x 8 col-groups, plain per-chunk loads (BW-bound regime
// at 4 waves/SIMD; no manual pipelining, no sched_barrier pinning).
// amdgpu_waves_per_eu(4,4): pin allocator at 128-VGPR / 4-wave point.
// --------------------------------------------------------------------------
__global__ __launch_bounds__(NT)
__attribute__((amdgpu_waves_per_eu(4, 4)))
void cand_kernel(
    const float* __restrict__ xc, int N,
    const _Float16* __restrict__ W1h, const _Float16* __restrict__ W1l,
    const _Float16* __restrict__ W2h, const _Float16* __restrict__ W2l,
    const float* __restrict__ b1, const float* __restrict__ lng,
    const float* __restrict__ lnb, const float* __restrict__ b2,
    const _Float16* __restrict__ qph, const _Float16* __restrict__ qpl,
    const _Float16* __restrict__ Wt,
    const float* __restrict__ q2, const float* __restrict__ qinv,
    const float* __restrict__ tempp,
    float* __restrict__ cosw, float* __restrict__ eucw,
    _Float16* __restrict__ scw, float* __restrict__ sums)
{
    __shared__ _Float16 AH[MT * D];            // 64 KB, XOR-swizzled hi tile
    __shared__ _Float16 AL[MT * D];            // 64 KB, lo tile (reused as SC)
    // scratch: dotp[2][64][33] (dots) aliases lnred[8][64] (GEMM1 stats)
    __shared__ __align__(16) float scr[2 * MT * 33];   // 16.9 KB
    __shared__ float k2p[8 * MT];              // 2 KB (live into dots phase)
    __shared__ float lnmu[MT], lnisd[MT];
    __shared__ float k2s[MT], kins[MT];

    float*  dotp_  = scr;                      // [2][64][33]
    float2* lnred_ = (float2*)scr;             // [8][64]

    const int t    = threadIdx.x;
    const int wave = t >> 6;                   // 0..15
    const int lane = t & 63;
    const int l16  = lane & 15;
    const int lK   = lane >> 4;                // 0..3
    const int rh   = wave >> 3;                // row-half 0/1
    const int cg   = wave & 7;                 // col-group 0..7
    const int wcol = cg * 64;
    const int rbase = rh * 32;
    const int n0   = blockIdx.x * MT;
    const int nvalid = min(MT, N - n0);
    const float expT = expf(tempp[0]);
    const float INVS = 1.0f / 1024.0f;
    const f4 fz = {0.f, 0.f, 0.f, 0.f};

    // ---- stage X (nt loads; scaled x32, hi/lo fp16, swizzled) ----
    #pragma unroll
    for (int i = 0; i < 8; ++i) {
        int g = t + NT * i;                    // 0 .. 8191 (float4 index)
        int row = g >> 7;                      // 128 float4 per row
        int c4 = (g & 127) * 4;
        f4 v = fz;
        if (n0 + row < N)
            v = __builtin_nontemporal_load((const f4*)(xc + (size_t)(n0 + row) * D + c4));
        h4v hi, lo;
        #pragma unroll
        for (int e = 0; e < 4; ++e) {
            float s = v[e] * 32.0f;
            _Float16 h = (_Float16)s;
            hi[e] = h;
            lo[e] = (_Float16)(s - (float)h);
        }
        int idx = row * D + (c4 ^ ((row & 7) << 3));
        *(h4v*)&AH[idx] = hi;
        *(h4v*)&AL[idx] = lo;
    }
    __syncthreads();                                           // #1

    const int sw = (l16 & 7) << 3;
    const int ra0 = (rbase + l16) * D;
    const int ra1 = (rbase + 16 + l16) * D;

    auto gemm = [&](const _Float16* __restrict__ Wh, const _Float16* __restrict__ Wl,
                    f4 (&acc)[2][4]) {
        const _Float16* ph = Wh + (size_t)(wcol + l16) * D;
        const _Float16* pl = Wl + (size_t)(wcol + l16) * D;
        #pragma unroll 2
        for (int ks = 0; ks < 16; ++ks) {
            const int k0 = ks * 32 + lK * 8;
            const int ksw = k0 ^ sw;
            h8 bh[4], bl[4];
            #pragma unroll
            for (int cb = 0; cb < 4; ++cb) {
                bh[cb] = *(const h8*)(ph + (size_t)cb * 16 * D + k0);
                bl[cb] = *(const h8*)(pl + (size_t)cb * 16 * D + k0);
            }
            h8 ah0 = *(const h8*)&AH[ra0 + ksw];
            h8 al0 = *(const h8*)&AL[ra0 + ksw];
            h8 ah1 = *(const h8*)&AH[ra1 + ksw];
            h8 al1 = *(const h8*)&AL[ra1 + ksw];
            #pragma unroll
            for (int cb = 0; cb < 4; ++cb) {
                acc[0][cb] = MF(ah0, bh[cb], acc[0][cb]);
                acc[0][cb] = MF(al0, bh[cb], acc[0][cb]);
                acc[0][cb] = MF(ah0, bl[cb], acc[0][cb]);
                acc[1][cb] = MF(ah1, bh[cb], acc[1][cb]);
                acc[1][cb] = MF(al1, bh[cb], acc[1][cb]);
                acc[1][cb] = MF(ah1, bl[cb], acc[1][cb]);
            }
        }
    };

    f4 acc[2][4];
    #pragma unroll
    for (int rb = 0; rb < 2; ++rb)
        #pragma unroll
        for (int cb = 0; cb < 4; ++cb) acc[rb][cb] = fz;

    // ---- GEMM1: h = x @ W1.T + b1 ----
    gemm(W1h, W1l, acc);

    float s1a[2][4], s2a[2][4];
    #pragma unroll
    for (int rb = 0; rb < 2; ++rb)
        #pragma unroll
        for (int r = 0; r < 4; ++r) { s1a[rb][r] = 0.f; s2a[rb][r] = 0.f; }
    #pragma unroll
    for (int rb = 0; rb < 2; ++rb)
        #pragma unroll
        for (int cb = 0; cb < 4; ++cb) {
            const int j = wcol + cb * 16 + l16;
            const float bb = b1[j];
            #pragma unroll
            for (int r = 0; r < 4; ++r) {
                float v = acc[rb][cb][r] * INVS + bb;
                acc[rb][cb][r] = v;
                s1a[rb][r] += v;
                s2a[rb][r] += v * v;
            }
        }
    #pragma unroll
    for (int mm = 1; mm < 16; mm <<= 1)
        #pragma unroll
        for (int rb = 0; rb < 2; ++rb)
            #pragma unroll
            for (int r = 0; r < 4; ++r) {
                s1a[rb][r] += __shfl_xor(s1a[rb][r], mm);
                s2a[rb][r] += __shfl_xor(s2a[rb][r], mm);
            }
    if (l16 == 0) {
        #pragma unroll
        for (int rb = 0; rb < 2; ++rb)
            #pragma unroll
            for (int r = 0; r < 4; ++r)
                lnred_[cg * MT + rbase + rb * 16 + lK * 4 + r] = make_float2(s1a[rb][r], s2a[rb][r]);
    }
    __syncthreads();                                           // #2
    if (t < MT) {
        float sa = 0.f, sb = 0.f;
        #pragma unroll
        for (int w = 0; w < 8; ++w) { sa += lnred_[w * MT + t].x; sb += lnred_[w * MT + t].y; }
        float mu = sa * (1.0f / 512.0f);
        float var = sb * (1.0f / 512.0f) - mu * mu;
        lnmu[t] = mu;
        lnisd[t] = rsqrtf(var + 1e-5f);
    }
    __syncthreads();                                           // #3

    // ---- LN + GELU in regs, convert g -> AH/AL ----
    #pragma unroll
    for (int rb = 0; rb < 2; ++rb)
        #pragma unroll
        for (int cb = 0; cb < 4; ++cb) {
            const int j = wcol + cb * 16 + l16;
            const float gg = lng[j], bb = lnb[j];
            #pragma unroll
            for (int r = 0; r < 4; ++r) {
                const int m = rbase + rb * 16 + lK * 4 + r;
                float v = (acc[rb][cb][r] - lnmu[m]) * lnisd[m] * gg + bb;
                v = gelu_fast(v) * 32.0f;
                _Float16 hi = (_Float16)v;
                const int idx = m * D + (j ^ ((m & 7) << 3));
                AH[idx] = hi;
                AL[idx] = (_Float16)(v - (float)hi);
            }
        }
    __syncthreads();                                           // #4

    // ---- GEMM2: kp = g @ W2.T + b2 ----
    #pragma unroll
    for (int rb = 0; rb < 2; ++rb)
        #pragma unroll
        for (int cb = 0; cb < 4; ++cb) acc[rb][cb] = fz;
    gemm(W2h, W2l, acc);

    float ss[2][4];
    #pragma unroll
    for (int rb = 0; rb < 2; ++rb)
        #pragma unroll
        for (int r = 0; r < 4; ++r) ss[rb][r] = 0.f;
    #pragma unroll
    for (int rb = 0; rb < 2; ++rb)
        #pragma unroll
        for (int cb = 0; cb < 4; ++cb) {
            const int j = wcol + cb * 16 + l16;
            const float bb = b2[j];
            #pragma unroll
            for (int r = 0; r < 4; ++r) {
                float v = acc[rb][cb][r] * INVS + bb;
                acc[rb][cb][r] = v;
                ss[rb][r] += v * v;
            }
        }
    #pragma unroll
    for (int mm = 1; mm < 16; mm <<= 1)
        #pragma unroll
        for (int rb = 0; rb < 2; ++rb)
            #pragma unroll
            for (int r = 0; r < 4; ++r)
                ss[rb][r] += __shfl_xor(ss[rb][r], mm);
    __syncthreads();                                           // #5 (GEMM2 reads done)
    if (l16 == 0) {
        #pragma unroll
        for (int rb = 0; rb < 2; ++rb)
            #pragma unroll
            for (int r = 0; r < 4; ++r)
                k2p[cg * MT + rbase + rb * 16 + lK * 4 + r] = ss[rb][r];
    }
    // convert kp (x32 hi/lo) -> AH/AL
    #pragma unroll
    for (int rb = 0; rb < 2; ++rb)
        #pragma unroll
        for (int cb = 0; cb < 4; ++cb) {
            const int j = wcol + cb * 16 + l16;
            #pragma unroll
            for (int r = 0; r < 4; ++r) {
                const int m = rbase + rb * 16 + lK * 4 + r;
                float v = acc[rb][cb][r] * 32.0f;
                _Float16 hi = (_Float16)v;
                const int idx = m * D + (j ^ ((m & 7) << 3));
                AH[idx] = hi;
                AL[idx] = (_Float16)(v - (float)hi);
            }
        }
    __syncthreads();                                           // #6

    if (t < MT) {
        float sa = 0.f;
        #pragma unroll
        for (int w = 0; w < 8; ++w) sa += k2p[w * MT + t];
        k2s[t] = sa;
        kins[t] = rsqrtf(fmaxf(sa, 1e-30f));
    }

    // ---- dots = kp @ qp.T via MFMA (16 waves = 4 rq x 2 kh x 2 cbq) ----
    {
        const int rq = wave >> 2, kh = (wave >> 1) & 1, cbq = wave & 1;
        f4 ad = fz;
        const int ra = (rq * 16 + l16) * D;
        const int j = cbq * 16 + l16;
        #pragma unroll 2
        for (int ks = 0; ks < 8; ++ks) {
            const int k0 = kh * 256 + ks * 32 + lK * 8;
            const int ksw = k0 ^ sw;
            h8 ah0 = *(const h8*)&AH[ra + ksw];
            h8 al0 = *(const h8*)&AL[ra + ksw];
            h8 bh = *(const h8*)&qph[j * D + k0];
            h8 bl = *(const h8*)&qpl[j * D + k0];
            ad = MF(ah0, bh, ad); ad = MF(al0, bh, ad); ad = MF(ah0, bl, ad);
        }
        #pragma unroll
        for (int r = 0; r < 4; ++r)
            dotp_[(kh * MT + rq * 16 + lK * 4 + r) * 33 + cbq * 16 + l16] = ad[r];
    }

    // ---- scores: kp_hi @ Wt.T (2 row-halves x 8 bh-groups) ----
    f4 as[2][2];
    as[0][0] = fz; as[0][1] = fz; as[1][0] = fz; as[1][1] = fz;
    {
        const _Float16* wt0 = Wt + (size_t)(cg * 32 + l16) * D;
        const _Float16* wt1 = wt0 + (size_t)16 * D;
        #pragma unroll 2
        for (int ks = 0; ks < 16; ++ks) {
            const int k0 = ks * 32 + lK * 8;
            const int ksw = k0 ^ sw;
            h8 w0 = *(const h8*)(wt0 + k0);
            h8 w1 = *(const h8*)(wt1 + k0);
            h8 a0 = *(const h8*)&AH[ra0 + ksw];
            h8 a1 = *(const h8*)&AH[ra1 + ksw];
            as[0][0] = MF(a0, w0, as[0][0]);
            as[0][1] = MF(a0, w1, as[0][1]);
            as[1][0] = MF(a1, w0, as[1][0]);
            as[1][1] = MF(a1, w1, as[1][1]);
        }
    }

    // ---- fused softmax-denominator partial sums ----
    {
        float part[2] = {0.f, 0.f};
        #pragma unroll
        for (int cb = 0; cb < 2; ++cb)
            #pragma unroll
            for (int rb = 0; rb < 2; ++rb)
                #pragma unroll
                for (int r = 0; r < 4; ++r) {
                    const int n = rbase + rb * 16 + lK * 4 + r;
                    if (n < nvalid)
                        part[cb] += __expf(as[rb][cb][r] * (1.0f / 32.0f));
                }
        #pragma unroll
        for (int cb = 0; cb < 2; ++cb) {
            part[cb] += __shfl_xor(part[cb], 16);
            part[cb] += __shfl_xor(part[cb], 32);
        }
        if (lK == 0) {
            atomicAdd(&sums[cg * 32 + l16], part[0]);
            atomicAdd(&sums[cg * 32 + 16 + l16], part[1]);
        }
    }
    __syncthreads();                                           // #7 (dotp/k2s done; AH/AL reads done)

    // ---- cos / euc outputs (nt stores) ----
    for (int p = t; p < BQ * MT; p += NT) {
        const int m = p & (MT - 1), b = p >> 6;
        if (m < nvalid) {
            float dt = (dotp_[(0 * MT + m) * 33 + b] + dotp_[(1 * MT + m) * 33 + b]) * INVS;
            __builtin_nontemporal_store(dt * qinv[b] * kins[m] * expT,
                                        &cosw[(size_t)b * N + n0 + m]);
            float dd = q2[b] + k2s[m] - 2.0f * dt;
            __builtin_nontemporal_store(1.0f / (1.0f + sqrtf(fmaxf(dd, 0.f))),
                                        &eucw[(size_t)b * N + n0 + m]);
        }
    }

    // ---- scores -> SC (overlay AL, dead after dots + #7), coalesced out ----
    _Float16* SC = AL;   // element layout: n*256 + (b ^ (n&31))*8 + h
    {
        #pragma unroll
        for (int cb = 0; cb < 2; ++cb) {
            const int bhc = cg * 32 + cb * 16 + l16;
            const int b = bhc >> 3, h = bhc & 7;
            #pragma unroll
            for (int rb = 0; rb < 2; ++rb) {
                #pragma unroll
                for (int r = 0; r < 4; ++r) {
                    const int n = rbase + rb * 16 + lK * 4 + r;
                    SC[n * 256 + ((b ^ (n & 31)) * 8) + h] =
                        (_Float16)(as[rb][cb][r] * (1.0f / 32.0f));
                }
            }
        }
    }
    __syncthreads();                                           // #8

    #pragma unroll
    for (int p = t; p < BQ * MT; p += NT) {
        const int b = p >> 6, n = p & (MT - 1);
        if (n < nvalid) {
            h8 v = *(const h8*)&SC[n * 256 + ((b ^ (n & 31)) * 8)];
            __builtin_nontemporal_store(v, (h8*)&scw[((size_t)b * N + n0 + n) * NH]);
        }
    }
}

// --------------------------------------------------------------------------
// Kernel 4: learned_sim + fused 3->64->1 MLP + sigmoid per (b,n).
// --------------------------------------------------------------------------
__global__ __launch_bounds__(256) void final_kernel(
    const float* __restrict__ cosw, const float* __restrict__ eucw,
    const _Float16* __restrict__ scw, int N,
    const float* __restrict__ sinv,
    const float* __restrict__ fW1, const float* __restrict__ fb1,
    const float* __restrict__ fW2, const float* __restrict__ fb2,
    float* __restrict__ out, int total)
{
    __shared__ float w1s[192], b1s[64], w2s[64];
    __shared__ float sis[BQ * NH];
    __shared__ float b2s;
    const int t = threadIdx.x;
    if (t < 192) w1s[t] = fW1[t];
    else { b1s[t - 192] = fb1[t - 192]; w2s[t - 192] = fW2[t - 192]; }
    sis[t] = sinv[t];
    if (t == 0) b2s = fb2[0];
    __syncthreads();

    const int idx = blockIdx.x * 256 + t;
    if (idx >= total) return;
    const int b = idx / N;

    float c = cosw[idx], e = eucw[idx];
    h8 v = *(const h8*)&scw[(size_t)idx * NH];
    float ls = 0.f;
    #pragma unroll
    for (int h = 0; h < NH; ++h)
        ls += __expf((float)v[h]) * sis[b * NH + h];
    ls *= 0.125f;

    float logit = b2s;
    #pragma unroll
    for (int j = 0; j < 64; ++j) {
        float hj = fmaf(w1s[j*3], c, fmaf(w1s[j*3+1], e, fmaf(w1s[j*3+2], ls, b1s[j])));
        logit = fmaf(w2s[j], fmaxf(hj, 0.f), logit);
    }
    out[idx] = 1.0f / (1.0f + expf(-logit));
}

// --------------------------------------------------------------------------
extern "C" void kernel_launch(void* const* d_in, const int* in_sizes, int n_in,
                              void* d_out, int out_size, void* d_ws, size_t ws_size,
                              hipStream_t stream)
{
    const float* xq   = (const float*)d_in[0];
    const float* xc   = (const float*)d_in[1];
    const float* temp = (const float*)d_in[2];
    const float* qW1  = (const float*)d_in[3];
    const float* qb1  = (const float*)d_in[4];
    const float* qlg  = (const float*)d_in[5];
    const float* qlb  = (const float*)d_in[6];
    const float* qW2  = (const float*)d_in[7];
    const float* qb2  = (const float*)d_in[8];
    const float* kW1  = (const float*)d_in[9];
    const float* kb1  = (const float*)d_in[10];
    const float* klg  = (const float*)d_in[11];
    const float* klb  = (const float*)d_in[12];
    const float* kW2  = (const float*)d_in[13];
    const float* kb2  = (const float*)d_in[14];
    const float* Wio  = (const float*)d_in[15];
    const float* bio  = (const float*)d_in[16];
    const float* fW1  = (const float*)d_in[17];
    const float* fb1  = (const float*)d_in[18];
    const float* fW2  = (const float*)d_in[19];
    const float* fb2  = (const float*)d_in[20];

    const int N = in_sizes[1] / D;

    float* ws   = (float*)d_ws;
    float* qp   = ws;                         // 16384
    float* qv   = qp + BQ * D;                // 16384
    float* q2   = qv + BQ * D;                // 32
    float* qinv = q2 + BQ;                    // 32
    float* sinv = qinv + BQ;                  // 256
    float* sums = sinv + BQ * NH;             // 256
    float* cosw = sums + BQ * NH;             // BQ*N
    float* eucw = cosw + (size_t)BQ * N;      // BQ*N
    float* fend = eucw + (size_t)BQ * N;

    _Float16* hb  = (_Float16*)fend;
    _Float16* W1h = hb;                       // 262144 each
    _Float16* W1l = W1h + D * D;
    _Float16* W2h = W1l + D * D;
    _Float16* W2l = W2h + D * D;
    _Float16* qph = W2l + D * D;              // 16384
    _Float16* qpl = qph + BQ * D;             // 16384
    _Float16* Wt  = qpl + BQ * D;             // 256*512
    _Float16* scw = Wt + BQ * NH * D;         // BQ*N*NH  ([b][n][h])

    qproj_kernel<<<BQ, 256, 0, stream>>>(xq, qW1, qb1, qlg, qlb, qW2, qb2,
                                         Wio, bio, qp, qv, q2, qinv,
                                         qph, qpl);

    wprep_kernel<<<(D * D + 255) / 256, 256, 0, stream>>>(kW1, kW2,
                                                          W1h, W1l, W2h, W2l);

    wtld_kernel<<<BQ * NH, 256, 0, stream>>>(qv, Wio, Wt);

    zero256_kernel<<<1, 256, 0, stream>>>(sums);

    const int nblk = (N + MT - 1) / MT;
    cand_kernel<<<nblk, NT, 0, stream>>>(xc, N,
                                         W1h, W1l, W2h, W2l,
                                         kb1, klg, klb, kb2,
                                         qph, qpl, Wt, q2, qinv, temp,
                                         cosw, eucw, scw, sums);

    inv256_kernel<<<1, 256, 0, stream>>>(sinv, sums);

    const int total = BQ * N;
    final_kernel<<<(total + 255) / 256, 256, 0, stream>>>(cosw, eucw, scw, N, sinv,
                                                          fW1, fb1, fW2, fb2,
                                                          (float*)d_out, total);
}

// Round 15
// 711.761 us; speedup vs baseline: 1.1470x; 1.1470x over previous
//
#include <hip/hip_runtime.h>
#include <math.h>

#define D    512
#define BQ   32
#define NH   8
#define MT   32
#define NT   512   // threads per cand block (8 waves)

typedef _Float16 h2  __attribute__((ext_vector_type(2)));
typedef _Float16 h4v __attribute__((ext_vector_type(4)));
typedef _Float16 h8  __attribute__((ext_vector_type(8)));
typedef float    f4  __attribute__((ext_vector_type(4)));

__device__ __forceinline__ f4 MF(h8 a, h8 b, f4 c) {
  return __builtin_amdgcn_mfma_f32_16x16x32_f16(a, b, c, 0, 0, 0);
}

__device__ __forceinline__ float erf_fast(float x) {
    float ax = fabsf(x);
    float tt = 1.0f / fmaf(0.3275911f, ax, 1.0f);
    float poly = tt * fmaf(tt, fmaf(tt, fmaf(tt, fmaf(tt, 1.061405429f, -1.453152027f),
                          1.421413741f), -0.284496736f), 0.254829592f);
    float r = 1.0f - poly * __expf(-ax * ax);
    return copysignf(r, x);
}
__device__ __forceinline__ float gelu_fast(float x) {
    return 0.5f * x * (1.0f + erf_fast(x * 0.7071067811865475f));
}
__device__ __forceinline__ float gelu_exact(float x) {
    return 0.5f * x * (1.0f + erff(x * 0.7071067811865475f));
}

// --------------------------------------------------------------------------
// Kernel 1: query path. One block per query row (32 blocks, 256 threads).
// --------------------------------------------------------------------------
__global__ __launch_bounds__(256) void qproj_kernel(
    const float* __restrict__ xq,
    const float* __restrict__ W1, const float* __restrict__ b1,
    const float* __restrict__ lng, const float* __restrict__ lnb,
    const float* __restrict__ W2, const float* __restrict__ b2,
    const float* __restrict__ Wio, const float* __restrict__ bio,
    float* __restrict__ qp, float* __restrict__ qv,
    float* __restrict__ q2o, float* __restrict__ qinvo,
    _Float16* __restrict__ qph, _Float16* __restrict__ qpl)
{
    __shared__ float xs[D];
    __shared__ float hs[D];
    __shared__ float red[16];
    const int t = threadIdx.x;
    const int row = blockIdx.x;

    for (int i = t; i < D; i += 256) xs[i] = xq[row * D + i];
    __syncthreads();

    float a0 = 0.f, a1 = 0.f;
    for (int i = 0; i < D; i += 4) {
        float4 xv = *(const float4*)&xs[i];
        float4 w0 = *(const float4*)&W1[(size_t)t * D + i];
        float4 w1 = *(const float4*)&W1[(size_t)(t + 256) * D + i];
        a0 += xv.x*w0.x + xv.y*w0.y + xv.z*w0.z + xv.w*w0.w;
        a1 += xv.x*w1.x + xv.y*w1.y + xv.z*w1.z + xv.w*w1.w;
    }
    float h0 = a0 + b1[t], h1 = a1 + b1[t + 256];

    float s1 = h0 + h1, s2 = h0*h0 + h1*h1;
    for (int off = 32; off > 0; off >>= 1) { s1 += __shfl_down(s1, off); s2 += __shfl_down(s2, off); }
    if ((t & 63) == 0) { red[t >> 6] = s1; red[(t >> 6) + 4] = s2; }
    __syncthreads();
    if (t == 0) {
        float sa = red[0] + red[1] + red[2] + red[3];
        float sb = red[4] + red[5] + red[6] + red[7];
        float mu = sa / (float)D;
        red[8] = mu;
        red[9] = sb / (float)D - mu * mu;
    }
    __syncthreads();
    float mu = red[8];
    float isd = 1.0f / sqrtf(red[9] + 1e-5f);
    hs[t]       = gelu_exact((h0 - mu) * isd * lng[t]       + lnb[t]);
    hs[t + 256] = gelu_exact((h1 - mu) * isd * lng[t + 256] + lnb[t + 256]);
    __syncthreads();

    a0 = 0.f; a1 = 0.f;
    for (int i = 0; i < D; i += 4) {
        float4 gv = *(const float4*)&hs[i];
        float4 w0 = *(const float4*)&W2[(size_t)t * D + i];
        float4 w1 = *(const float4*)&W2[(size_t)(t + 256) * D + i];
        a0 += gv.x*w0.x + gv.y*w0.y + gv.z*w0.z + gv.w*w0.w;
        a1 += gv.x*w1.x + gv.y*w1.y + gv.z*w1.z + gv.w*w1.w;
    }
    float p0 = a0 + b2[t], p1 = a1 + b2[t + 256];
    qp[row * D + t] = p0;
    qp[row * D + t + 256] = p1;
    {
        float sc0 = p0 * 32.0f, sc1 = p1 * 32.0f;
        _Float16 hh0 = (_Float16)sc0, hh1 = (_Float16)sc1;
        qph[row * D + t]       = hh0;
        qpl[row * D + t]       = (_Float16)(sc0 - (float)hh0);
        qph[row * D + t + 256] = hh1;
        qpl[row * D + t + 256] = (_Float16)(sc1 - (float)hh1);
    }
    __syncthreads();
    xs[t] = p0; xs[t + 256] = p1;

    s1 = p0*p0 + p1*p1;
    for (int off = 32; off > 0; off >>= 1) s1 += __shfl_down(s1, off);
    if ((t & 63) == 0) red[t >> 6] = s1;
    __syncthreads();
    if (t == 0) {
        float sa = red[0] + red[1] + red[2] + red[3];
        q2o[row] = sa;
        qinvo[row] = 1.0f / sqrtf(sa);
    }
    __syncthreads();

    a0 = 0.f; a1 = 0.f;
    for (int i = 0; i < D; i += 4) {
        float4 pv = *(const float4*)&xs[i];
        float4 w0 = *(const float4*)&Wio[(size_t)t * D + i];
        float4 w1 = *(const float4*)&Wio[(size_t)(t + 256) * D + i];
        a0 += pv.x*w0.x + pv.y*w0.y + pv.z*w0.z + pv.w*w0.w;
        a1 += pv.x*w1.x + pv.y*w1.y + pv.z*w1.z + pv.w*w1.w;
    }
    qv[row * D + t]       = a0 + bio[t];
    qv[row * D + t + 256] = a1 + bio[t + 256];
}

// --------------------------------------------------------------------------
// Weight prep: fp16 hi/lo split of 32*W for W1, W2.
// --------------------------------------------------------------------------
__global__ __launch_bounds__(256) void wprep_kernel(
    const float* __restrict__ W1, const float* __restrict__ W2,
    _Float16* __restrict__ W1h, _Float16* __restrict__ W1l,
    _Float16* __restrict__ W2h, _Float16* __restrict__ W2l)
{
    int idx = blockIdx.x * 256 + threadIdx.x;
    if (idx >= D * D) return;
    float a = W1[idx] * 32.0f;
    _Float16 hi = (_Float16)a;
    W1h[idx] = hi; W1l[idx] = (_Float16)(a - (float)hi);
    float b = W2[idx] * 32.0f;
    hi = (_Float16)b;
    W2h[idx] = hi; W2l[idx] = (_Float16)(b - (float)hi);
}

// --------------------------------------------------------------------------
// W-tilde prep: Wt[b,h,:] = (1/8) * sum_d qv[b, h*64+d] * Wk[h*64+d, :]
// --------------------------------------------------------------------------
__global__ __launch_bounds__(256) void wtld_kernel(
    const float* __restrict__ qv, const float* __restrict__ Wio,
    _Float16* __restrict__ Wt)
{
    __shared__ float qs[64];
    const int bh = blockIdx.x, b = bh >> 3, h = bh & 7;
    const int t = threadIdx.x;
    if (t < 64) qs[t] = qv[b * D + h * 64 + t] * 0.125f;
    __syncthreads();
    const float* Wk = Wio + (size_t)D * D + (size_t)(h * 64) * D;
    float a0 = 0.f, a1 = 0.f;
    #pragma unroll 4
    for (int d = 0; d < 64; ++d) {
        float q = qs[d];
        a0 += q * Wk[(size_t)d * D + t];
        a1 += q * Wk[(size_t)d * D + t + 256];
    }
    Wt[(size_t)bh * D + t]       = (_Float16)a0;
    Wt[(size_t)bh * D + t + 256] = (_Float16)a1;
}

// --------------------------------------------------------------------------
// Tiny helpers.
// --------------------------------------------------------------------------
__global__ __launch_bounds__(256) void zero256_kernel(float* __restrict__ p)
{
    p[threadIdx.x] = 0.0f;
}
__global__ __launch_bounds__(256) void inv256_kernel(
    float* __restrict__ sinv, const float* __restrict__ sums)
{
    sinv[threadIdx.x] = 1.0f / sums[threadIdx.x];
}

// --------------------------------------------------------------------------
// Kernel 2: candidate path. 32 rows/block, 512 threads (8 waves).
// 2-product GEMM: activations fp16-single (AH tile only), weights hi/lo
// from L2 (plain unroll-2 loads). LDS ~45 KB -> 2 blocks/CU = 4 waves/SIMD
// (the occupancy that rounds 5-13 never actually achieved).
// --------------------------------------------------------------------------
__global__ __launch_bounds__(NT) void cand_kernel(
    const float* __restrict__ xc, int N,
    const _Float16* __restrict__ W1h, const _Float16* __restrict__ W1l,
    const _Float16* __restrict__ W2h, const _Float16* __restrict__ W2l,
    const float* __restrict__ b1, const float* __restrict__ lng,
    const float* __restrict__ lnb, const float* __restrict__ b2,
    const _Float16* __restrict__ qph, const _Float16* __restrict__ qpl,
    const _Float16* __restrict__ Wt,
    const float* __restrict__ q2, const float* __restrict__ qinv,
    const float* __restrict__ tempp,
    float* __restrict__ cosw, float* __restrict__ eucw,
    _Float16* __restrict__ scw, float* __restrict__ sums)
{
    __shared__ _Float16 AH[MT * D];          // 32 KB (swizzled); reused as SC
    __shared__ float dotp_[2 * MT * 33];     // 8.4 KB
    __shared__ float k2p_[8 * MT];           // 1 KB
    __shared__ float k2s_[MT], kins_[MT];
    __shared__ float2 lnred_[8 * MT];        // 2 KB
    __shared__ float lnmu_[MT], lnisd_[MT];

    const int t    = threadIdx.x;
    const int wave = t >> 6;
    const int lane = t & 63;
    const int l16  = lane & 15;
    const int lK   = lane >> 4;
    const int wcol = wave * 64;
    const int n0   = blockIdx.x * MT;
    const int nvalid = min(MT, N - n0);
    const float expT = expf(tempp[0]);
    const float INVS = 1.0f / 1024.0f;
    const f4 fz = {0.f, 0.f, 0.f, 0.f};

    // ---- stage X (nt loads; scaled x32, fp16 single, swizzled) ----
    #pragma unroll
    for (int i = 0; i < 8; ++i) {
        int g = t + NT * i;                  // 0 .. 4095 (float4 index)
        int row = g >> 7;                    // 128 float4 per row
        int c4 = (g & 127) * 4;
        f4 v = fz;
        if (n0 + row < N)
            v = __builtin_nontemporal_load((const f4*)(xc + (size_t)(n0 + row) * D + c4));
        h4v hi;
        #pragma unroll
        for (int e = 0; e < 4; ++e) hi[e] = (_Float16)(v[e] * 32.0f);
        *(h4v*)&AH[row * D + (c4 ^ ((row & 7) << 3))] = hi;
    }
    __syncthreads();                                           // #1

    const int sw = (l16 & 7) << 3;
    const int r0 = l16 * D, r1 = (l16 + 16) * D;

    // 2-product GEMM: C = xh * (Wh + Wl). 16 MFMAs / 8 weight loads / chunk.
    auto gemm = [&](const _Float16* __restrict__ Wh, const _Float16* __restrict__ Wl,
                    f4 (&acc)[2][4]) {
        const _Float16* ph = Wh + (size_t)(wcol + l16) * D;
        const _Float16* pl = Wl + (size_t)(wcol + l16) * D;
        #pragma unroll 2
        for (int ks = 0; ks < 16; ++ks) {
            const int k0 = ks * 32 + lK * 8;
            const int ksw = k0 ^ sw;
            h8 bh[4], bl[4];
            #pragma unroll
            for (int cb = 0; cb < 4; ++cb) {
                bh[cb] = *(const h8*)(ph + (size_t)cb * 16 * D + k0);
                bl[cb] = *(const h8*)(pl + (size_t)cb * 16 * D + k0);
            }
            h8 ah0 = *(const h8*)&AH[r0 + ksw];
            h8 ah1 = *(const h8*)&AH[r1 + ksw];
            #pragma unroll
            for (int cb = 0; cb < 4; ++cb) {
                acc[0][cb] = MF(ah0, bh[cb], acc[0][cb]);
                acc[0][cb] = MF(ah0, bl[cb], acc[0][cb]);
                acc[1][cb] = MF(ah1, bh[cb], acc[1][cb]);
                acc[1][cb] = MF(ah1, bl[cb], acc[1][cb]);
            }
        }
    };

    f4 acc[2][4];
    #pragma unroll
    for (int rb = 0; rb < 2; ++rb)
        #pragma unroll
        for (int cb = 0; cb < 4; ++cb) acc[rb][cb] = fz;

    // ---- GEMM1: h = x @ W1.T + b1 ----
    gemm(W1h, W1l, acc);

    float s1a[2][4], s2a[2][4];
    #pragma unroll
    for (int rb = 0; rb < 2; ++rb)
        #pragma unroll
        for (int r = 0; r < 4; ++r) { s1a[rb][r] = 0.f; s2a[rb][r] = 0.f; }
    #pragma unroll
    for (int rb = 0; rb < 2; ++rb)
        #pragma unroll
        for (int cb = 0; cb < 4; ++cb) {
            const int j = wcol + cb * 16 + l16;
            const float bb = b1[j];
            #pragma unroll
            for (int r = 0; r < 4; ++r) {
                float v = acc[rb][cb][r] * INVS + bb;
                acc[rb][cb][r] = v;
                s1a[rb][r] += v;
                s2a[rb][r] += v * v;
            }
        }
    #pragma unroll
    for (int mm = 1; mm < 16; mm <<= 1)
        #pragma unroll
        for (int rb = 0; rb < 2; ++rb)
            #pragma unroll
            for (int r = 0; r < 4; ++r) {
                s1a[rb][r] += __shfl_xor(s1a[rb][r], mm);
                s2a[rb][r] += __shfl_xor(s2a[rb][r], mm);
            }
    if (l16 == 0) {
        #pragma unroll
        for (int rb = 0; rb < 2; ++rb)
            #pragma unroll
            for (int r = 0; r < 4; ++r)
                lnred_[wave * MT + rb * 16 + lK * 4 + r] = make_float2(s1a[rb][r], s2a[rb][r]);
    }
    __syncthreads();                                           // #2
    if (t < MT) {
        float sa = 0.f, sb = 0.f;
        #pragma unroll
        for (int w = 0; w < 8; ++w) { sa += lnred_[w * MT + t].x; sb += lnred_[w * MT + t].y; }
        float mu = sa * (1.0f / 512.0f);
        float var = sb * (1.0f / 512.0f) - mu * mu;
        lnmu_[t] = mu;
        lnisd_[t] = rsqrtf(var + 1e-5f);
    }
    __syncthreads();                                           // #3

    // ---- LN + GELU in regs, convert g (fp16 single) -> AH ----
    #pragma unroll
    for (int rb = 0; rb < 2; ++rb)
        #pragma unroll
        for (int cb = 0; cb < 4; ++cb) {
            const int j = wcol + cb * 16 + l16;
            const float gg = lng[j], bb = lnb[j];
            #pragma unroll
            for (int r = 0; r < 4; ++r) {
                const int m = rb * 16 + lK * 4 + r;
                float v = (acc[rb][cb][r] - lnmu_[m]) * lnisd_[m] * gg + bb;
                v = gelu_fast(v) * 32.0f;
                AH[m * D + (j ^ ((m & 7) << 3))] = (_Float16)v;
            }
        }
    __syncthreads();                                           // #4

    // ---- GEMM2: kp = g @ W2.T + b2 ----
    #pragma unroll
    for (int rb = 0; rb < 2; ++rb)
        #pragma unroll
        for (int cb = 0; cb < 4; ++cb) acc[rb][cb] = fz;
    gemm(W2h, W2l, acc);

    float ss[2][4];
    #pragma unroll
    for (int rb = 0; rb < 2; ++rb)
        #pragma unroll
        for (int r = 0; r < 4; ++r) ss[rb][r] = 0.f;
    #pragma unroll
    for (int rb = 0; rb < 2; ++rb)
        #pragma unroll
        for (int cb = 0; cb < 4; ++cb) {
            const int j = wcol + cb * 16 + l16;
            const float bb = b2[j];
            #pragma unroll
            for (int r = 0; r < 4; ++r) {
                float v = acc[rb][cb][r] * INVS + bb;
                acc[rb][cb][r] = v;
                ss[rb][r] += v * v;
            }
        }
    #pragma unroll
    for (int mm = 1; mm < 16; mm <<= 1)
        #pragma unroll
        for (int rb = 0; rb < 2; ++rb)
            #pragma unroll
            for (int r = 0; r < 4; ++r)
                ss[rb][r] += __shfl_xor(ss[rb][r], mm);
    __syncthreads();                                           // #5 (GEMM2 AH reads done)
    if (l16 == 0) {
        #pragma unroll
        for (int rb = 0; rb < 2; ++rb)
            #pragma unroll
            for (int r = 0; r < 4; ++r)
                k2p_[wave * MT + rb * 16 + lK * 4 + r] = ss[rb][r];
    }
    // convert kp (x32, fp16 single) -> AH
    #pragma unroll
    for (int rb = 0; rb < 2; ++rb)
        #pragma unroll
        for (int cb = 0; cb < 4; ++cb) {
            const int j = wcol + cb * 16 + l16;
            #pragma unroll
            for (int r = 0; r < 4; ++r) {
                const int m = rb * 16 + lK * 4 + r;
                AH[m * D + (j ^ ((m & 7) << 3))] = (_Float16)(acc[rb][cb][r] * 32.0f);
            }
        }
    __syncthreads();                                           // #6

    if (t < MT) {
        float sa = 0.f;
        #pragma unroll
        for (int w = 0; w < 8; ++w) sa += k2p_[w * MT + t];
        k2s_[t] = sa;
        kins_[t] = rsqrtf(fmaxf(sa, 1e-30f));
    }

    // ---- dots = kp @ qp.T via MFMA (8 waves = 2 rh x 2 kh x 2 cbq) ----
    {
        const int rh = wave >> 2, kh = (wave >> 1) & 1, cbq = wave & 1;
        f4 ad = fz;
        const int ra = (rh * 16 + l16) * D;
        const int j = cbq * 16 + l16;
        #pragma unroll 2
        for (int ks = 0; ks < 8; ++ks) {
            const int k0 = kh * 256 + ks * 32 + lK * 8;
            const int ksw = k0 ^ sw;
            h8 ah0 = *(const h8*)&AH[ra + ksw];
            h8 bh = *(const h8*)&qph[j * D + k0];
            h8 bl = *(const h8*)&qpl[j * D + k0];
            ad = MF(ah0, bh, ad);
            ad = MF(ah0, bl, ad);
        }
        #pragma unroll
        for (int r = 0; r < 4; ++r)
            dotp_[(kh * MT + rh * 16 + lK * 4 + r) * 33 + cbq * 16 + l16] = ad[r];
    }

    // ---- scores: kp_hi @ Wt.T (wave owns 32 (b,h) cols) ----
    f4 as[2][2];
    as[0][0] = fz; as[0][1] = fz; as[1][0] = fz; as[1][1] = fz;
    {
        const _Float16* wt0 = Wt + (size_t)(wave * 32 + l16) * D;
        const _Float16* wt1 = wt0 + (size_t)16 * D;
        #pragma unroll 2
        for (int ks = 0; ks < 16; ++ks) {
            const int k0 = ks * 32 + lK * 8;
            const int ksw = k0 ^ sw;
            h8 w0 = *(const h8*)(wt0 + k0);
            h8 w1 = *(const h8*)(wt1 + k0);
            h8 a0 = *(const h8*)&AH[r0 + ksw];
            h8 a1 = *(const h8*)&AH[r1 + ksw];
            as[0][0] = MF(a0, w0, as[0][0]);
            as[0][1] = MF(a0, w1, as[0][1]);
            as[1][0] = MF(a1, w0, as[1][0]);
            as[1][1] = MF(a1, w1, as[1][1]);
        }
    }

    // ---- fused softmax-denominator partial sums ----
    {
        float part[2] = {0.f, 0.f};
        #pragma unroll
        for (int cb = 0; cb < 2; ++cb)
            #pragma unroll
            for (int rb = 0; rb < 2; ++rb)
                #pragma unroll
                for (int r = 0; r < 4; ++r) {
                    const int n = rb * 16 + lK * 4 + r;
                    if (n < nvalid)
                        part[cb] += __expf(as[rb][cb][r] * (1.0f / 32.0f));
                }
        #pragma unroll
        for (int cb = 0; cb < 2; ++cb) {
            part[cb] += __shfl_xor(part[cb], 16);
            part[cb] += __shfl_xor(part[cb], 32);
        }
        if (lK == 0) {
            atomicAdd(&sums[wave * 32 + l16], part[0]);
            atomicAdd(&sums[wave * 32 + 16 + l16], part[1]);
        }
    }
    __syncthreads();                                           // #7 (AH reads done)

    // ---- cos / euc outputs (nt stores) ----
    for (int p = t; p < BQ * MT; p += NT) {
        const int m = p & (MT - 1), b = p >> 5;
        if (m < nvalid) {
            float dt = (dotp_[(0 * MT + m) * 33 + b] + dotp_[(1 * MT + m) * 33 + b]) * INVS;
            __builtin_nontemporal_store(dt * qinv[b] * kins_[m] * expT,
                                        &cosw[(size_t)b * N + n0 + m]);
            float dd = q2[b] + k2s_[m] - 2.0f * dt;
            __builtin_nontemporal_store(1.0f / (1.0f + sqrtf(fmaxf(dd, 0.f))),
                                        &eucw[(size_t)b * N + n0 + m]);
        }
    }

    // ---- scores -> SC (overlay AH, dead after #7), then coalesced out ----
    _Float16* SC = AH;   // element layout: n*256 + (b ^ (n&31))*8 + h
    {
        const int bh0 = wave * 32 + l16;
        #pragma unroll
        for (int cb = 0; cb < 2; ++cb) {
            const int bhc = bh0 + cb * 16;
            const int b = bhc >> 3, h = bhc & 7;
            #pragma unroll
            for (int rb = 0; rb < 2; ++rb) {
                #pragma unroll
                for (int r = 0; r < 4; ++r) {
                    const int n = rb * 16 + lK * 4 + r;
                    SC[n * 256 + ((b ^ (n & 31)) * 8) + h] =
                        (_Float16)(as[rb][cb][r] * (1.0f / 32.0f));
                }
            }
        }
    }
    __syncthreads();                                           // #8

    #pragma unroll
    for (int p = t; p < BQ * MT; p += NT) {
        const int b = p >> 5, n = p & (MT - 1);
        if (n < nvalid) {
            h8 v = *(const h8*)&SC[n * 256 + ((b ^ (n & 31)) * 8)];
            __builtin_nontemporal_store(v, (h8*)&scw[((size_t)b * N + n0 + n) * NH]);
        }
    }
}

// --------------------------------------------------------------------------
// Kernel 4: learned_sim + fused 3->64->1 MLP + sigmoid per (b,n).
// --------------------------------------------------------------------------
__global__ __launch_bounds__(256) void final_kernel(
    const float* __restrict__ cosw, const float* __restrict__ eucw,
    const _Float16* __restrict__ scw, int N,
    const float* __restrict__ sinv,
    const float* __restrict__ fW1, const float* __restrict__ fb1,
    const float* __restrict__ fW2, const float* __restrict__ fb2,
    float* __restrict__ out, int total)
{
    __shared__ float w1s[192], b1s[64], w2s[64];
    __shared__ float sis[BQ * NH];
    __shared__ float b2s;
    const int t = threadIdx.x;
    if (t < 192) w1s[t] = fW1[t];
    else { b1s[t - 192] = fb1[t - 192]; w2s[t - 192] = fW2[t - 192]; }
    sis[t] = sinv[t];
    if (t == 0) b2s = fb2[0];
    __syncthreads();

    const int idx = blockIdx.x * 256 + t;
    if (idx >= total) return;
    const int b = idx / N;

    float c = cosw[idx], e = eucw[idx];
    h8 v = *(const h8*)&scw[(size_t)idx * NH];
    float ls = 0.f;
    #pragma unroll
    for (int h = 0; h < NH; ++h)
        ls += __expf((float)v[h]) * sis[b * NH + h];
    ls *= 0.125f;

    float logit = b2s;
    #pragma unroll
    for (int j = 0; j < 64; ++j) {
        float hj = fmaf(w1s[j*3], c, fmaf(w1s[j*3+1], e, fmaf(w1s[j*3+2], ls, b1s[j])));
        logit = fmaf(w2s[j], fmaxf(hj, 0.f), logit);
    }
    out[idx] = 1.0f / (1.0f + expf(-logit));
}

// --------------------------------------------------------------------------
extern "C" void kernel_launch(void* const* d_in, const int* in_sizes, int n_in,
                              void* d_out, int out_size, void* d_ws, size_t ws_size,
                              hipStream_t stream)
{
    const float* xq   = (const float*)d_in[0];
    const float* xc   = (const float*)d_in[1];
    const float* temp = (const float*)d_in[2];
    const float* qW1  = (const float*)d_in[3];
    const float* qb1  = (const float*)d_in[4];
    const float* qlg  = (const float*)d_in[5];
    const float* qlb  = (const float*)d_in[6];
    const float* qW2  = (const float*)d_in[7];
    const float* qb2  = (const float*)d_in[8];
    const float* kW1  = (const float*)d_in[9];
    const float* kb1  = (const float*)d_in[10];
    const float* klg  = (const float*)d_in[11];
    const float* klb  = (const float*)d_in[12];
    const float* kW2  = (const float*)d_in[13];
    const float* kb2  = (const float*)d_in[14];
    const float* Wio  = (const float*)d_in[15];
    const float* bio  = (const float*)d_in[16];
    const float* fW1  = (const float*)d_in[17];
    const float* fb1  = (const float*)d_in[18];
    const float* fW2  = (const float*)d_in[19];
    const float* fb2  = (const float*)d_in[20];

    const int N = in_sizes[1] / D;

    float* ws   = (float*)d_ws;
    float* qp   = ws;                         // 16384
    float* qv   = qp + BQ * D;                // 16384
    float* q2   = qv + BQ * D;                // 32
    float* qinv = q2 + BQ;                    // 32
    float* sinv = qinv + BQ;                  // 256
    float* sums = sinv + BQ * NH;             // 256
    float* cosw = sums + BQ * NH;             // BQ*N
    float* eucw = cosw + (size_t)BQ * N;      // BQ*N
    float* fend = eucw + (size_t)BQ * N;

    _Float16* hb  = (_Float16*)fend;
    _Float16* W1h = hb;                       // 262144 each
    _Float16* W1l = W1h + D * D;
    _Float16* W2h = W1l + D * D;
    _Float16* W2l = W2h + D * D;
    _Float16* qph = W2l + D * D;              // 16384
    _Float16* qpl = qph + BQ * D;             // 16384
    _Float16* Wt  = qpl + BQ * D;             // 256*512
    _Float16* scw = Wt + BQ * NH * D;         // BQ*N*NH  ([b][n][h])

    qproj_kernel<<<BQ, 256, 0, stream>>>(xq, qW1, qb1, qlg, qlb, qW2, qb2,
                                         Wio, bio, qp, qv, q2, qinv,
                                         qph, qpl);

    wprep_kernel<<<(D * D + 255) / 256, 256, 0, stream>>>(kW1, kW2,
                                                          W1h, W1l, W2h, W2l);

    wtld_kernel<<<BQ * NH, 256, 0, stream>>>(qv, Wio, Wt);

    zero256_kernel<<<1, 256, 0, stream>>>(sums);

    const int nblk = (N + MT - 1) / MT;
    cand_kernel<<<nblk, NT, 0, stream>>>(xc, N,
                                         W1h, W1l, W2h, W2l,
                                         kb1, klg, klb, kb2,
                                         qph, qpl, Wt, q2, qinv, temp,
                                         cosw, eucw, scw, sums);

    inv256_kernel<<<1, 256, 0, stream>>>(sinv, sums);

    const int total = BQ * N;
    final_kernel<<<(total + 255) / 256, 256, 0, stream>>>(cosw, eucw, scw, N, sinv,
                                                          fW1, fb1, fW2, fb2,
                                                          (float*)d_out, total);
}

// Round 16
// 368.651 us; speedup vs baseline: 2.2145x; 1.9307x over previous
//
#include <hip/hip_runtime.h>
#include <math.h>

#define D    512
#define BQ   32
#define NH   8
#define MT   32
#define NT   512   // threads per cand block (8 waves)

typedef _Float16 h2  __attribute__((ext_vector_type(2)));
typedef _Float16 h4v __attribute__((ext_vector_type(4)));
typedef _Float16 h8  __attribute__((ext_vector_type(8)));
typedef float    f4  __attribute__((ext_vector_type(4)));

typedef const __attribute__((address_space(1))) void gas_void;
typedef __attribute__((address_space(3))) void las_void;

__device__ __forceinline__ f4 MF(h8 a, h8 b, f4 c) {
  return __builtin_amdgcn_mfma_f32_16x16x32_f16(a, b, c, 0, 0, 0);
}

__device__ __forceinline__ float erf_fast(float x) {
    float ax = fabsf(x);
    float tt = 1.0f / fmaf(0.3275911f, ax, 1.0f);
    float poly = tt * fmaf(tt, fmaf(tt, fmaf(tt, fmaf(tt, 1.061405429f, -1.453152027f),
                          1.421413741f), -0.284496736f), 0.254829592f);
    float r = 1.0f - poly * __expf(-ax * ax);
    return copysignf(r, x);
}
__device__ __forceinline__ float gelu_fast(float x) {
    return 0.5f * x * (1.0f + erf_fast(x * 0.7071067811865475f));
}
__device__ __forceinline__ float gelu_exact(float x) {
    return 0.5f * x * (1.0f + erff(x * 0.7071067811865475f));
}

// --------------------------------------------------------------------------
// Kernel 1: query path. One block per query row (32 blocks, 256 threads).
// --------------------------------------------------------------------------
__global__ __launch_bounds__(256) void qproj_kernel(
    const float* __restrict__ xq,
    const float* __restrict__ W1, const float* __restrict__ b1,
    const float* __restrict__ lng, const float* __restrict__ lnb,
    const float* __restrict__ W2, const float* __restrict__ b2,
    const float* __restrict__ Wio, const float* __restrict__ bio,
    float* __restrict__ qp, float* __restrict__ qv,
    float* __restrict__ q2o, float* __restrict__ qinvo,
    _Float16* __restrict__ qph)
{
    __shared__ float xs[D];
    __shared__ float hs[D];
    __shared__ float red[16];
    const int t = threadIdx.x;
    const int row = blockIdx.x;

    for (int i = t; i < D; i += 256) xs[i] = xq[row * D + i];
    __syncthreads();

    float a0 = 0.f, a1 = 0.f;
    for (int i = 0; i < D; i += 4) {
        float4 xv = *(const float4*)&xs[i];
        float4 w0 = *(const float4*)&W1[(size_t)t * D + i];
        float4 w1 = *(const float4*)&W1[(size_t)(t + 256) * D + i];
        a0 += xv.x*w0.x + xv.y*w0.y + xv.z*w0.z + xv.w*w0.w;
        a1 += xv.x*w1.x + xv.y*w1.y + xv.z*w1.z + xv.w*w1.w;
    }
    float h0 = a0 + b1[t], h1 = a1 + b1[t + 256];

    float s1 = h0 + h1, s2 = h0*h0 + h1*h1;
    for (int off = 32; off > 0; off >>= 1) { s1 += __shfl_down(s1, off); s2 += __shfl_down(s2, off); }
    if ((t & 63) == 0) { red[t >> 6] = s1; red[(t >> 6) + 4] = s2; }
    __syncthreads();
    if (t == 0) {
        float sa = red[0] + red[1] + red[2] + red[3];
        float sb = red[4] + red[5] + red[6] + red[7];
        float mu = sa / (float)D;
        red[8] = mu;
        red[9] = sb / (float)D - mu * mu;
    }
    __syncthreads();
    float mu = red[8];
    float isd = 1.0f / sqrtf(red[9] + 1e-5f);
    hs[t]       = gelu_exact((h0 - mu) * isd * lng[t]       + lnb[t]);
    hs[t + 256] = gelu_exact((h1 - mu) * isd * lng[t + 256] + lnb[t + 256]);
    __syncthreads();

    a0 = 0.f; a1 = 0.f;
    for (int i = 0; i < D; i += 4) {
        float4 gv = *(const float4*)&hs[i];
        float4 w0 = *(const float4*)&W2[(size_t)t * D + i];
        float4 w1 = *(const float4*)&W2[(size_t)(t + 256) * D + i];
        a0 += gv.x*w0.x + gv.y*w0.y + gv.z*w0.z + gv.w*w0.w;
        a1 += gv.x*w1.x + gv.y*w1.y + gv.z*w1.z + gv.w*w1.w;
    }
    float p0 = a0 + b2[t], p1 = a1 + b2[t + 256];
    qp[row * D + t] = p0;
    qp[row * D + t + 256] = p1;
    qph[row * D + t]       = (_Float16)(p0 * 32.0f);
    qph[row * D + t + 256] = (_Float16)(p1 * 32.0f);
    __syncthreads();
    xs[t] = p0; xs[t + 256] = p1;

    s1 = p0*p0 + p1*p1;
    for (int off = 32; off > 0; off >>= 1) s1 += __shfl_down(s1, off);
    if ((t & 63) == 0) red[t >> 6] = s1;
    __syncthreads();
    if (t == 0) {
        float sa = red[0] + red[1] + red[2] + red[3];
        q2o[row] = sa;
        qinvo[row] = 1.0f / sqrtf(sa);
    }
    __syncthreads();

    a0 = 0.f; a1 = 0.f;
    for (int i = 0; i < D; i += 4) {
        float4 pv = *(const float4*)&xs[i];
        float4 w0 = *(const float4*)&Wio[(size_t)t * D + i];
        float4 w1 = *(const float4*)&Wio[(size_t)(t + 256) * D + i];
        a0 += pv.x*w0.x + pv.y*w0.y + pv.z*w0.z + pv.w*w0.w;
        a1 += pv.x*w1.x + pv.y*w1.y + pv.z*w1.z + pv.w*w1.w;
    }
    qv[row * D + t]       = a0 + bio[t];
    qv[row * D + t + 256] = a1 + bio[t + 256];
}

// --------------------------------------------------------------------------
// Weight prep: single fp16 of 32*W for W1, W2.
// --------------------------------------------------------------------------
__global__ __launch_bounds__(256) void wprep_kernel(
    const float* __restrict__ W1, const float* __restrict__ W2,
    _Float16* __restrict__ W1m, _Float16* __restrict__ W2m)
{
    int idx = blockIdx.x * 256 + threadIdx.x;
    if (idx >= D * D) return;
    W1m[idx] = (_Float16)(W1[idx] * 32.0f);
    W2m[idx] = (_Float16)(W2[idx] * 32.0f);
}

// --------------------------------------------------------------------------
// W-tilde prep: Wt[b,h,:] = (1/8) * sum_d qv[b, h*64+d] * Wk[h*64+d, :]
// --------------------------------------------------------------------------
__global__ __launch_bounds__(256) void wtld_kernel(
    const float* __restrict__ qv, const float* __restrict__ Wio,
    _Float16* __restrict__ Wt)
{
    __shared__ float qs[64];
    const int bh = blockIdx.x, b = bh >> 3, h = bh & 7;
    const int t = threadIdx.x;
    if (t < 64) qs[t] = qv[b * D + h * 64 + t] * 0.125f;
    __syncthreads();
    const float* Wk = Wio + (size_t)D * D + (size_t)(h * 64) * D;
    float a0 = 0.f, a1 = 0.f;
    #pragma unroll 4
    for (int d = 0; d < 64; ++d) {
        float q = qs[d];
        a0 += q * Wk[(size_t)d * D + t];
        a1 += q * Wk[(size_t)d * D + t + 256];
    }
    Wt[(size_t)bh * D + t]       = (_Float16)a0;
    Wt[(size_t)bh * D + t + 256] = (_Float16)a1;
}

// --------------------------------------------------------------------------
// Tiny helpers.
// --------------------------------------------------------------------------
__global__ __launch_bounds__(256) void zero256_kernel(float* __restrict__ p)
{
    p[threadIdx.x] = 0.0f;
}
__global__ __launch_bounds__(256) void inv256_kernel(
    float* __restrict__ sinv, const float* __restrict__ sums)
{
    sinv[threadIdx.x] = 1.0f / sums[threadIdx.x];
}

// --------------------------------------------------------------------------
// Kernel 2: candidate path. 32 rows/block, 512 threads (8 waves).
// Single-fp16 weights/activations. gll weight pipeline, 2-ahead wave-private
// double buffer, counted vmcnt(4). Scores: gll-staged Wt, 4-buf, 3-ahead.
// --------------------------------------------------------------------------
__global__ __launch_bounds__(NT) void cand_kernel(
    const float* __restrict__ xc, int N,
    const _Float16* __restrict__ W1m, const _Float16* __restrict__ W2m,
    const float* __restrict__ b1, const float* __restrict__ lng,
    const float* __restrict__ lnb, const float* __restrict__ b2,
    const _Float16* __restrict__ qph,
    const _Float16* __restrict__ Wt,
    const float* __restrict__ q2, const float* __restrict__ qinv,
    const float* __restrict__ tempp,
    float* __restrict__ cosw, float* __restrict__ eucw,
    _Float16* __restrict__ scw, float* __restrict__ sums)
{
    __shared__ _Float16 AH[MT * D];                      // 32 KB (swizzled); reused as SC
    __shared__ __align__(16) unsigned char WBUF[65536];  // weight staging
    __shared__ float dotp_[2 * MT * 33];                 // 8.4 KB
    __shared__ float k2p_[8 * MT];
    __shared__ float k2s_[MT], kins_[MT];
    __shared__ float2 lnred_[8 * MT];
    __shared__ float lnmu_[MT], lnisd_[MT];

    const int t    = threadIdx.x;
    const int wave = t >> 6;
    const int lane = t & 63;
    const int l16  = lane & 15;
    const int lK   = lane >> 4;
    const int wcol = wave * 64;
    const int n0   = blockIdx.x * MT;
    const int nvalid = min(MT, N - n0);
    const float expT = expf(tempp[0]);
    const float INVS = 1.0f / 1024.0f;
    const f4 fz = {0.f, 0.f, 0.f, 0.f};

    // ---- stage X (nt loads; scaled x32, fp16 single, swizzled) ----
    #pragma unroll
    for (int i = 0; i < 8; ++i) {
        int g = t + NT * i;
        int row = g >> 7;
        int c4 = (g & 127) * 4;
        f4 v = fz;
        if (n0 + row < N)
            v = __builtin_nontemporal_load((const f4*)(xc + (size_t)(n0 + row) * D + c4));
        h4v hi;
        #pragma unroll
        for (int e = 0; e < 4; ++e) hi[e] = (_Float16)(v[e] * 32.0f);
        *(h4v*)&AH[row * D + (c4 ^ ((row & 7) << 3))] = hi;
    }
    __syncthreads();                                           // #1

    const int sw = (l16 & 7) << 3;
    const int r0 = l16 * D, r1 = (l16 + 16) * D;

    auto stageW = [&](const _Float16* __restrict__ Wm, int c, int buf) {
        #pragma unroll
        for (int j = 0; j < 4; ++j) {
            const int col  = (wave * 4 + j) * 16 + (lane >> 2);
            const int slot = (lane & 3) ^ ((col >> 1) & 3);
            const _Float16* src = Wm + (size_t)col * D + c * 32 + slot * 8;
            las_void* dst = (las_void*)(WBUF + buf * 32768 + wave * 4096 + j * 1024);
            __builtin_amdgcn_global_load_lds((gas_void*)src, dst, 16, 0, 0);
        }
    };

    // Single-product GEMM with 2-ahead gll pipeline (wave-private buffers).
    auto gemm = [&](const _Float16* __restrict__ Wm, f4 (&acc)[2][4]) {
        stageW(Wm, 0, 0);
        stageW(Wm, 1, 1);
        #pragma unroll 1
        for (int c = 0; c < 16; ++c) {
            const int buf = c & 1;
            if (c < 15) asm volatile("s_waitcnt vmcnt(4)" ::: "memory");
            else        asm volatile("s_waitcnt vmcnt(0)" ::: "memory");
            __builtin_amdgcn_sched_barrier(0);
            const unsigned char* wb = WBUF + buf * 32768;
            h8 bh[4];
            #pragma unroll
            for (int cb = 0; cb < 4; ++cb) {
                const int col = wcol + cb * 16 + l16;
                bh[cb] = *(const h8*)(wb + col * 64 + ((lK ^ ((col >> 1) & 3)) << 4));
            }
            const int ksw = (c * 32 + lK * 8) ^ sw;
            h8 ah0 = *(const h8*)&AH[r0 + ksw];
            h8 ah1 = *(const h8*)&AH[r1 + ksw];
            asm volatile("s_waitcnt lgkmcnt(0)" ::: "memory");
            __builtin_amdgcn_sched_barrier(0);
            if (c < 14) stageW(Wm, c + 2, buf);
            __builtin_amdgcn_sched_barrier(0);
            #pragma unroll
            for (int cb = 0; cb < 4; ++cb) {
                acc[0][cb] = MF(ah0, bh[cb], acc[0][cb]);
                acc[1][cb] = MF(ah1, bh[cb], acc[1][cb]);
            }
        }
    };

    f4 acc[2][4];
    #pragma unroll
    for (int rb = 0; rb < 2; ++rb)
        #pragma unroll
        for (int cb = 0; cb < 4; ++cb) acc[rb][cb] = fz;

    // ---- GEMM1: h = x @ W1.T + b1 ----
    gemm(W1m, acc);

    float s1a[2][4], s2a[2][4];
    #pragma unroll
    for (int rb = 0; rb < 2; ++rb)
        #pragma unroll
        for (int r = 0; r < 4; ++r) { s1a[rb][r] = 0.f; s2a[rb][r] = 0.f; }
    #pragma unroll
    for (int rb = 0; rb < 2; ++rb)
        #pragma unroll
        for (int cb = 0; cb < 4; ++cb) {
            const int j = wcol + cb * 16 + l16;
            const float bb = b1[j];
            #pragma unroll
            for (int r = 0; r < 4; ++r) {
                float v = acc[rb][cb][r] * INVS + bb;
                acc[rb][cb][r] = v;
                s1a[rb][r] += v;
                s2a[rb][r] += v * v;
            }
        }
    #pragma unroll
    for (int mm = 1; mm < 16; mm <<= 1)
        #pragma unroll
        for (int rb = 0; rb < 2; ++rb)
            #pragma unroll
            for (int r = 0; r < 4; ++r) {
                s1a[rb][r] += __shfl_xor(s1a[rb][r], mm);
                s2a[rb][r] += __shfl_xor(s2a[rb][r], mm);
            }
    if (l16 == 0) {
        #pragma unroll
        for (int rb = 0; rb < 2; ++rb)
            #pragma unroll
            for (int r = 0; r < 4; ++r)
                lnred_[wave * MT + rb * 16 + lK * 4 + r] = make_float2(s1a[rb][r], s2a[rb][r]);
    }
    __syncthreads();                                           // #2
    if (t < MT) {
        float sa = 0.f, sb = 0.f;
        #pragma unroll
        for (int w = 0; w < 8; ++w) { sa += lnred_[w * MT + t].x; sb += lnred_[w * MT + t].y; }
        float mu = sa * (1.0f / 512.0f);
        float var = sb * (1.0f / 512.0f) - mu * mu;
        lnmu_[t] = mu;
        lnisd_[t] = rsqrtf(var + 1e-5f);
    }
    __syncthreads();                                           // #3

    // ---- LN + GELU in regs, convert g (fp16 single) -> AH ----
    #pragma unroll
    for (int rb = 0; rb < 2; ++rb)
        #pragma unroll
        for (int cb = 0; cb < 4; ++cb) {
            const int j = wcol + cb * 16 + l16;
            const float gg = lng[j], bb = lnb[j];
            #pragma unroll
            for (int r = 0; r < 4; ++r) {
                const int m = rb * 16 + lK * 4 + r;
                float v = (acc[rb][cb][r] - lnmu_[m]) * lnisd_[m] * gg + bb;
                v = gelu_fast(v) * 32.0f;
                AH[m * D + (j ^ ((m & 7) << 3))] = (_Float16)v;
            }
        }
    __syncthreads();                                           // #4

    // ---- GEMM2: kp = g @ W2.T + b2 ----
    #pragma unroll
    for (int rb = 0; rb < 2; ++rb)
        #pragma unroll
        for (int cb = 0; cb < 4; ++cb) acc[rb][cb] = fz;
    gemm(W2m, acc);

    float ss[2][4];
    #pragma unroll
    for (int rb = 0; rb < 2; ++rb)
        #pragma unroll
        for (int r = 0; r < 4; ++r) ss[rb][r] = 0.f;
    #pragma unroll
    for (int rb = 0; rb < 2; ++rb)
        #pragma unroll
        for (int cb = 0; cb < 4; ++cb) {
            const int j = wcol + cb * 16 + l16;
            const float bb = b2[j];
            #pragma unroll
            for (int r = 0; r < 4; ++r) {
                float v = acc[rb][cb][r] * INVS + bb;
                acc[rb][cb][r] = v;
                ss[rb][r] += v * v;
            }
        }
    #pragma unroll
    for (int mm = 1; mm < 16; mm <<= 1)
        #pragma unroll
        for (int rb = 0; rb < 2; ++rb)
            #pragma unroll
            for (int r = 0; r < 4; ++r)
                ss[rb][r] += __shfl_xor(ss[rb][r], mm);
    __syncthreads();                                           // #5 (GEMM2 AH reads done)
    if (l16 == 0) {
        #pragma unroll
        for (int rb = 0; rb < 2; ++rb)
            #pragma unroll
            for (int r = 0; r < 4; ++r)
                k2p_[wave * MT + rb * 16 + lK * 4 + r] = ss[rb][r];
    }
    // convert kp (x32, fp16 single) -> AH
    #pragma unroll
    for (int rb = 0; rb < 2; ++rb)
        #pragma unroll
        for (int cb = 0; cb < 4; ++cb) {
            const int j = wcol + cb * 16 + l16;
            #pragma unroll
            for (int r = 0; r < 4; ++r) {
                const int m = rb * 16 + lK * 4 + r;
                AH[m * D + (j ^ ((m & 7) << 3))] = (_Float16)(acc[rb][cb][r] * 32.0f);
            }
        }
    __syncthreads();                                           // #6

    if (t < MT) {
        float sa = 0.f;
        #pragma unroll
        for (int w = 0; w < 8; ++w) sa += k2p_[w * MT + t];
        k2s_[t] = sa;
        kins_[t] = rsqrtf(fmaxf(sa, 1e-30f));
    }

    // ---- scores: kp_hi @ Wt.T via gll-staged Wt (4-buf rotation, 3-ahead) ----
    f4 as[2][2];
    as[0][0] = fz; as[0][1] = fz; as[1][0] = fz; as[1][1] = fz;
    {
        auto stageWT = [&](int c, int buf) {
            #pragma unroll
            for (int j = 0; j < 2; ++j) {
                const int rr   = j * 16 + (lane >> 2);
                const int slot = (lane & 3) ^ ((rr >> 1) & 3);
                const _Float16* src = Wt + (size_t)(wave * 32 + rr) * D + c * 32 + slot * 8;
                las_void* dst = (las_void*)(WBUF + buf * 16384 + wave * 2048 + j * 1024);
                __builtin_amdgcn_global_load_lds((gas_void*)src, dst, 16, 0, 0);
            }
        };
        auto scoreChunk = [&](int c, int buf) {
            const unsigned char* wb = WBUF + buf * 16384 + wave * 2048;
            h8 w0 = *(const h8*)(wb + l16 * 64 + ((lK ^ ((l16 >> 1) & 3)) << 4));
            h8 w1 = *(const h8*)(wb + 1024 + l16 * 64 + ((lK ^ ((l16 >> 1) & 3)) << 4));
            const int ksw = (c * 32 + lK * 8) ^ sw;
            h8 a0 = *(const h8*)&AH[r0 + ksw];
            h8 a1 = *(const h8*)&AH[r1 + ksw];
            as[0][0] = MF(a0, w0, as[0][0]);
            as[0][1] = MF(a0, w1, as[0][1]);
            as[1][0] = MF(a1, w0, as[1][0]);
            as[1][1] = MF(a1, w1, as[1][1]);
        };
        stageWT(0, 0); stageWT(1, 1); stageWT(2, 2);
        #pragma unroll 4
        for (int c = 0; c < 12; ++c) {
            asm volatile("s_waitcnt vmcnt(4)" ::: "memory");
            __builtin_amdgcn_sched_barrier(0);
            scoreChunk(c, c & 3);
            __builtin_amdgcn_sched_barrier(0);
            stageWT(c + 3, (c + 3) & 3);
            __builtin_amdgcn_sched_barrier(0);
        }
        asm volatile("s_waitcnt vmcnt(4)" ::: "memory");
        __builtin_amdgcn_sched_barrier(0);
        scoreChunk(12, 0);
        __builtin_amdgcn_sched_barrier(0);
        stageWT(15, 3);
        __builtin_amdgcn_sched_barrier(0);
        asm volatile("s_waitcnt vmcnt(4)" ::: "memory");
        __builtin_amdgcn_sched_barrier(0);
        scoreChunk(13, 1);
        asm volatile("s_waitcnt vmcnt(2)" ::: "memory");
        __builtin_amdgcn_sched_barrier(0);
        scoreChunk(14, 2);
        asm volatile("s_waitcnt vmcnt(0)" ::: "memory");
        __builtin_amdgcn_sched_barrier(0);
        scoreChunk(15, 3);
    }

    // ---- fused softmax-denominator partial sums ----
    {
        float part[2] = {0.f, 0.f};
        #pragma unroll
        for (int cb = 0; cb < 2; ++cb)
            #pragma unroll
            for (int rb = 0; rb < 2; ++rb)
                #pragma unroll
                for (int r = 0; r < 4; ++r) {
                    const int n = rb * 16 + lK * 4 + r;
                    if (n < nvalid)
                        part[cb] += __expf(as[rb][cb][r] * (1.0f / 32.0f));
                }
        #pragma unroll
        for (int cb = 0; cb < 2; ++cb) {
            part[cb] += __shfl_xor(part[cb], 16);
            part[cb] += __shfl_xor(part[cb], 32);
        }
        if (lK == 0) {
            atomicAdd(&sums[wave * 32 + l16], part[0]);
            atomicAdd(&sums[wave * 32 + 16 + l16], part[1]);
        }
    }

    // ---- dots = kp @ qp.T via MFMA (8 waves = 2 rh x 2 kh x 2 cbq) ----
    {
        const int rh = wave >> 2, kh = (wave >> 1) & 1, cbq = wave & 1;
        f4 ad = fz;
        const int ra = (rh * 16 + l16) * D;
        const int j = cbq * 16 + l16;
        #pragma unroll 2
        for (int ks = 0; ks < 8; ++ks) {
            const int k0 = kh * 256 + ks * 32 + lK * 8;
            const int ksw = k0 ^ sw;
            h8 ah0 = *(const h8*)&AH[ra + ksw];
            h8 bh = *(const h8*)&qph[j * D + k0];
            ad = MF(ah0, bh, ad);
        }
        #pragma unroll
        for (int r = 0; r < 4; ++r)
            dotp_[(kh * MT + rh * 16 + lK * 4 + r) * 33 + cbq * 16 + l16] = ad[r];
    }
    __syncthreads();                                           // #7

    // ---- cos / euc outputs (nt stores) ----
    for (int p = t; p < BQ * MT; p += NT) {
        const int m = p & (MT - 1), b = p >> 5;
        if (m < nvalid) {
            float dt = (dotp_[(0 * MT + m) * 33 + b] + dotp_[(1 * MT + m) * 33 + b]) * INVS;
            __builtin_nontemporal_store(dt * qinv[b] * kins_[m] * expT,
                                        &cosw[(size_t)b * N + n0 + m]);
            float dd = q2[b] + k2s_[m] - 2.0f * dt;
            __builtin_nontemporal_store(1.0f / (1.0f + sqrtf(fmaxf(dd, 0.f))),
                                        &eucw[(size_t)b * N + n0 + m]);
        }
    }

    // ---- scores -> SC (overlay AH, dead after #7), then coalesced out ----
    _Float16* SC = AH;   // element layout: n*256 + (b ^ (n&31))*8 + h
    {
        const int bh0 = wave * 32 + l16;
        #pragma unroll
        for (int cb = 0; cb < 2; ++cb) {
            const int bhc = bh0 + cb * 16;
            const int b = bhc >> 3, h = bhc & 7;
            #pragma unroll
            for (int rb = 0; rb < 2; ++rb) {
                #pragma unroll
                for (int r = 0; r < 4; ++r) {
                    const int n = rb * 16 + lK * 4 + r;
                    SC[n * 256 + ((b ^ (n & 31)) * 8) + h] =
                        (_Float16)(as[rb][cb][r] * (1.0f / 32.0f));
                }
            }
        }
    }
    __syncthreads();                                           // #8

    #pragma unroll
    for (int p = t; p < BQ * MT; p += NT) {
        const int b = p >> 5, n = p & (MT - 1);
        if (n < nvalid) {
            h8 v = *(const h8*)&SC[n * 256 + ((b ^ (n & 31)) * 8)];
            __builtin_nontemporal_store(v, (h8*)&scw[((size_t)b * N + n0 + n) * NH]);
        }
    }
}

// --------------------------------------------------------------------------
// Kernel 4: learned_sim + fused 3->64->1 MLP + sigmoid per (b,n).
// --------------------------------------------------------------------------
__global__ __launch_bounds__(256) void final_kernel(
    const float* __restrict__ cosw, const float* __restrict__ eucw,
    const _Float16* __restrict__ scw, int N,
    const float* __restrict__ sinv,
    const float* __restrict__ fW1, const float* __restrict__ fb1,
    const float* __restrict__ fW2, const float* __restrict__ fb2,
    float* __restrict__ out, int total)
{
    __shared__ float w1s[192], b1s[64], w2s[64];
    __shared__ float sis[BQ * NH];
    __shared__ float b2s;
    const int t = threadIdx.x;
    if (t < 192) w1s[t] = fW1[t];
    else { b1s[t - 192] = fb1[t - 192]; w2s[t - 192] = fW2[t - 192]; }
    sis[t] = sinv[t];
    if (t == 0) b2s = fb2[0];
    __syncthreads();

    const int idx = blockIdx.x * 256 + t;
    if (idx >= total) return;
    const int b = idx / N;

    float c = cosw[idx], e = eucw[idx];
    h8 v = *(const h8*)&scw[(size_t)idx * NH];
    float ls = 0.f;
    #pragma unroll
    for (int h = 0; h < NH; ++h)
        ls += __expf((float)v[h]) * sis[b * NH + h];
    ls *= 0.125f;

    float logit = b2s;
    #pragma unroll
    for (int j = 0; j < 64; ++j) {
        float hj = fmaf(w1s[j*3], c, fmaf(w1s[j*3+1], e, fmaf(w1s[j*3+2], ls, b1s[j])));
        logit = fmaf(w2s[j], fmaxf(hj, 0.f), logit);
    }
    out[idx] = 1.0f / (1.0f + expf(-logit));
}

// --------------------------------------------------------------------------
extern "C" void kernel_launch(void* const* d_in, const int* in_sizes, int n_in,
                              void* d_out, int out_size, void* d_ws, size_t ws_size,
                              hipStream_t stream)
{
    const float* xq   = (const float*)d_in[0];
    const float* xc   = (const float*)d_in[1];
    const float* temp = (const float*)d_in[2];
    const float* qW1  = (const float*)d_in[3];
    const float* qb1  = (const float*)d_in[4];
    const float* qlg  = (const float*)d_in[5];
    const float* qlb  = (const float*)d_in[6];
    const float* qW2  = (const float*)d_in[7];
    const float* qb2  = (const float*)d_in[8];
    const float* kW1  = (const float*)d_in[9];
    const float* kb1  = (const float*)d_in[10];
    const float* klg  = (const float*)d_in[11];
    const float* klb  = (const float*)d_in[12];
    const float* kW2  = (const float*)d_in[13];
    const float* kb2  = (const float*)d_in[14];
    const float* Wio  = (const float*)d_in[15];
    const float* bio  = (const float*)d_in[16];
    const float* fW1  = (const float*)d_in[17];
    const float* fb1  = (const float*)d_in[18];
    const float* fW2  = (const float*)d_in[19];
    const float* fb2  = (const float*)d_in[20];

    const int N = in_sizes[1] / D;

    float* ws   = (float*)d_ws;
    float* qp   = ws;                         // 16384
    float* qv   = qp + BQ * D;                // 16384
    float* q2   = qv + BQ * D;                // 32
    float* qinv = q2 + BQ;                    // 32
    float* sinv = qinv + BQ;                  // 256
    float* sums = sinv + BQ * NH;             // 256
    float* cosw = sums + BQ * NH;             // BQ*N
    float* eucw = cosw + (size_t)BQ * N;      // BQ*N
    float* fend = eucw + (size_t)BQ * N;

    _Float16* hb  = (_Float16*)fend;
    _Float16* W1m = hb;                       // 262144 each
    _Float16* W2m = W1m + D * D;
    _Float16* qph = W2m + D * D;              // 16384
    _Float16* Wt  = qph + BQ * D;             // 256*512
    _Float16* scw = Wt + BQ * NH * D;         // BQ*N*NH  ([b][n][h])

    qproj_kernel<<<BQ, 256, 0, stream>>>(xq, qW1, qb1, qlg, qlb, qW2, qb2,
                                         Wio, bio, qp, qv, q2, qinv, qph);

    wprep_kernel<<<(D * D + 255) / 256, 256, 0, stream>>>(kW1, kW2, W1m, W2m);

    wtld_kernel<<<BQ * NH, 256, 0, stream>>>(qv, Wio, Wt);

    zero256_kernel<<<1, 256, 0, stream>>>(sums);

    const int nblk = (N + MT - 1) / MT;
    cand_kernel<<<nblk, NT, 0, stream>>>(xc, N, W1m, W2m,
                                         kb1, klg, klb, kb2,
                                         qph, Wt, q2, qinv, temp,
                                         cosw, eucw, scw, sums);

    inv256_kernel<<<1, 256, 0, stream>>>(sinv, sums);

    const int total = BQ * N;
    final_kernel<<<(total + 255) / 256, 256, 0, stream>>>(cosw, eucw, scw, N, sinv,
                                                          fW1, fb1, fW2, fb2,
                                                          (float*)d_out, total);
}

// Round 17
// 366.922 us; speedup vs baseline: 2.2249x; 1.0047x over previous
//
#include <hip/hip_runtime.h>
#include <math.h>

#define D    512
#define BQ   32
#define NH   8
#define MT   32
#define NT   512   // threads per cand block (8 waves)

typedef _Float16 h2  __attribute__((ext_vector_type(2)));
typedef _Float16 h4v __attribute__((ext_vector_type(4)));
typedef _Float16 h8  __attribute__((ext_vector_type(8)));
typedef float    f4  __attribute__((ext_vector_type(4)));

typedef const __attribute__((address_space(1))) void gas_void;
typedef __attribute__((address_space(3))) void las_void;

__device__ __forceinline__ f4 MF(h8 a, h8 b, f4 c) {
  return __builtin_amdgcn_mfma_f32_16x16x32_f16(a, b, c, 0, 0, 0);
}

__device__ __forceinline__ float erf_fast(float x) {
    float ax = fabsf(x);
    float tt = 1.0f / fmaf(0.3275911f, ax, 1.0f);
    float poly = tt * fmaf(tt, fmaf(tt, fmaf(tt, fmaf(tt, 1.061405429f, -1.453152027f),
                          1.421413741f), -0.284496736f), 0.254829592f);
    float r = 1.0f - poly * __expf(-ax * ax);
    return copysignf(r, x);
}
__device__ __forceinline__ float gelu_fast(float x) {
    return 0.5f * x * (1.0f + erf_fast(x * 0.7071067811865475f));
}
__device__ __forceinline__ float gelu_exact(float x) {
    return 0.5f * x * (1.0f + erff(x * 0.7071067811865475f));
}

// --------------------------------------------------------------------------
// Kernel 1: query path. One block per query row (32 blocks, 256 threads).
// --------------------------------------------------------------------------
__global__ __launch_bounds__(256) void qproj_kernel(
    const float* __restrict__ xq,
    const float* __restrict__ W1, const float* __restrict__ b1,
    const float* __restrict__ lng, const float* __restrict__ lnb,
    const float* __restrict__ W2, const float* __restrict__ b2,
    const float* __restrict__ Wio, const float* __restrict__ bio,
    float* __restrict__ qp, float* __restrict__ qv,
    float* __restrict__ q2o, float* __restrict__ qinvo,
    _Float16* __restrict__ qph)
{
    __shared__ float xs[D];
    __shared__ float hs[D];
    __shared__ float red[16];
    const int t = threadIdx.x;
    const int row = blockIdx.x;

    for (int i = t; i < D; i += 256) xs[i] = xq[row * D + i];
    __syncthreads();

    float a0 = 0.f, a1 = 0.f;
    for (int i = 0; i < D; i += 4) {
        float4 xv = *(const float4*)&xs[i];
        float4 w0 = *(const float4*)&W1[(size_t)t * D + i];
        float4 w1 = *(const float4*)&W1[(size_t)(t + 256) * D + i];
        a0 += xv.x*w0.x + xv.y*w0.y + xv.z*w0.z + xv.w*w0.w;
        a1 += xv.x*w1.x + xv.y*w1.y + xv.z*w1.z + xv.w*w1.w;
    }
    float h0 = a0 + b1[t], h1 = a1 + b1[t + 256];

    float s1 = h0 + h1, s2 = h0*h0 + h1*h1;
    for (int off = 32; off > 0; off >>= 1) { s1 += __shfl_down(s1, off); s2 += __shfl_down(s2, off); }
    if ((t & 63) == 0) { red[t >> 6] = s1; red[(t >> 6) + 4] = s2; }
    __syncthreads();
    if (t == 0) {
        float sa = red[0] + red[1] + red[2] + red[3];
        float sb = red[4] + red[5] + red[6] + red[7];
        float mu = sa / (float)D;
        red[8] = mu;
        red[9] = sb / (float)D - mu * mu;
    }
    __syncthreads();
    float mu = red[8];
    float isd = 1.0f / sqrtf(red[9] + 1e-5f);
    hs[t]       = gelu_exact((h0 - mu) * isd * lng[t]       + lnb[t]);
    hs[t + 256] = gelu_exact((h1 - mu) * isd * lng[t + 256] + lnb[t + 256]);
    __syncthreads();

    a0 = 0.f; a1 = 0.f;
    for (int i = 0; i < D; i += 4) {
        float4 gv = *(const float4*)&hs[i];
        float4 w0 = *(const float4*)&W2[(size_t)t * D + i];
        float4 w1 = *(const float4*)&W2[(size_t)(t + 256) * D + i];
        a0 += gv.x*w0.x + gv.y*w0.y + gv.z*w0.z + gv.w*w0.w;
        a1 += gv.x*w1.x + gv.y*w1.y + gv.z*w1.z + gv.w*w1.w;
    }
    float p0 = a0 + b2[t], p1 = a1 + b2[t + 256];
    qp[row * D + t] = p0;
    qp[row * D + t + 256] = p1;
    qph[row * D + t]       = (_Float16)(p0 * 32.0f);
    qph[row * D + t + 256] = (_Float16)(p1 * 32.0f);
    __syncthreads();
    xs[t] = p0; xs[t + 256] = p1;

    s1 = p0*p0 + p1*p1;
    for (int off = 32; off > 0; off >>= 1) s1 += __shfl_down(s1, off);
    if ((t & 63) == 0) red[t >> 6] = s1;
    __syncthreads();
    if (t == 0) {
        float sa = red[0] + red[1] + red[2] + red[3];
        q2o[row] = sa;
        qinvo[row] = 1.0f / sqrtf(sa);
    }
    __syncthreads();

    a0 = 0.f; a1 = 0.f;
    for (int i = 0; i < D; i += 4) {
        float4 pv = *(const float4*)&xs[i];
        float4 w0 = *(const float4*)&Wio[(size_t)t * D + i];
        float4 w1 = *(const float4*)&Wio[(size_t)(t + 256) * D + i];
        a0 += pv.x*w0.x + pv.y*w0.y + pv.z*w0.z + pv.w*w0.w;
        a1 += pv.x*w1.x + pv.y*w1.y + pv.z*w1.z + pv.w*w1.w;
    }
    qv[row * D + t]       = a0 + bio[t];
    qv[row * D + t + 256] = a1 + bio[t + 256];
}

// --------------------------------------------------------------------------
// Weight prep: single fp16 of 32*W for W1, W2. Block 0 also zeroes sums.
// --------------------------------------------------------------------------
__global__ __launch_bounds__(256) void wprep_kernel(
    const float* __restrict__ W1, const float* __restrict__ W2,
    _Float16* __restrict__ W1m, _Float16* __restrict__ W2m,
    float* __restrict__ sums)
{
    int idx = blockIdx.x * 256 + threadIdx.x;
    if (blockIdx.x == 0) sums[threadIdx.x] = 0.0f;
    if (idx >= D * D) return;
    W1m[idx] = (_Float16)(W1[idx] * 32.0f);
    W2m[idx] = (_Float16)(W2[idx] * 32.0f);
}

// --------------------------------------------------------------------------
// W-tilde prep: Wt[b,h,:] = (1/8) * sum_d qv[b, h*64+d] * Wk[h*64+d, :]
// --------------------------------------------------------------------------
__global__ __launch_bounds__(256) void wtld_kernel(
    const float* __restrict__ qv, const float* __restrict__ Wio,
    _Float16* __restrict__ Wt)
{
    __shared__ float qs[64];
    const int bh = blockIdx.x, b = bh >> 3, h = bh & 7;
    const int t = threadIdx.x;
    if (t < 64) qs[t] = qv[b * D + h * 64 + t] * 0.125f;
    __syncthreads();
    const float* Wk = Wio + (size_t)D * D + (size_t)(h * 64) * D;
    float a0 = 0.f, a1 = 0.f;
    #pragma unroll 4
    for (int d = 0; d < 64; ++d) {
        float q = qs[d];
        a0 += q * Wk[(size_t)d * D + t];
        a1 += q * Wk[(size_t)d * D + t + 256];
    }
    Wt[(size_t)bh * D + t]       = (_Float16)a0;
    Wt[(size_t)bh * D + t + 256] = (_Float16)a1;
}

// --------------------------------------------------------------------------
// Kernel 2: candidate path. 32 rows/block, 512 threads (8 waves).
// Single-fp16 weights; 3-buffer gll rotation (no per-chunk LDS drain,
// 3-chunk latency window); hoisted staging/read addresses.
// --------------------------------------------------------------------------
__global__ __launch_bounds__(NT) void cand_kernel(
    const float* __restrict__ xc, int N,
    const _Float16* __restrict__ W1m, const _Float16* __restrict__ W2m,
    const float* __restrict__ b1, const float* __restrict__ lng,
    const float* __restrict__ lnb, const float* __restrict__ b2,
    const _Float16* __restrict__ qph,
    const _Float16* __restrict__ Wt,
    const float* __restrict__ q2, const float* __restrict__ qinv,
    const float* __restrict__ tempp,
    float* __restrict__ cosw, float* __restrict__ eucw,
    _Float16* __restrict__ scw, float* __restrict__ sums)
{
    __shared__ _Float16 AH[MT * D];                      // 32 KB (swizzled); reused as SC
    __shared__ __align__(16) unsigned char WBUF[98304];  // 3 x 32 KB weight staging
    __shared__ float dotp_[2 * MT * 33];                 // 8.4 KB
    __shared__ float k2p_[8 * MT];
    __shared__ float k2s_[MT], kins_[MT];
    __shared__ float2 lnred_[8 * MT];
    __shared__ float lnmu_[MT], lnisd_[MT];

    const int t    = threadIdx.x;
    const int wave = t >> 6;
    const int lane = t & 63;
    const int l16  = lane & 15;
    const int lK   = lane >> 4;
    const int wcol = wave * 64;
    const int n0   = blockIdx.x * MT;
    const int nvalid = min(MT, N - n0);
    const float expT = expf(tempp[0]);
    const float INVS = 1.0f / 1024.0f;
    const f4 fz = {0.f, 0.f, 0.f, 0.f};

    // ---- stage X (nt loads; scaled x32, fp16 single, swizzled) ----
    #pragma unroll
    for (int i = 0; i < 8; ++i) {
        int g = t + NT * i;
        int row = g >> 7;
        int c4 = (g & 127) * 4;
        f4 v = fz;
        if (n0 + row < N)
            v = __builtin_nontemporal_load((const f4*)(xc + (size_t)(n0 + row) * D + c4));
        h4v hi;
        #pragma unroll
        for (int e = 0; e < 4; ++e) hi[e] = (_Float16)(v[e] * 32.0f);
        *(h4v*)&AH[row * D + (c4 ^ ((row & 7) << 3))] = hi;
    }
    __syncthreads();                                           // #1

    const int sw = (l16 & 7) << 3;
    const int r0 = l16 * D, r1 = (l16 + 16) * D;

    // hoisted LDS read offsets for the weight fragments (chunk-invariant)
    unsigned rdO[4];
    #pragma unroll
    for (int cb = 0; cb < 4; ++cb) {
        const int col = wcol + cb * 16 + l16;
        rdO[cb] = (unsigned)(col * 64 + ((lK ^ ((col >> 1) & 3)) << 4));
    }
    // hoisted staging dst offsets (chunk-invariant; buf adds 32KB strides)
    unsigned dstO[4];
    #pragma unroll
    for (int j = 0; j < 4; ++j) dstO[j] = (unsigned)(wave * 4096 + j * 1024);

    // 3-buffer single-product GEMM
    auto gemm = [&](const _Float16* __restrict__ Wm, f4 (&acc)[2][4]) {
        const _Float16* srcB[4];
        #pragma unroll
        for (int j = 0; j < 4; ++j) {
            const int col  = (wave * 4 + j) * 16 + (lane >> 2);
            const int slot = (lane & 3) ^ ((col >> 1) & 3);
            srcB[j] = Wm + (size_t)col * D + slot * 8;
        }
        auto stage = [&](int c, int buf) {
            #pragma unroll
            for (int j = 0; j < 4; ++j)
                __builtin_amdgcn_global_load_lds((gas_void*)(srcB[j] + c * 32),
                    (las_void*)(WBUF + buf * 32768 + dstO[j]), 16, 0, 0);
        };
        auto compute = [&](int c, int buf) {
            const unsigned char* wb = WBUF + buf * 32768;
            h8 bh[4];
            #pragma unroll
            for (int cb = 0; cb < 4; ++cb) bh[cb] = *(const h8*)(wb + rdO[cb]);
            const int ksw = (c * 32 + lK * 8) ^ sw;
            h8 ah0 = *(const h8*)&AH[r0 + ksw];
            h8 ah1 = *(const h8*)&AH[r1 + ksw];
            #pragma unroll
            for (int cb = 0; cb < 4; ++cb) {
                acc[0][cb] = MF(ah0, bh[cb], acc[0][cb]);
                acc[1][cb] = MF(ah1, bh[cb], acc[1][cb]);
            }
        };
        stage(0, 0); stage(1, 1); stage(2, 2);
        #pragma unroll 1
        for (int c = 0; c < 13; ++c) {
            const int buf = c % 3;                          // uniform (SALU)
            asm volatile("s_waitcnt vmcnt(8)" ::: "memory"); // drain chunk c only
            __builtin_amdgcn_sched_barrier(0);
            compute(c, buf);
            asm volatile("s_waitcnt lgkmcnt(0)" ::: "memory"); // ~free here
            __builtin_amdgcn_sched_barrier(0);
            stage(c + 3, buf);                               // buffer idle 3 chunks
            __builtin_amdgcn_sched_barrier(0);
        }
        asm volatile("s_waitcnt vmcnt(8)" ::: "memory");
        __builtin_amdgcn_sched_barrier(0);
        compute(13, 1);
        asm volatile("s_waitcnt vmcnt(4)" ::: "memory");
        __builtin_amdgcn_sched_barrier(0);
        compute(14, 2);
        asm volatile("s_waitcnt vmcnt(0)" ::: "memory");
        __builtin_amdgcn_sched_barrier(0);
        compute(15, 0);
    };

    f4 acc[2][4];
    #pragma unroll
    for (int rb = 0; rb < 2; ++rb)
        #pragma unroll
        for (int cb = 0; cb < 4; ++cb) acc[rb][cb] = fz;

    // ---- GEMM1: h = x @ W1.T + b1 ----
    gemm(W1m, acc);

    float s1a[2][4], s2a[2][4];
    #pragma unroll
    for (int rb = 0; rb < 2; ++rb)
        #pragma unroll
        for (int r = 0; r < 4; ++r) { s1a[rb][r] = 0.f; s2a[rb][r] = 0.f; }
    #pragma unroll
    for (int rb = 0; rb < 2; ++rb)
        #pragma unroll
        for (int cb = 0; cb < 4; ++cb) {
            const int j = wcol + cb * 16 + l16;
            const float bb = b1[j];
            #pragma unroll
            for (int r = 0; r < 4; ++r) {
                float v = acc[rb][cb][r] * INVS + bb;
                acc[rb][cb][r] = v;
                s1a[rb][r] += v;
                s2a[rb][r] += v * v;
            }
        }
    #pragma unroll
    for (int mm = 1; mm < 16; mm <<= 1)
        #pragma unroll
        for (int rb = 0; rb < 2; ++rb)
            #pragma unroll
            for (int r = 0; r < 4; ++r) {
                s1a[rb][r] += __shfl_xor(s1a[rb][r], mm);
                s2a[rb][r] += __shfl_xor(s2a[rb][r], mm);
            }
    if (l16 == 0) {
        #pragma unroll
        for (int rb = 0; rb < 2; ++rb)
            #pragma unroll
            for (int r = 0; r < 4; ++r)
                lnred_[wave * MT + rb * 16 + lK * 4 + r] = make_float2(s1a[rb][r], s2a[rb][r]);
    }
    __syncthreads();                                           // #2
    if (t < MT) {
        float sa = 0.f, sb = 0.f;
        #pragma unroll
        for (int w = 0; w < 8; ++w) { sa += lnred_[w * MT + t].x; sb += lnred_[w * MT + t].y; }
        float mu = sa * (1.0f / 512.0f);
        float var = sb * (1.0f / 512.0f) - mu * mu;
        lnmu_[t] = mu;
        lnisd_[t] = rsqrtf(var + 1e-5f);
    }
    __syncthreads();                                           // #3

    // ---- LN + GELU in regs, convert g (fp16 single) -> AH ----
    #pragma unroll
    for (int rb = 0; rb < 2; ++rb)
        #pragma unroll
        for (int cb = 0; cb < 4; ++cb) {
            const int j = wcol + cb * 16 + l16;
            const float gg = lng[j], bb = lnb[j];
            #pragma unroll
            for (int r = 0; r < 4; ++r) {
                const int m = rb * 16 + lK * 4 + r;
                float v = (acc[rb][cb][r] - lnmu_[m]) * lnisd_[m] * gg + bb;
                v = gelu_fast(v) * 32.0f;
                AH[m * D + (j ^ ((m & 7) << 3))] = (_Float16)v;
            }
        }
    __syncthreads();                                           // #4

    // ---- GEMM2: kp = g @ W2.T + b2 ----
    #pragma unroll
    for (int rb = 0; rb < 2; ++rb)
        #pragma unroll
        for (int cb = 0; cb < 4; ++cb) acc[rb][cb] = fz;
    gemm(W2m, acc);

    float ss[2][4];
    #pragma unroll
    for (int rb = 0; rb < 2; ++rb)
        #pragma unroll
        for (int r = 0; r < 4; ++r) ss[rb][r] = 0.f;
    #pragma unroll
    for (int rb = 0; rb < 2; ++rb)
        #pragma unroll
        for (int cb = 0; cb < 4; ++cb) {
            const int j = wcol + cb * 16 + l16;
            const float bb = b2[j];
            #pragma unroll
            for (int r = 0; r < 4; ++r) {
                float v = acc[rb][cb][r] * INVS + bb;
                acc[rb][cb][r] = v;
                ss[rb][r] += v * v;
            }
        }
    #pragma unroll
    for (int mm = 1; mm < 16; mm <<= 1)
        #pragma unroll
        for (int rb = 0; rb < 2; ++rb)
            #pragma unroll
            for (int r = 0; r < 4; ++r)
                ss[rb][r] += __shfl_xor(ss[rb][r], mm);
    __syncthreads();                                           // #5 (GEMM2 AH reads done)
    if (l16 == 0) {
        #pragma unroll
        for (int rb = 0; rb < 2; ++rb)
            #pragma unroll
            for (int r = 0; r < 4; ++r)
                k2p_[wave * MT + rb * 16 + lK * 4 + r] = ss[rb][r];
    }
    // convert kp (x32, fp16 single) -> AH
    #pragma unroll
    for (int rb = 0; rb < 2; ++rb)
        #pragma unroll
        for (int cb = 0; cb < 4; ++cb) {
            const int j = wcol + cb * 16 + l16;
            #pragma unroll
            for (int r = 0; r < 4; ++r) {
                const int m = rb * 16 + lK * 4 + r;
                AH[m * D + (j ^ ((m & 7) << 3))] = (_Float16)(acc[rb][cb][r] * 32.0f);
            }
        }
    __syncthreads();                                           // #6

    if (t < MT) {
        float sa = 0.f;
        #pragma unroll
        for (int w = 0; w < 8; ++w) sa += k2p_[w * MT + t];
        k2s_[t] = sa;
        kins_[t] = rsqrtf(fmaxf(sa, 1e-30f));
    }

    // ---- scores: kp_hi @ Wt.T via gll-staged Wt (4-buf rotation, 3-ahead) ----
    f4 as[2][2];
    as[0][0] = fz; as[0][1] = fz; as[1][0] = fz; as[1][1] = fz;
    {
        const _Float16* wsrcB[2];
        #pragma unroll
        for (int j = 0; j < 2; ++j) {
            const int rr   = j * 16 + (lane >> 2);
            const int slot = (lane & 3) ^ ((rr >> 1) & 3);
            wsrcB[j] = Wt + (size_t)(wave * 32 + rr) * D + slot * 8;
        }
        auto stageWT = [&](int c, int buf) {
            #pragma unroll
            for (int j = 0; j < 2; ++j)
                __builtin_amdgcn_global_load_lds((gas_void*)(wsrcB[j] + c * 32),
                    (las_void*)(WBUF + buf * 16384 + wave * 2048 + j * 1024), 16, 0, 0);
        };
        const unsigned wrd0 = (unsigned)(l16 * 64 + ((lK ^ ((l16 >> 1) & 3)) << 4));
        auto scoreChunk = [&](int c, int buf) {
            const unsigned char* wb = WBUF + buf * 16384 + wave * 2048;
            h8 w0 = *(const h8*)(wb + wrd0);
            h8 w1 = *(const h8*)(wb + 1024 + wrd0);
            const int ksw = (c * 32 + lK * 8) ^ sw;
            h8 a0 = *(const h8*)&AH[r0 + ksw];
            h8 a1 = *(const h8*)&AH[r1 + ksw];
            as[0][0] = MF(a0, w0, as[0][0]);
            as[0][1] = MF(a0, w1, as[0][1]);
            as[1][0] = MF(a1, w0, as[1][0]);
            as[1][1] = MF(a1, w1, as[1][1]);
        };
        stageWT(0, 0); stageWT(1, 1); stageWT(2, 2);
        #pragma unroll 4
        for (int c = 0; c < 12; ++c) {
            asm volatile("s_waitcnt vmcnt(4)" ::: "memory");
            __builtin_amdgcn_sched_barrier(0);
            scoreChunk(c, c & 3);
            asm volatile("s_waitcnt lgkmcnt(0)" ::: "memory");
            __builtin_amdgcn_sched_barrier(0);
            stageWT(c + 3, (c + 3) & 3);
            __builtin_amdgcn_sched_barrier(0);
        }
        asm volatile("s_waitcnt vmcnt(4)" ::: "memory");
        __builtin_amdgcn_sched_barrier(0);
        scoreChunk(12, 0);
        asm volatile("s_waitcnt lgkmcnt(0)" ::: "memory");
        __builtin_amdgcn_sched_barrier(0);
        stageWT(15, 3);
        __builtin_amdgcn_sched_barrier(0);
        asm volatile("s_waitcnt vmcnt(4)" ::: "memory");
        __builtin_amdgcn_sched_barrier(0);
        scoreChunk(13, 1);
        asm volatile("s_waitcnt vmcnt(2)" ::: "memory");
        __builtin_amdgcn_sched_barrier(0);
        scoreChunk(14, 2);
        asm volatile("s_waitcnt vmcnt(0)" ::: "memory");
        __builtin_amdgcn_sched_barrier(0);
        scoreChunk(15, 3);
    }

    // ---- fused softmax-denominator partial sums ----
    {
        float part[2] = {0.f, 0.f};
        #pragma unroll
        for (int cb = 0; cb < 2; ++cb)
            #pragma unroll
            for (int rb = 0; rb < 2; ++rb)
                #pragma unroll
                for (int r = 0; r < 4; ++r) {
                    const int n = rb * 16 + lK * 4 + r;
                    if (n < nvalid)
                        part[cb] += __expf(as[rb][cb][r] * (1.0f / 32.0f));
                }
        #pragma unroll
        for (int cb = 0; cb < 2; ++cb) {
            part[cb] += __shfl_xor(part[cb], 16);
            part[cb] += __shfl_xor(part[cb], 32);
        }
        if (lK == 0) {
            atomicAdd(&sums[wave * 32 + l16], part[0]);
            atomicAdd(&sums[wave * 32 + 16 + l16], part[1]);
        }
    }

    // ---- dots = kp @ qp.T via MFMA (8 waves = 2 rh x 2 kh x 2 cbq) ----
    {
        const int rh = wave >> 2, kh = (wave >> 1) & 1, cbq = wave & 1;
        f4 ad = fz;
        const int ra = (rh * 16 + l16) * D;
        const int j = cbq * 16 + l16;
        #pragma unroll 2
        for (int ks = 0; ks < 8; ++ks) {
            const int k0 = kh * 256 + ks * 32 + lK * 8;
            const int ksw = k0 ^ sw;
            h8 ah0 = *(const h8*)&AH[ra + ksw];
            h8 bh = *(const h8*)&qph[j * D + k0];
            ad = MF(ah0, bh, ad);
        }
        #pragma unroll
        for (int r = 0; r < 4; ++r)
            dotp_[(kh * MT + rh * 16 + lK * 4 + r) * 33 + cbq * 16 + l16] = ad[r];
    }
    __syncthreads();                                           // #7

    // ---- cos / euc outputs (nt stores) ----
    for (int p = t; p < BQ * MT; p += NT) {
        const int m = p & (MT - 1), b = p >> 5;
        if (m < nvalid) {
            float dt = (dotp_[(0 * MT + m) * 33 + b] + dotp_[(1 * MT + m) * 33 + b]) * INVS;
            __builtin_nontemporal_store(dt * qinv[b] * kins_[m] * expT,
                                        &cosw[(size_t)b * N + n0 + m]);
            float dd = q2[b] + k2s_[m] - 2.0f * dt;
            __builtin_nontemporal_store(1.0f / (1.0f + sqrtf(fmaxf(dd, 0.f))),
                                        &eucw[(size_t)b * N + n0 + m]);
        }
    }

    // ---- scores -> SC (overlay AH, dead after #7), then coalesced out ----
    _Float16* SC = AH;   // element layout: n*256 + (b ^ (n&31))*8 + h
    {
        const int bh0 = wave * 32 + l16;
        #pragma unroll
        for (int cb = 0; cb < 2; ++cb) {
            const int bhc = bh0 + cb * 16;
            const int b = bhc >> 3, h = bhc & 7;
            #pragma unroll
            for (int rb = 0; rb < 2; ++rb) {
                #pragma unroll
                for (int r = 0; r < 4; ++r) {
                    const int n = rb * 16 + lK * 4 + r;
                    SC[n * 256 + ((b ^ (n & 31)) * 8) + h] =
                        (_Float16)(as[rb][cb][r] * (1.0f / 32.0f));
                }
            }
        }
    }
    __syncthreads();                                           // #8

    #pragma unroll
    for (int p = t; p < BQ * MT; p += NT) {
        const int b = p >> 5, n = p & (MT - 1);
        if (n < nvalid) {
            h8 v = *(const h8*)&SC[n * 256 + ((b ^ (n & 31)) * 8)];
            __builtin_nontemporal_store(v, (h8*)&scw[((size_t)b * N + n0 + n) * NH]);
        }
    }
}

// --------------------------------------------------------------------------
// Kernel 4: learned_sim + fused 3->64->1 MLP + sigmoid per (b,n).
// Computes 1/sums inline (inv kernel folded in).
// --------------------------------------------------------------------------
__global__ __launch_bounds__(256) void final_kernel(
    const float* __restrict__ cosw, const float* __restrict__ eucw,
    const _Float16* __restrict__ scw, int N,
    const float* __restrict__ sums,
    const float* __restrict__ fW1, const float* __restrict__ fb1,
    const float* __restrict__ fW2, const float* __restrict__ fb2,
    float* __restrict__ out, int total)
{
    __shared__ float w1s[192], b1s[64], w2s[64];
    __shared__ float sis[BQ * NH];
    __shared__ float b2s;
    const int t = threadIdx.x;
    if (t < 192) w1s[t] = fW1[t];
    else { b1s[t - 192] = fb1[t - 192]; w2s[t - 192] = fW2[t - 192]; }
    sis[t] = 1.0f / sums[t];
    if (t == 0) b2s = fb2[0];
    __syncthreads();

    const int idx = blockIdx.x * 256 + t;
    if (idx >= total) return;
    const int b = idx / N;

    float c = cosw[idx], e = eucw[idx];
    h8 v = *(const h8*)&scw[(size_t)idx * NH];
    float ls = 0.f;
    #pragma unroll
    for (int h = 0; h < NH; ++h)
        ls += __expf((float)v[h]) * sis[b * NH + h];
    ls *= 0.125f;

    float logit = b2s;
    #pragma unroll
    for (int j = 0; j < 64; ++j) {
        float hj = fmaf(w1s[j*3], c, fmaf(w1s[j*3+1], e, fmaf(w1s[j*3+2], ls, b1s[j])));
        logit = fmaf(w2s[j], fmaxf(hj, 0.f), logit);
    }
    out[idx] = 1.0f / (1.0f + expf(-logit));
}

// --------------------------------------------------------------------------
extern "C" void kernel_launch(void* const* d_in, const int* in_sizes, int n_in,
                              void* d_out, int out_size, void* d_ws, size_t ws_size,
                              hipStream_t stream)
{
    const float* xq   = (const float*)d_in[0];
    const float* xc   = (const float*)d_in[1];
    const float* temp = (const float*)d_in[2];
    const float* qW1  = (const float*)d_in[3];
    const float* qb1  = (const float*)d_in[4];
    const float* qlg  = (const float*)d_in[5];
    const float* qlb  = (const float*)d_in[6];
    const float* qW2  = (const float*)d_in[7];
    const float* qb2  = (const float*)d_in[8];
    const float* kW1  = (const float*)d_in[9];
    const float* kb1  = (const float*)d_in[10];
    const float* klg  = (const float*)d_in[11];
    const float* klb  = (const float*)d_in[12];
    const float* kW2  = (const float*)d_in[13];
    const float* kb2  = (const float*)d_in[14];
    const float* Wio  = (const float*)d_in[15];
    const float* bio  = (const float*)d_in[16];
    const float* fW1  = (const float*)d_in[17];
    const float* fb1  = (const float*)d_in[18];
    const float* fW2  = (const float*)d_in[19];
    const float* fb2  = (const float*)d_in[20];

    const int N = in_sizes[1] / D;

    float* ws   = (float*)d_ws;
    float* qp   = ws;                         // 16384
    float* qv   = qp + BQ * D;                // 16384
    float* q2   = qv + BQ * D;                // 32
    float* qinv = q2 + BQ;                    // 32
    float* sinv = qinv + BQ;                  // 256 (unused slot kept)
    float* sums = sinv + BQ * NH;             // 256
    float* cosw = sums + BQ * NH;             // BQ*N
    float* eucw = cosw + (size_t)BQ * N;      // BQ*N
    float* fend = eucw + (size_t)BQ * N;

    _Float16* hb  = (_Float16*)fend;
    _Float16* W1m = hb;                       // 262144 each
    _Float16* W2m = W1m + D * D;
    _Float16* qph = W2m + D * D;              // 16384
    _Float16* Wt  = qph + BQ * D;             // 256*512
    _Float16* scw = Wt + BQ * NH * D;         // BQ*N*NH  ([b][n][h])

    qproj_kernel<<<BQ, 256, 0, stream>>>(xq, qW1, qb1, qlg, qlb, qW2, qb2,
                                         Wio, bio, qp, qv, q2, qinv, qph);

    wprep_kernel<<<(D * D + 255) / 256, 256, 0, stream>>>(kW1, kW2, W1m, W2m, sums);

    wtld_kernel<<<BQ * NH, 256, 0, stream>>>(qv, Wio, Wt);

    const int nblk = (N + MT - 1) / MT;
    cand_kernel<<<nblk, NT, 0, stream>>>(xc, N, W1m, W2m,
                                         kb1, klg, klb, kb2,
                                         qph, Wt, q2, qinv, temp,
                                         cosw, eucw, scw, sums);

    const int total = BQ * N;
    final_kernel<<<(total + 255) / 256, 256, 0, stream>>>(cosw, eucw, scw, N, sums,
                                                          fW1, fb1, fW2, fb2,
                                                          (float*)d_out, total);
}

// Round 18
// 339.160 us; speedup vs baseline: 2.4071x; 1.0819x over previous
//
#include <hip/hip_runtime.h>
#include <math.h>

#define D    512
#define BQ   32
#define NH   8
#define MT   64
#define NT   512   // threads per cand block (8 waves)

typedef _Float16 h2  __attribute__((ext_vector_type(2)));
typedef _Float16 h4v __attribute__((ext_vector_type(4)));
typedef _Float16 h8  __attribute__((ext_vector_type(8)));
typedef float    f4  __attribute__((ext_vector_type(4)));

typedef const __attribute__((address_space(1))) void gas_void;
typedef __attribute__((address_space(3))) void las_void;

__device__ __forceinline__ f4 MF(h8 a, h8 b, f4 c) {
  return __builtin_amdgcn_mfma_f32_16x16x32_f16(a, b, c, 0, 0, 0);
}

__device__ __forceinline__ float erf_fast(float x) {
    float ax = fabsf(x);
    float tt = 1.0f / fmaf(0.3275911f, ax, 1.0f);
    float poly = tt * fmaf(tt, fmaf(tt, fmaf(tt, fmaf(tt, 1.061405429f, -1.453152027f),
                          1.421413741f), -0.284496736f), 0.254829592f);
    float r = 1.0f - poly * __expf(-ax * ax);
    return copysignf(r, x);
}
__device__ __forceinline__ float gelu_fast(float x) {
    return 0.5f * x * (1.0f + erf_fast(x * 0.7071067811865475f));
}
__device__ __forceinline__ float gelu_exact(float x) {
    return 0.5f * x * (1.0f + erff(x * 0.7071067811865475f));
}

// --------------------------------------------------------------------------
// Kernel 1: query path. One block per query row (32 blocks, 256 threads).
// --------------------------------------------------------------------------
__global__ __launch_bounds__(256) void qproj_kernel(
    const float* __restrict__ xq,
    const float* __restrict__ W1, const float* __restrict__ b1,
    const float* __restrict__ lng, const float* __restrict__ lnb,
    const float* __restrict__ W2, const float* __restrict__ b2,
    const float* __restrict__ Wio, const float* __restrict__ bio,
    float* __restrict__ qp, float* __restrict__ qv,
    float* __restrict__ q2o, float* __restrict__ qinvo,
    _Float16* __restrict__ qph)
{
    __shared__ float xs[D];
    __shared__ float hs[D];
    __shared__ float red[16];
    const int t = threadIdx.x;
    const int row = blockIdx.x;

    for (int i = t; i < D; i += 256) xs[i] = xq[row * D + i];
    __syncthreads();

    float a0 = 0.f, a1 = 0.f;
    for (int i = 0; i < D; i += 4) {
        float4 xv = *(const float4*)&xs[i];
        float4 w0 = *(const float4*)&W1[(size_t)t * D + i];
        float4 w1 = *(const float4*)&W1[(size_t)(t + 256) * D + i];
        a0 += xv.x*w0.x + xv.y*w0.y + xv.z*w0.z + xv.w*w0.w;
        a1 += xv.x*w1.x + xv.y*w1.y + xv.z*w1.z + xv.w*w1.w;
    }
    float h0 = a0 + b1[t], h1 = a1 + b1[t + 256];

    float s1 = h0 + h1, s2 = h0*h0 + h1*h1;
    for (int off = 32; off > 0; off >>= 1) { s1 += __shfl_down(s1, off); s2 += __shfl_down(s2, off); }
    if ((t & 63) == 0) { red[t >> 6] = s1; red[(t >> 6) + 4] = s2; }
    __syncthreads();
    if (t == 0) {
        float sa = red[0] + red[1] + red[2] + red[3];
        float sb = red[4] + red[5] + red[6] + red[7];
        float mu = sa / (float)D;
        red[8] = mu;
        red[9] = sb / (float)D - mu * mu;
    }
    __syncthreads();
    float mu = red[8];
    float isd = 1.0f / sqrtf(red[9] + 1e-5f);
    hs[t]       = gelu_exact((h0 - mu) * isd * lng[t]       + lnb[t]);
    hs[t + 256] = gelu_exact((h1 - mu) * isd * lng[t + 256] + lnb[t + 256]);
    __syncthreads();

    a0 = 0.f; a1 = 0.f;
    for (int i = 0; i < D; i += 4) {
        float4 gv = *(const float4*)&hs[i];
        float4 w0 = *(const float4*)&W2[(size_t)t * D + i];
        float4 w1 = *(const float4*)&W2[(size_t)(t + 256) * D + i];
        a0 += gv.x*w0.x + gv.y*w0.y + gv.z*w0.z + gv.w*w0.w;
        a1 += gv.x*w1.x + gv.y*w1.y + gv.z*w1.z + gv.w*w1.w;
    }
    float p0 = a0 + b2[t], p1 = a1 + b2[t + 256];
    qp[row * D + t] = p0;
    qp[row * D + t + 256] = p1;
    qph[row * D + t]       = (_Float16)(p0 * 32.0f);
    qph[row * D + t + 256] = (_Float16)(p1 * 32.0f);
    __syncthreads();
    xs[t] = p0; xs[t + 256] = p1;

    s1 = p0*p0 + p1*p1;
    for (int off = 32; off > 0; off >>= 1) s1 += __shfl_down(s1, off);
    if ((t & 63) == 0) red[t >> 6] = s1;
    __syncthreads();
    if (t == 0) {
        float sa = red[0] + red[1] + red[2] + red[3];
        q2o[row] = sa;
        qinvo[row] = 1.0f / sqrtf(sa);
    }
    __syncthreads();

    a0 = 0.f; a1 = 0.f;
    for (int i = 0; i < D; i += 4) {
        float4 pv = *(const float4*)&xs[i];
        float4 w0 = *(const float4*)&Wio[(size_t)t * D + i];
        float4 w1 = *(const float4*)&Wio[(size_t)(t + 256) * D + i];
        a0 += pv.x*w0.x + pv.y*w0.y + pv.z*w0.z + pv.w*w0.w;
        a1 += pv.x*w1.x + pv.y*w1.y + pv.z*w1.z + pv.w*w1.w;
    }
    qv[row * D + t]       = a0 + bio[t];
    qv[row * D + t + 256] = a1 + bio[t + 256];
}

// --------------------------------------------------------------------------
// Weight prep: single fp16 of 32*W for W1, W2. Block 0 also zeroes sums.
// --------------------------------------------------------------------------
__global__ __launch_bounds__(256) void wprep_kernel(
    const float* __restrict__ W1, const float* __restrict__ W2,
    _Float16* __restrict__ W1m, _Float16* __restrict__ W2m,
    float* __restrict__ sums)
{
    int idx = blockIdx.x * 256 + threadIdx.x;
    if (blockIdx.x == 0) sums[threadIdx.x] = 0.0f;
    if (idx >= D * D) return;
    W1m[idx] = (_Float16)(W1[idx] * 32.0f);
    W2m[idx] = (_Float16)(W2[idx] * 32.0f);
}

// --------------------------------------------------------------------------
// W-tilde prep: Wt[b,h,:] = (1/8) * sum_d qv[b, h*64+d] * Wk[h*64+d, :]
// --------------------------------------------------------------------------
__global__ __launch_bounds__(256) void wtld_kernel(
    const float* __restrict__ qv, const float* __restrict__ Wio,
    _Float16* __restrict__ Wt)
{
    __shared__ float qs[64];
    const int bh = blockIdx.x, b = bh >> 3, h = bh & 7;
    const int t = threadIdx.x;
    if (t < 64) qs[t] = qv[b * D + h * 64 + t] * 0.125f;
    __syncthreads();
    const float* Wk = Wio + (size_t)D * D + (size_t)(h * 64) * D;
    float a0 = 0.f, a1 = 0.f;
    #pragma unroll 4
    for (int d = 0; d < 64; ++d) {
        float q = qs[d];
        a0 += q * Wk[(size_t)d * D + t];
        a1 += q * Wk[(size_t)d * D + t + 256];
    }
    Wt[(size_t)bh * D + t]       = (_Float16)a0;
    Wt[(size_t)bh * D + t + 256] = (_Float16)a1;
}

// --------------------------------------------------------------------------
// Kernel 2: candidate path. 64 rows/block, 512 threads (8 waves).
// Single-fp16 weights; 2-buffer gll rotation; each wave owns 64 cols x
// 64 rows (acc[4][4]). Half the barriers & weight-bytes per candidate
// vs MT=32.
// --------------------------------------------------------------------------
__global__ __launch_bounds__(NT) void cand_kernel(
    const float* __restrict__ xc, int N,
    const _Float16* __restrict__ W1m, const _Float16* __restrict__ W2m,
    const float* __restrict__ b1, const float* __restrict__ lng,
    const float* __restrict__ lnb, const float* __restrict__ b2,
    const _Float16* __restrict__ qph,
    const _Float16* __restrict__ Wt,
    const float* __restrict__ q2, const float* __restrict__ qinv,
    const float* __restrict__ tempp,
    float* __restrict__ cosw, float* __restrict__ eucw,
    _Float16* __restrict__ scw, float* __restrict__ sums)
{
    __shared__ _Float16 AH[MT * D];                      // 64 KB (swizzled); reused as SC
    __shared__ __align__(16) unsigned char WBUF[65536];  // 2 x 32 KB weight staging
    // dotp (dots phase) aliases lnred (GEMM1 stats phase)
    __shared__ __align__(16) float scr[MT * 33];         // 8.4 KB
    __shared__ float k2p_[8 * MT];                       // 2 KB
    __shared__ float k2s_[MT], kins_[MT];
    __shared__ float lnmu_[MT], lnisd_[MT];

    float*  dotp_  = scr;                                // [64][33]
    float2* lnred_ = (float2*)scr;                       // [8][64] = 2 KB (fits)

    const int t    = threadIdx.x;
    const int wave = t >> 6;
    const int lane = t & 63;
    const int l16  = lane & 15;
    const int lK   = lane >> 4;
    const int wcol = wave * 64;
    const int n0   = blockIdx.x * MT;
    const int nvalid = min(MT, N - n0);
    const float expT = expf(tempp[0]);
    const float INVS = 1.0f / 1024.0f;
    const f4 fz = {0.f, 0.f, 0.f, 0.f};

    // ---- stage X (nt loads; scaled x32, fp16 single, swizzled) ----
    #pragma unroll
    for (int i = 0; i < 16; ++i) {
        int g = t + NT * i;                  // 0 .. 8191 (float4 index)
        int row = g >> 7;
        int c4 = (g & 127) * 4;
        f4 v = fz;
        if (n0 + row < N)
            v = __builtin_nontemporal_load((const f4*)(xc + (size_t)(n0 + row) * D + c4));
        h4v hi;
        #pragma unroll
        for (int e = 0; e < 4; ++e) hi[e] = (_Float16)(v[e] * 32.0f);
        *(h4v*)&AH[row * D + (c4 ^ ((row & 7) << 3))] = hi;
    }
    __syncthreads();                                           // #1

    const int sw = (l16 & 7) << 3;

    // hoisted LDS read offsets for the weight fragments (chunk-invariant)
    unsigned rdO[4];
    #pragma unroll
    for (int cb = 0; cb < 4; ++cb) {
        const int col = wcol + cb * 16 + l16;
        rdO[cb] = (unsigned)(col * 64 + ((lK ^ ((col >> 1) & 3)) << 4));
    }
    unsigned dstO[4];
    #pragma unroll
    for (int j = 0; j < 4; ++j) dstO[j] = (unsigned)(wave * 4096 + j * 1024);

    // 2-buffer single-product GEMM, acc[4][4] (64 rows x 64 cols per wave)
    auto gemm = [&](const _Float16* __restrict__ Wm, f4 (&acc)[4][4]) {
        const _Float16* srcB[4];
        #pragma unroll
        for (int j = 0; j < 4; ++j) {
            const int col  = (wave * 4 + j) * 16 + (lane >> 2);
            const int slot = (lane & 3) ^ ((col >> 1) & 3);
            srcB[j] = Wm + (size_t)col * D + slot * 8;
        }
        auto stage = [&](int c, int buf) {
            #pragma unroll
            for (int j = 0; j < 4; ++j)
                __builtin_amdgcn_global_load_lds((gas_void*)(srcB[j] + c * 32),
                    (las_void*)(WBUF + buf * 32768 + dstO[j]), 16, 0, 0);
        };
        auto compute = [&](int c, int buf) {
            const unsigned char* wb = WBUF + buf * 32768;
            h8 bh[4];
            #pragma unroll
            for (int cb = 0; cb < 4; ++cb) bh[cb] = *(const h8*)(wb + rdO[cb]);
            const int ksw = (c * 32 + lK * 8) ^ sw;
            h8 ah[4];
            #pragma unroll
            for (int rb = 0; rb < 4; ++rb)
                ah[rb] = *(const h8*)&AH[(rb * 16 + l16) * D + ksw];
            #pragma unroll
            for (int rb = 0; rb < 4; ++rb)
                #pragma unroll
                for (int cb = 0; cb < 4; ++cb)
                    acc[rb][cb] = MF(ah[rb], bh[cb], acc[rb][cb]);
        };
        stage(0, 0); stage(1, 1);
        #pragma unroll 1
        for (int c = 0; c < 14; ++c) {
            const int buf = c & 1;
            asm volatile("s_waitcnt vmcnt(4)" ::: "memory"); // drain chunk c only
            __builtin_amdgcn_sched_barrier(0);
            compute(c, buf);
            asm volatile("s_waitcnt lgkmcnt(0)" ::: "memory");
            __builtin_amdgcn_sched_barrier(0);
            stage(c + 2, buf);
            __builtin_amdgcn_sched_barrier(0);
        }
        asm volatile("s_waitcnt vmcnt(4)" ::: "memory");
        __builtin_amdgcn_sched_barrier(0);
        compute(14, 0);
        asm volatile("s_waitcnt vmcnt(0)" ::: "memory");
        __builtin_amdgcn_sched_barrier(0);
        compute(15, 1);
    };

    f4 acc[4][4];
    #pragma unroll
    for (int rb = 0; rb < 4; ++rb)
        #pragma unroll
        for (int cb = 0; cb < 4; ++cb) acc[rb][cb] = fz;

    // ---- GEMM1: h = x @ W1.T + b1 ----
    gemm(W1m, acc);

    float s1a[4][4], s2a[4][4];
    #pragma unroll
    for (int rb = 0; rb < 4; ++rb)
        #pragma unroll
        for (int r = 0; r < 4; ++r) { s1a[rb][r] = 0.f; s2a[rb][r] = 0.f; }
    #pragma unroll
    for (int rb = 0; rb < 4; ++rb)
        #pragma unroll
        for (int cb = 0; cb < 4; ++cb) {
            const int j = wcol + cb * 16 + l16;
            const float bb = b1[j];
            #pragma unroll
            for (int r = 0; r < 4; ++r) {
                float v = acc[rb][cb][r] * INVS + bb;
                acc[rb][cb][r] = v;
                s1a[rb][r] += v;
                s2a[rb][r] += v * v;
            }
        }
    #pragma unroll
    for (int mm = 1; mm < 16; mm <<= 1)
        #pragma unroll
        for (int rb = 0; rb < 4; ++rb)
            #pragma unroll
            for (int r = 0; r < 4; ++r) {
                s1a[rb][r] += __shfl_xor(s1a[rb][r], mm);
                s2a[rb][r] += __shfl_xor(s2a[rb][r], mm);
            }
    if (l16 == 0) {
        #pragma unroll
        for (int rb = 0; rb < 4; ++rb)
            #pragma unroll
            for (int r = 0; r < 4; ++r)
                lnred_[wave * MT + rb * 16 + lK * 4 + r] = make_float2(s1a[rb][r], s2a[rb][r]);
    }
    __syncthreads();                                           // #2
    if (t < MT) {
        float sa = 0.f, sb = 0.f;
        #pragma unroll
        for (int w = 0; w < 8; ++w) { sa += lnred_[w * MT + t].x; sb += lnred_[w * MT + t].y; }
        float mu = sa * (1.0f / 512.0f);
        float var = sb * (1.0f / 512.0f) - mu * mu;
        lnmu_[t] = mu;
        lnisd_[t] = rsqrtf(var + 1e-5f);
    }
    __syncthreads();                                           // #3

    // ---- LN + GELU in regs, convert g (fp16 single) -> AH ----
    #pragma unroll
    for (int rb = 0; rb < 4; ++rb)
        #pragma unroll
        for (int cb = 0; cb < 4; ++cb) {
            const int j = wcol + cb * 16 + l16;
            const float gg = lng[j], bb = lnb[j];
            #pragma unroll
            for (int r = 0; r < 4; ++r) {
                const int m = rb * 16 + lK * 4 + r;
                float v = (acc[rb][cb][r] - lnmu_[m]) * lnisd_[m] * gg + bb;
                v = gelu_fast(v) * 32.0f;
                AH[m * D + (j ^ ((m & 7) << 3))] = (_Float16)v;
            }
        }
    __syncthreads();                                           // #4

    // ---- GEMM2: kp = g @ W2.T + b2 ----
    #pragma unroll
    for (int rb = 0; rb < 4; ++rb)
        #pragma unroll
        for (int cb = 0; cb < 4; ++cb) acc[rb][cb] = fz;
    gemm(W2m, acc);

    float ss[4][4];
    #pragma unroll
    for (int rb = 0; rb < 4; ++rb)
        #pragma unroll
        for (int r = 0; r < 4; ++r) ss[rb][r] = 0.f;
    #pragma unroll
    for (int rb = 0; rb < 4; ++rb)
        #pragma unroll
        for (int cb = 0; cb < 4; ++cb) {
            const int j = wcol + cb * 16 + l16;
            const float bb = b2[j];
            #pragma unroll
            for (int r = 0; r < 4; ++r) {
                float v = acc[rb][cb][r] * INVS + bb;
                acc[rb][cb][r] = v;
                ss[rb][r] += v * v;
            }
        }
    #pragma unroll
    for (int mm = 1; mm < 16; mm <<= 1)
        #pragma unroll
        for (int rb = 0; rb < 4; ++rb)
            #pragma unroll
            for (int r = 0; r < 4; ++r)
                ss[rb][r] += __shfl_xor(ss[rb][r], mm);
    __syncthreads();                                           // #5 (GEMM2 AH reads done)
    if (l16 == 0) {
        #pragma unroll
        for (int rb = 0; rb < 4; ++rb)
            #pragma unroll
            for (int r = 0; r < 4; ++r)
                k2p_[wave * MT + rb * 16 + lK * 4 + r] = ss[rb][r];
    }
    // convert kp (x32, fp16 single) -> AH
    #pragma unroll
    for (int rb = 0; rb < 4; ++rb)
        #pragma unroll
        for (int cb = 0; cb < 4; ++cb) {
            const int j = wcol + cb * 16 + l16;
            #pragma unroll
            for (int r = 0; r < 4; ++r) {
                const int m = rb * 16 + lK * 4 + r;
                AH[m * D + (j ^ ((m & 7) << 3))] = (_Float16)(acc[rb][cb][r] * 32.0f);
            }
        }
    __syncthreads();                                           // #6

    if (t < MT) {
        float sa = 0.f;
        #pragma unroll
        for (int w = 0; w < 8; ++w) sa += k2p_[w * MT + t];
        k2s_[t] = sa;
        kins_[t] = rsqrtf(fmaxf(sa, 1e-30f));
    }

    // ---- scores: kp @ Wt.T via gll-staged Wt (4-buf rotation, 3-ahead) ----
    f4 as[4][2];
    #pragma unroll
    for (int rb = 0; rb < 4; ++rb) { as[rb][0] = fz; as[rb][1] = fz; }
    {
        const _Float16* wsrcB[2];
        #pragma unroll
        for (int j = 0; j < 2; ++j) {
            const int rr   = j * 16 + (lane >> 2);
            const int slot = (lane & 3) ^ ((rr >> 1) & 3);
            wsrcB[j] = Wt + (size_t)(wave * 32 + rr) * D + slot * 8;
        }
        auto stageWT = [&](int c, int buf) {
            #pragma unroll
            for (int j = 0; j < 2; ++j)
                __builtin_amdgcn_global_load_lds((gas_void*)(wsrcB[j] + c * 32),
                    (las_void*)(WBUF + buf * 16384 + wave * 2048 + j * 1024), 16, 0, 0);
        };
        const unsigned wrd0 = (unsigned)(l16 * 64 + ((lK ^ ((l16 >> 1) & 3)) << 4));
        auto scoreChunk = [&](int c, int buf) {
            const unsigned char* wb = WBUF + buf * 16384 + wave * 2048;
            h8 w0 = *(const h8*)(wb + wrd0);
            h8 w1 = *(const h8*)(wb + 1024 + wrd0);
            const int ksw = (c * 32 + lK * 8) ^ sw;
            #pragma unroll
            for (int rb = 0; rb < 4; ++rb) {
                h8 a = *(const h8*)&AH[(rb * 16 + l16) * D + ksw];
                as[rb][0] = MF(a, w0, as[rb][0]);
                as[rb][1] = MF(a, w1, as[rb][1]);
            }
        };
        stageWT(0, 0); stageWT(1, 1); stageWT(2, 2);
        #pragma unroll 4
        for (int c = 0; c < 12; ++c) {
            asm volatile("s_waitcnt vmcnt(4)" ::: "memory");
            __builtin_amdgcn_sched_barrier(0);
            scoreChunk(c, c & 3);
            asm volatile("s_waitcnt lgkmcnt(0)" ::: "memory");
            __builtin_amdgcn_sched_barrier(0);
            stageWT(c + 3, (c + 3) & 3);
            __builtin_amdgcn_sched_barrier(0);
        }
        asm volatile("s_waitcnt vmcnt(4)" ::: "memory");
        __builtin_amdgcn_sched_barrier(0);
        scoreChunk(12, 0);
        asm volatile("s_waitcnt lgkmcnt(0)" ::: "memory");
        __builtin_amdgcn_sched_barrier(0);
        stageWT(15, 3);
        __builtin_amdgcn_sched_barrier(0);
        asm volatile("s_waitcnt vmcnt(4)" ::: "memory");
        __builtin_amdgcn_sched_barrier(0);
        scoreChunk(13, 1);
        asm volatile("s_waitcnt vmcnt(2)" ::: "memory");
        __builtin_amdgcn_sched_barrier(0);
        scoreChunk(14, 2);
        asm volatile("s_waitcnt vmcnt(0)" ::: "memory");
        __builtin_amdgcn_sched_barrier(0);
        scoreChunk(15, 3);
    }

    // ---- fused softmax-denominator partial sums ----
    {
        float part[2] = {0.f, 0.f};
        #pragma unroll
        for (int cb = 0; cb < 2; ++cb)
            #pragma unroll
            for (int rb = 0; rb < 4; ++rb)
                #pragma unroll
                for (int r = 0; r < 4; ++r) {
                    const int n = rb * 16 + lK * 4 + r;
                    if (n < nvalid)
                        part[cb] += __expf(as[rb][cb][r] * (1.0f / 32.0f));
                }
        #pragma unroll
        for (int cb = 0; cb < 2; ++cb) {
            part[cb] += __shfl_xor(part[cb], 16);
            part[cb] += __shfl_xor(part[cb], 32);
        }
        if (lK == 0) {
            atomicAdd(&sums[wave * 32 + l16], part[0]);
            atomicAdd(&sums[wave * 32 + 16 + l16], part[1]);
        }
    }

    // ---- dots = kp @ qp.T via MFMA (8 waves = 4 rq x 2 cbq; full K) ----
    {
        const int rq = wave >> 1, cbq = wave & 1;
        f4 ad = fz;
        const int ra = (rq * 16 + l16) * D;
        const int j = cbq * 16 + l16;
        #pragma unroll 2
        for (int ks = 0; ks < 16; ++ks) {
            const int k0 = ks * 32 + lK * 8;
            const int ksw = k0 ^ sw;
            h8 ah0 = *(const h8*)&AH[ra + ksw];
            h8 bh = *(const h8*)&qph[j * D + k0];
            ad = MF(ah0, bh, ad);
        }
        #pragma unroll
        for (int r = 0; r < 4; ++r)
            dotp_[(rq * 16 + lK * 4 + r) * 33 + cbq * 16 + l16] = ad[r];
    }
    __syncthreads();                                           // #7

    // ---- cos / euc outputs (nt stores) ----
    for (int p = t; p < BQ * MT; p += NT) {
        const int m = p & (MT - 1), b = p >> 6;
        if (m < nvalid) {
            float dt = dotp_[m * 33 + b] * INVS;
            __builtin_nontemporal_store(dt * qinv[b] * kins_[m] * expT,
                                        &cosw[(size_t)b * N + n0 + m]);
            float dd = q2[b] + k2s_[m] - 2.0f * dt;
            __builtin_nontemporal_store(1.0f / (1.0f + sqrtf(fmaxf(dd, 0.f))),
                                        &eucw[(size_t)b * N + n0 + m]);
        }
    }

    // ---- scores -> SC (overlay AH, dead after #7), then coalesced out ----
    _Float16* SC = AH;   // element layout: n*256 + (b ^ (n&31))*8 + h
    {
        const int bh0 = wave * 32 + l16;
        #pragma unroll
        for (int cb = 0; cb < 2; ++cb) {
            const int bhc = bh0 + cb * 16;
            const int b = bhc >> 3, h = bhc & 7;
            #pragma unroll
            for (int rb = 0; rb < 4; ++rb) {
                #pragma unroll
                for (int r = 0; r < 4; ++r) {
                    const int n = rb * 16 + lK * 4 + r;
                    SC[n * 256 + ((b ^ (n & 31)) * 8) + h] =
                        (_Float16)(as[rb][cb][r] * (1.0f / 32.0f));
                }
            }
        }
    }
    __syncthreads();                                           // #8

    #pragma unroll
    for (int p = t; p < BQ * MT; p += NT) {
        const int b = p >> 6, n = p & (MT - 1);
        if (n < nvalid) {
            h8 v = *(const h8*)&SC[n * 256 + ((b ^ (n & 31)) * 8)];
            __builtin_nontemporal_store(v, (h8*)&scw[((size_t)b * N + n0 + n) * NH]);
        }
    }
}

// --------------------------------------------------------------------------
// Kernel 4: learned_sim + fused 3->64->1 MLP + sigmoid per (b,n).
// --------------------------------------------------------------------------
__global__ __launch_bounds__(256) void final_kernel(
    const float* __restrict__ cosw, const float* __restrict__ eucw,
    const _Float16* __restrict__ scw, int N,
    const float* __restrict__ sums,
    const float* __restrict__ fW1, const float* __restrict__ fb1,
    const float* __restrict__ fW2, const float* __restrict__ fb2,
    float* __restrict__ out, int total)
{
    __shared__ float w1s[192], b1s[64], w2s[64];
    __shared__ float sis[BQ * NH];
    __shared__ float b2s;
    const int t = threadIdx.x;
    if (t < 192) w1s[t] = fW1[t];
    else { b1s[t - 192] = fb1[t - 192]; w2s[t - 192] = fW2[t - 192]; }
    sis[t] = 1.0f / sums[t];
    if (t == 0) b2s = fb2[0];
    __syncthreads();

    const int idx = blockIdx.x * 256 + t;
    if (idx >= total) return;
    const int b = idx / N;

    float c = cosw[idx], e = eucw[idx];
    h8 v = *(const h8*)&scw[(size_t)idx * NH];
    float ls = 0.f;
    #pragma unroll
    for (int h = 0; h < NH; ++h)
        ls += __expf((float)v[h]) * sis[b * NH + h];
    ls *= 0.125f;

    float logit = b2s;
    #pragma unroll
    for (int j = 0; j < 64; ++j) {
        float hj = fmaf(w1s[j*3], c, fmaf(w1s[j*3+1], e, fmaf(w1s[j*3+2], ls, b1s[j])));
        logit = fmaf(w2s[j], fmaxf(hj, 0.f), logit);
    }
    out[idx] = 1.0f / (1.0f + expf(-logit));
}

// --------------------------------------------------------------------------
extern "C" void kernel_launch(void* const* d_in, const int* in_sizes, int n_in,
                              void* d_out, int out_size, void* d_ws, size_t ws_size,
                              hipStream_t stream)
{
    const float* xq   = (const float*)d_in[0];
    const float* xc   = (const float*)d_in[1];
    const float* temp = (const float*)d_in[2];
    const float* qW1  = (const float*)d_in[3];
    const float* qb1  = (const float*)d_in[4];
    const float* qlg  = (const float*)d_in[5];
    const float* qlb  = (const float*)d_in[6];
    const float* qW2  = (const float*)d_in[7];
    const float* qb2  = (const float*)d_in[8];
    const float* kW1  = (const float*)d_in[9];
    const float* kb1  = (const float*)d_in[10];
    const float* klg  = (const float*)d_in[11];
    const float* klb  = (const float*)d_in[12];
    const float* kW2  = (const float*)d_in[13];
    const float* kb2  = (const float*)d_in[14];
    const float* Wio  = (const float*)d_in[15];
    const float* bio  = (const float*)d_in[16];
    const float* fW1  = (const float*)d_in[17];
    const float* fb1  = (const float*)d_in[18];
    const float* fW2  = (const float*)d_in[19];
    const float* fb2  = (const float*)d_in[20];

    const int N = in_sizes[1] / D;

    float* ws   = (float*)d_ws;
    float* qp   = ws;                         // 16384
    float* qv   = qp + BQ * D;                // 16384
    float* q2   = qv + BQ * D;                // 32
    float* qinv = q2 + BQ;                    // 32
    float* sinv = qinv + BQ;                  // 256 (unused slot kept)
    float* sums = sinv + BQ * NH;             // 256
    float* cosw = sums + BQ * NH;             // BQ*N
    float* eucw = cosw + (size_t)BQ * N;      // BQ*N
    float* fend = eucw + (size_t)BQ * N;

    _Float16* hb  = (_Float16*)fend;
    _Float16* W1m = hb;                       // 262144 each
    _Float16* W2m = W1m + D * D;
    _Float16* qph = W2m + D * D;              // 16384
    _Float16* Wt  = qph + BQ * D;             // 256*512
    _Float16* scw = Wt + BQ * NH * D;         // BQ*N*NH  ([b][n][h])

    qproj_kernel<<<BQ, 256, 0, stream>>>(xq, qW1, qb1, qlg, qlb, qW2, qb2,
                                         Wio, bio, qp, qv, q2, qinv, qph);

    wprep_kernel<<<(D * D + 255) / 256, 256, 0, stream>>>(kW1, kW2, W1m, W2m, sums);

    wtld_kernel<<<BQ * NH, 256, 0, stream>>>(qv, Wio, Wt);

    const int nblk = (N + MT - 1) / MT;
    cand_kernel<<<nblk, NT, 0, stream>>>(xc, N, W1m, W2m,
                                         kb1, klg, klb, kb2,
                                         qph, Wt, q2, qinv, temp,
                                         cosw, eucw, scw, sums);

    const int total = BQ * N;
    final_kernel<<<(total + 255) / 256, 256, 0, stream>>>(cosw, eucw, scw, N, sums,
                                                          fW1, fb1, fW2, fb2,
                                                          (float*)d_out, total);
}

// Round 19
// 311.543 us; speedup vs baseline: 2.6204x; 1.0886x over previous
//
#include <hip/hip_runtime.h>
#include <math.h>

#define D    512
#define BQ   32
#define NH   8
#define MT   64
#define NT   512   // threads per cand block (8 waves)

typedef _Float16 h2  __attribute__((ext_vector_type(2)));
typedef _Float16 h4v __attribute__((ext_vector_type(4)));
typedef _Float16 h8  __attribute__((ext_vector_type(8)));
typedef float    f4  __attribute__((ext_vector_type(4)));

typedef const __attribute__((address_space(1))) void gas_void;
typedef __attribute__((address_space(3))) void las_void;

__device__ __forceinline__ f4 MF(h8 a, h8 b, f4 c) {
  return __builtin_amdgcn_mfma_f32_16x16x32_f16(a, b, c, 0, 0, 0);
}

__device__ __forceinline__ float erf_fast(float x) {
    float ax = fabsf(x);
    float tt = 1.0f / fmaf(0.3275911f, ax, 1.0f);
    float poly = tt * fmaf(tt, fmaf(tt, fmaf(tt, fmaf(tt, 1.061405429f, -1.453152027f),
                          1.421413741f), -0.284496736f), 0.254829592f);
    float r = 1.0f - poly * __expf(-ax * ax);
    return copysignf(r, x);
}
__device__ __forceinline__ float gelu_fast(float x) {
    return 0.5f * x * (1.0f + erf_fast(x * 0.7071067811865475f));
}
__device__ __forceinline__ float gelu_exact(float x) {
    return 0.5f * x * (1.0f + erff(x * 0.7071067811865475f));
}

// --------------------------------------------------------------------------
// Kernel 1: query proj block only (h->LN->GELU->qp). 512 threads, 1 col each.
// q = qp@Wq.T moved into wtld (it only needs 64 values per (b,h) block).
// --------------------------------------------------------------------------
__global__ __launch_bounds__(512) void qproj_kernel(
    const float* __restrict__ xq,
    const float* __restrict__ W1, const float* __restrict__ b1,
    const float* __restrict__ lng, const float* __restrict__ lnb,
    const float* __restrict__ W2, const float* __restrict__ b2,
    float* __restrict__ qp,
    float* __restrict__ q2o, float* __restrict__ qinvo,
    _Float16* __restrict__ qph)
{
    __shared__ float xs[D];
    __shared__ float hs[D];
    __shared__ float red[20];
    const int t = threadIdx.x;
    const int row = blockIdx.x;
    const int wave = t >> 6, lane = t & 63;

    xs[t] = xq[row * D + t];
    __syncthreads();

    float a0 = 0.f;
    for (int i = 0; i < D; i += 4) {
        float4 xv = *(const float4*)&xs[i];
        float4 w0 = *(const float4*)&W1[(size_t)t * D + i];
        a0 += xv.x*w0.x + xv.y*w0.y + xv.z*w0.z + xv.w*w0.w;
    }
    float h0 = a0 + b1[t];

    float s1 = h0, s2 = h0 * h0;
    for (int off = 32; off > 0; off >>= 1) { s1 += __shfl_down(s1, off); s2 += __shfl_down(s2, off); }
    if (lane == 0) { red[wave] = s1; red[8 + wave] = s2; }
    __syncthreads();
    if (t == 0) {
        float sa = 0.f, sb = 0.f;
        #pragma unroll
        for (int w = 0; w < 8; ++w) { sa += red[w]; sb += red[8 + w]; }
        float mu = sa / (float)D;
        red[16] = mu;
        red[17] = rsqrtf(sb / (float)D - mu * mu + 1e-5f);
    }
    __syncthreads();
    float mu = red[16], isd = red[17];
    hs[t] = gelu_exact((h0 - mu) * isd * lng[t] + lnb[t]);
    __syncthreads();

    a0 = 0.f;
    for (int i = 0; i < D; i += 4) {
        float4 gv = *(const float4*)&hs[i];
        float4 w0 = *(const float4*)&W2[(size_t)t * D + i];
        a0 += gv.x*w0.x + gv.y*w0.y + gv.z*w0.z + gv.w*w0.w;
    }
    float p0 = a0 + b2[t];
    qp[row * D + t]  = p0;
    qph[row * D + t] = (_Float16)p0;

    s1 = p0 * p0;
    for (int off = 32; off > 0; off >>= 1) s1 += __shfl_down(s1, off);
    if (lane == 0) red[wave] = s1;
    __syncthreads();
    if (t == 0) {
        float sa = 0.f;
        #pragma unroll
        for (int w = 0; w < 8; ++w) sa += red[w];
        q2o[row] = sa;
        qinvo[row] = 1.0f / sqrtf(sa);
    }
}

// --------------------------------------------------------------------------
// Weight prep: fp16 of W1, W2 (no scaling). Block 0 also zeroes sums.
// --------------------------------------------------------------------------
__global__ __launch_bounds__(256) void wprep_kernel(
    const float* __restrict__ W1, const float* __restrict__ W2,
    _Float16* __restrict__ W1m, _Float16* __restrict__ W2m,
    float* __restrict__ sums)
{
    int idx = blockIdx.x * 256 + threadIdx.x;
    if (blockIdx.x == 0) sums[threadIdx.x] = 0.0f;
    if (idx >= D * D) return;
    W1m[idx] = (_Float16)W1[idx];
    W2m[idx] = (_Float16)W2[idx];
}

// --------------------------------------------------------------------------
// W-tilde prep: q[b,h,d] = qp[b]·Wq[h*64+d] + bq, then
// Wt[b,h,:] = (1/8) * sum_d q[b,h,d] * Wk[h*64+d, :].
// One block per (b,h); 256 threads.
// --------------------------------------------------------------------------
__global__ __launch_bounds__(256) void wtld_kernel(
    const float* __restrict__ qp, const float* __restrict__ Wio,
    const float* __restrict__ bio,
    _Float16* __restrict__ Wt)
{
    __shared__ float qpb[D];
    __shared__ float qs[64];
    const int bh = blockIdx.x, b = bh >> 3, h = bh & 7;
    const int t = threadIdx.x;

    qpb[t]       = qp[b * D + t];
    qpb[t + 256] = qp[b * D + t + 256];
    __syncthreads();

    // q-projection slice: d = t>>2, 4 threads per d
    {
        const int d = t >> 2, part = t & 3;
        const float* Wq = Wio + (size_t)(h * 64 + d) * D + part * 128;
        const float* xp = qpb + part * 128;
        float a = 0.f;
        #pragma unroll 8
        for (int i = 0; i < 128; i += 4) {
            float4 xv = *(const float4*)&xp[i];
            float4 wv = *(const float4*)&Wq[i];
            a += xv.x*wv.x + xv.y*wv.y + xv.z*wv.z + xv.w*wv.w;
        }
        a += __shfl_xor(a, 1);
        a += __shfl_xor(a, 2);
        if (part == 0) qs[d] = (a + bio[h * 64 + d]) * 0.125f;
    }
    __syncthreads();

    const float* Wk = Wio + (size_t)D * D + (size_t)(h * 64) * D;
    float a0 = 0.f, a1 = 0.f;
    #pragma unroll 4
    for (int d = 0; d < 64; ++d) {
        float q = qs[d];
        a0 += q * Wk[(size_t)d * D + t];
        a1 += q * Wk[(size_t)d * D + t + 256];
    }
    Wt[(size_t)bh * D + t]       = (_Float16)a0;
    Wt[(size_t)bh * D + t + 256] = (_Float16)a1;
}

// --------------------------------------------------------------------------
// Kernel 2: candidate path. 64 rows/block, 512 threads (8 waves).
// Unscaled fp16 everywhere; 2-buffer gll rotation; acc[4][4] per wave.
// scw stores exp(score) (fp16) so final needs no expf.
// --------------------------------------------------------------------------
__global__ __launch_bounds__(NT) void cand_kernel(
    const float* __restrict__ xc, int N,
    const _Float16* __restrict__ W1m, const _Float16* __restrict__ W2m,
    const float* __restrict__ b1, const float* __restrict__ lng,
    const float* __restrict__ lnb, const float* __restrict__ b2,
    const _Float16* __restrict__ qph,
    const _Float16* __restrict__ Wt,
    const float* __restrict__ q2, const float* __restrict__ qinv,
    const float* __restrict__ tempp,
    float* __restrict__ cosw, float* __restrict__ eucw,
    _Float16* __restrict__ scw, float* __restrict__ sums)
{
    __shared__ _Float16 AH[MT * D];                      // 64 KB (swizzled); reused as SC
    __shared__ __align__(16) unsigned char WBUF[65536];  // 2 x 32 KB weight staging
    __shared__ __align__(16) float scr[MT * 33];         // dotp aliases lnred
    __shared__ float k2p_[8 * MT];
    __shared__ float k2s_[MT], kins_[MT];
    __shared__ float lnmu_[MT], lnisd_[MT];

    float*  dotp_  = scr;
    float2* lnred_ = (float2*)scr;

    const int t    = threadIdx.x;
    const int wave = t >> 6;
    const int lane = t & 63;
    const int l16  = lane & 15;
    const int lK   = lane >> 4;
    const int wcol = wave * 64;
    const int n0   = blockIdx.x * MT;
    const int nvalid = min(MT, N - n0);
    const float expT = expf(tempp[0]);
    const f4 fz = {0.f, 0.f, 0.f, 0.f};

    // ---- stage X (nt loads; fp16, swizzled) ----
    #pragma unroll
    for (int i = 0; i < 16; ++i) {
        int g = t + NT * i;
        int row = g >> 7;
        int c4 = (g & 127) * 4;
        f4 v = fz;
        if (n0 + row < N)
            v = __builtin_nontemporal_load((const f4*)(xc + (size_t)(n0 + row) * D + c4));
        h4v hi;
        #pragma unroll
        for (int e = 0; e < 4; ++e) hi[e] = (_Float16)v[e];
        *(h4v*)&AH[row * D + (c4 ^ ((row & 7) << 3))] = hi;
    }
    __syncthreads();                                           // #1

    const int sw = (l16 & 7) << 3;

    unsigned rdO[4];
    #pragma unroll
    for (int cb = 0; cb < 4; ++cb) {
        const int col = wcol + cb * 16 + l16;
        rdO[cb] = (unsigned)(col * 64 + ((lK ^ ((col >> 1) & 3)) << 4));
    }
    unsigned dstO[4];
    #pragma unroll
    for (int j = 0; j < 4; ++j) dstO[j] = (unsigned)(wave * 4096 + j * 1024);

    auto gemm = [&](const _Float16* __restrict__ Wm, f4 (&acc)[4][4]) {
        const _Float16* srcB[4];
        #pragma unroll
        for (int j = 0; j < 4; ++j) {
            const int col  = (wave * 4 + j) * 16 + (lane >> 2);
            const int slot = (lane & 3) ^ ((col >> 1) & 3);
            srcB[j] = Wm + (size_t)col * D + slot * 8;
        }
        auto stage = [&](int c, int buf) {
            #pragma unroll
            for (int j = 0; j < 4; ++j)
                __builtin_amdgcn_global_load_lds((gas_void*)(srcB[j] + c * 32),
                    (las_void*)(WBUF + buf * 32768 + dstO[j]), 16, 0, 0);
        };
        auto compute = [&](int c, int buf) {
            const unsigned char* wb = WBUF + buf * 32768;
            h8 bh[4];
            #pragma unroll
            for (int cb = 0; cb < 4; ++cb) bh[cb] = *(const h8*)(wb + rdO[cb]);
            const int ksw = (c * 32 + lK * 8) ^ sw;
            h8 ah[4];
            #pragma unroll
            for (int rb = 0; rb < 4; ++rb)
                ah[rb] = *(const h8*)&AH[(rb * 16 + l16) * D + ksw];
            #pragma unroll
            for (int rb = 0; rb < 4; ++rb)
                #pragma unroll
                for (int cb = 0; cb < 4; ++cb)
                    acc[rb][cb] = MF(ah[rb], bh[cb], acc[rb][cb]);
        };
        stage(0, 0); stage(1, 1);
        #pragma unroll 1
        for (int c = 0; c < 14; ++c) {
            const int buf = c & 1;
            asm volatile("s_waitcnt vmcnt(4)" ::: "memory");
            __builtin_amdgcn_sched_barrier(0);
            compute(c, buf);
            asm volatile("s_waitcnt lgkmcnt(0)" ::: "memory");
            __builtin_amdgcn_sched_barrier(0);
            stage(c + 2, buf);
            __builtin_amdgcn_sched_barrier(0);
        }
        asm volatile("s_waitcnt vmcnt(4)" ::: "memory");
        __builtin_amdgcn_sched_barrier(0);
        compute(14, 0);
        asm volatile("s_waitcnt vmcnt(0)" ::: "memory");
        __builtin_amdgcn_sched_barrier(0);
        compute(15, 1);
    };

    f4 acc[4][4];
    #pragma unroll
    for (int rb = 0; rb < 4; ++rb)
        #pragma unroll
        for (int cb = 0; cb < 4; ++cb) acc[rb][cb] = fz;

    // ---- GEMM1: h = x @ W1.T + b1 ----
    gemm(W1m, acc);

    float s1a[4][4], s2a[4][4];
    #pragma unroll
    for (int rb = 0; rb < 4; ++rb)
        #pragma unroll
        for (int r = 0; r < 4; ++r) { s1a[rb][r] = 0.f; s2a[rb][r] = 0.f; }
    #pragma unroll
    for (int rb = 0; rb < 4; ++rb)
        #pragma unroll
        for (int cb = 0; cb < 4; ++cb) {
            const int j = wcol + cb * 16 + l16;
            const float bb = b1[j];
            #pragma unroll
            for (int r = 0; r < 4; ++r) {
                float v = acc[rb][cb][r] + bb;
                acc[rb][cb][r] = v;
                s1a[rb][r] += v;
                s2a[rb][r] += v * v;
            }
        }
    #pragma unroll
    for (int mm = 1; mm < 16; mm <<= 1)
        #pragma unroll
        for (int rb = 0; rb < 4; ++rb)
            #pragma unroll
            for (int r = 0; r < 4; ++r) {
                s1a[rb][r] += __shfl_xor(s1a[rb][r], mm);
                s2a[rb][r] += __shfl_xor(s2a[rb][r], mm);
            }
    if (l16 == 0) {
        #pragma unroll
        for (int rb = 0; rb < 4; ++rb)
            #pragma unroll
            for (int r = 0; r < 4; ++r)
                lnred_[wave * MT + rb * 16 + lK * 4 + r] = make_float2(s1a[rb][r], s2a[rb][r]);
    }
    __syncthreads();                                           // #2
    if (t < MT) {
        float sa = 0.f, sb = 0.f;
        #pragma unroll
        for (int w = 0; w < 8; ++w) { sa += lnred_[w * MT + t].x; sb += lnred_[w * MT + t].y; }
        float mu = sa * (1.0f / 512.0f);
        float var = sb * (1.0f / 512.0f) - mu * mu;
        lnmu_[t] = mu;
        lnisd_[t] = rsqrtf(var + 1e-5f);
    }
    __syncthreads();                                           // #3

    // ---- LN + GELU in regs, convert g -> AH ----
    #pragma unroll
    for (int rb = 0; rb < 4; ++rb)
        #pragma unroll
        for (int cb = 0; cb < 4; ++cb) {
            const int j = wcol + cb * 16 + l16;
            const float gg = lng[j], bb = lnb[j];
            #pragma unroll
            for (int r = 0; r < 4; ++r) {
                const int m = rb * 16 + lK * 4 + r;
                float v = (acc[rb][cb][r] - lnmu_[m]) * lnisd_[m] * gg + bb;
                AH[m * D + (j ^ ((m & 7) << 3))] = (_Float16)gelu_fast(v);
            }
        }
    __syncthreads();                                           // #4

    // ---- GEMM2: kp = g @ W2.T + b2 ----
    #pragma unroll
    for (int rb = 0; rb < 4; ++rb)
        #pragma unroll
        for (int cb = 0; cb < 4; ++cb) acc[rb][cb] = fz;
    gemm(W2m, acc);

    float ss[4][4];
    #pragma unroll
    for (int rb = 0; rb < 4; ++rb)
        #pragma unroll
        for (int r = 0; r < 4; ++r) ss[rb][r] = 0.f;
    #pragma unroll
    for (int rb = 0; rb < 4; ++rb)
        #pragma unroll
        for (int cb = 0; cb < 4; ++cb) {
            const int j = wcol + cb * 16 + l16;
            const float bb = b2[j];
            #pragma unroll
            for (int r = 0; r < 4; ++r) {
                float v = acc[rb][cb][r] + bb;
                acc[rb][cb][r] = v;
                ss[rb][r] += v * v;
            }
        }
    #pragma unroll
    for (int mm = 1; mm < 16; mm <<= 1)
        #pragma unroll
        for (int rb = 0; rb < 4; ++rb)
            #pragma unroll
            for (int r = 0; r < 4; ++r)
                ss[rb][r] += __shfl_xor(ss[rb][r], mm);
    __syncthreads();                                           // #5
    if (l16 == 0) {
        #pragma unroll
        for (int rb = 0; rb < 4; ++rb)
            #pragma unroll
            for (int r = 0; r < 4; ++r)
                k2p_[wave * MT + rb * 16 + lK * 4 + r] = ss[rb][r];
    }
    // convert kp (fp16) -> AH
    #pragma unroll
    for (int rb = 0; rb < 4; ++rb)
        #pragma unroll
        for (int cb = 0; cb < 4; ++cb) {
            const int j = wcol + cb * 16 + l16;
            #pragma unroll
            for (int r = 0; r < 4; ++r) {
                const int m = rb * 16 + lK * 4 + r;
                AH[m * D + (j ^ ((m & 7) << 3))] = (_Float16)acc[rb][cb][r];
            }
        }
    __syncthreads();                                           // #6

    if (t < MT) {
        float sa = 0.f;
        #pragma unroll
        for (int w = 0; w < 8; ++w) sa += k2p_[w * MT + t];
        k2s_[t] = sa;
        kins_[t] = rsqrtf(fmaxf(sa, 1e-30f));
    }

    // ---- scores: kp @ Wt.T via gll-staged Wt (4-buf rotation, 3-ahead) ----
    f4 as[4][2];
    #pragma unroll
    for (int rb = 0; rb < 4; ++rb) { as[rb][0] = fz; as[rb][1] = fz; }
    {
        const _Float16* wsrcB[2];
        #pragma unroll
        for (int j = 0; j < 2; ++j) {
            const int rr   = j * 16 + (lane >> 2);
            const int slot = (lane & 3) ^ ((rr >> 1) & 3);
            wsrcB[j] = Wt + (size_t)(wave * 32 + rr) * D + slot * 8;
        }
        auto stageWT = [&](int c, int buf) {
            #pragma unroll
            for (int j = 0; j < 2; ++j)
                __builtin_amdgcn_global_load_lds((gas_void*)(wsrcB[j] + c * 32),
                    (las_void*)(WBUF + buf * 16384 + wave * 2048 + j * 1024), 16, 0, 0);
        };
        const unsigned wrd0 = (unsigned)(l16 * 64 + ((lK ^ ((l16 >> 1) & 3)) << 4));
        auto scoreChunk = [&](int c, int buf) {
            const unsigned char* wb = WBUF + buf * 16384 + wave * 2048;
            h8 w0 = *(const h8*)(wb + wrd0);
            h8 w1 = *(const h8*)(wb + 1024 + wrd0);
            const int ksw = (c * 32 + lK * 8) ^ sw;
            #pragma unroll
            for (int rb = 0; rb < 4; ++rb) {
                h8 a = *(const h8*)&AH[(rb * 16 + l16) * D + ksw];
                as[rb][0] = MF(a, w0, as[rb][0]);
                as[rb][1] = MF(a, w1, as[rb][1]);
            }
        };
        stageWT(0, 0); stageWT(1, 1); stageWT(2, 2);
        #pragma unroll 4
        for (int c = 0; c < 12; ++c) {
            asm volatile("s_waitcnt vmcnt(4)" ::: "memory");
            __builtin_amdgcn_sched_barrier(0);
            scoreChunk(c, c & 3);
            asm volatile("s_waitcnt lgkmcnt(0)" ::: "memory");
            __builtin_amdgcn_sched_barrier(0);
            stageWT(c + 3, (c + 3) & 3);
            __builtin_amdgcn_sched_barrier(0);
        }
        asm volatile("s_waitcnt vmcnt(4)" ::: "memory");
        __builtin_amdgcn_sched_barrier(0);
        scoreChunk(12, 0);
        asm volatile("s_waitcnt lgkmcnt(0)" ::: "memory");
        __builtin_amdgcn_sched_barrier(0);
        stageWT(15, 3);
        __builtin_amdgcn_sched_barrier(0);
        asm volatile("s_waitcnt vmcnt(4)" ::: "memory");
        __builtin_amdgcn_sched_barrier(0);
        scoreChunk(13, 1);
        asm volatile("s_waitcnt vmcnt(2)" ::: "memory");
        __builtin_amdgcn_sched_barrier(0);
        scoreChunk(14, 2);
        asm volatile("s_waitcnt vmcnt(0)" ::: "memory");
        __builtin_amdgcn_sched_barrier(0);
        scoreChunk(15, 3);
    }

    // ---- exp(scores) in place; fused softmax-denominator partial sums ----
    {
        #pragma unroll
        for (int cb = 0; cb < 2; ++cb)
            #pragma unroll
            for (int rb = 0; rb < 4; ++rb)
                #pragma unroll
                for (int r = 0; r < 4; ++r)
                    as[rb][cb][r] = __expf(as[rb][cb][r]);
        float part[2] = {0.f, 0.f};
        #pragma unroll
        for (int cb = 0; cb < 2; ++cb)
            #pragma unroll
            for (int rb = 0; rb < 4; ++rb)
                #pragma unroll
                for (int r = 0; r < 4; ++r) {
                    const int n = rb * 16 + lK * 4 + r;
                    if (n < nvalid) part[cb] += as[rb][cb][r];
                }
        #pragma unroll
        for (int cb = 0; cb < 2; ++cb) {
            part[cb] += __shfl_xor(part[cb], 16);
            part[cb] += __shfl_xor(part[cb], 32);
        }
        if (lK == 0) {
            atomicAdd(&sums[wave * 32 + l16], part[0]);
            atomicAdd(&sums[wave * 32 + 16 + l16], part[1]);
        }
    }

    // ---- dots = kp @ qp.T via MFMA (8 waves = 4 rq x 2 cbq; full K) ----
    {
        const int rq = wave >> 1, cbq = wave & 1;
        f4 ad = fz;
        const int ra = (rq * 16 + l16) * D;
        const int j = cbq * 16 + l16;
        #pragma unroll 2
        for (int ks = 0; ks < 16; ++ks) {
            const int k0 = ks * 32 + lK * 8;
            const int ksw = k0 ^ sw;
            h8 ah0 = *(const h8*)&AH[ra + ksw];
            h8 bh = *(const h8*)&qph[j * D + k0];
            ad = MF(ah0, bh, ad);
        }
        #pragma unroll
        for (int r = 0; r < 4; ++r)
            dotp_[(rq * 16 + lK * 4 + r) * 33 + cbq * 16 + l16] = ad[r];
    }
    __syncthreads();                                           // #7

    // ---- cos / euc outputs (nt stores) ----
    for (int p = t; p < BQ * MT; p += NT) {
        const int m = p & (MT - 1), b = p >> 6;
        if (m < nvalid) {
            float dt = dotp_[m * 33 + b];
            __builtin_nontemporal_store(dt * qinv[b] * kins_[m] * expT,
                                        &cosw[(size_t)b * N + n0 + m]);
            float dd = q2[b] + k2s_[m] - 2.0f * dt;
            __builtin_nontemporal_store(1.0f / (1.0f + sqrtf(fmaxf(dd, 0.f))),
                                        &eucw[(size_t)b * N + n0 + m]);
        }
    }

    // ---- exp(scores) -> SC (overlay AH), then coalesced scw out ----
    _Float16* SC = AH;   // element layout: n*256 + (b ^ (n&31))*8 + h
    {
        const int bh0 = wave * 32 + l16;
        #pragma unroll
        for (int cb = 0; cb < 2; ++cb) {
            const int bhc = bh0 + cb * 16;
            const int b = bhc >> 3, h = bhc & 7;
            #pragma unroll
            for (int rb = 0; rb < 4; ++rb) {
                #pragma unroll
                for (int r = 0; r < 4; ++r) {
                    const int n = rb * 16 + lK * 4 + r;
                    SC[n * 256 + ((b ^ (n & 31)) * 8) + h] = (_Float16)as[rb][cb][r];
                }
            }
        }
    }
    __syncthreads();                                           // #8

    #pragma unroll
    for (int p = t; p < BQ * MT; p += NT) {
        const int b = p >> 6, n = p & (MT - 1);
        if (n < nvalid) {
            h8 v = *(const h8*)&SC[n * 256 + ((b ^ (n & 31)) * 8)];
            __builtin_nontemporal_store(v, (h8*)&scw[((size_t)b * N + n0 + n) * NH]);
        }
    }
}

// --------------------------------------------------------------------------
// Kernel 4: learned_sim + fused 3->64->1 MLP + sigmoid per (b,n).
// scw holds exp(score); no expf needed here.
// --------------------------------------------------------------------------
__global__ __launch_bounds__(256) void final_kernel(
    const float* __restrict__ cosw, const float* __restrict__ eucw,
    const _Float16* __restrict__ scw, int N,
    const float* __restrict__ sums,
    const float* __restrict__ fW1, const float* __restrict__ fb1,
    const float* __restrict__ fW2, const float* __restrict__ fb2,
    float* __restrict__ out, int total)
{
    __shared__ float w1s[192], b1s[64], w2s[64];
    __shared__ float sis[BQ * NH];
    __shared__ float b2s;
    const int t = threadIdx.x;
    if (t < 192) w1s[t] = fW1[t];
    else { b1s[t - 192] = fb1[t - 192]; w2s[t - 192] = fW2[t - 192]; }
    sis[t] = 0.125f / sums[t];
    if (t == 0) b2s = fb2[0];
    __syncthreads();

    const int idx = blockIdx.x * 256 + t;
    if (idx >= total) return;
    const int b = idx / N;

    float c = cosw[idx], e = eucw[idx];
    h8 v = *(const h8*)&scw[(size_t)idx * NH];
    float ls = 0.f;
    #pragma unroll
    for (int h = 0; h < NH; ++h)
        ls += (float)v[h] * sis[b * NH + h];

    float logit = b2s;
    #pragma unroll
    for (int j = 0; j < 64; ++j) {
        float hj = fmaf(w1s[j*3], c, fmaf(w1s[j*3+1], e, fmaf(w1s[j*3+2], ls, b1s[j])));
        logit = fmaf(w2s[j], fmaxf(hj, 0.f), logit);
    }
    out[idx] = 1.0f / (1.0f + expf(-logit));
}

// --------------------------------------------------------------------------
extern "C" void kernel_launch(void* const* d_in, const int* in_sizes, int n_in,
                              void* d_out, int out_size, void* d_ws, size_t ws_size,
                              hipStream_t stream)
{
    const float* xq   = (const float*)d_in[0];
    const float* xc   = (const float*)d_in[1];
    const float* temp = (const float*)d_in[2];
    const float* qW1  = (const float*)d_in[3];
    const float* qb1  = (const float*)d_in[4];
    const float* qlg  = (const float*)d_in[5];
    const float* qlb  = (const float*)d_in[6];
    const float* qW2  = (const float*)d_in[7];
    const float* qb2  = (const float*)d_in[8];
    const float* kW1  = (const float*)d_in[9];
    const float* kb1  = (const float*)d_in[10];
    const float* klg  = (const float*)d_in[11];
    const float* klb  = (const float*)d_in[12];
    const float* kW2  = (const float*)d_in[13];
    const float* kb2  = (const float*)d_in[14];
    const float* Wio  = (const float*)d_in[15];
    const float* bio  = (const float*)d_in[16];
    const float* fW1  = (const float*)d_in[17];
    const float* fb1  = (const float*)d_in[18];
    const float* fW2  = (const float*)d_in[19];
    const float* fb2  = (const float*)d_in[20];

    const int N = in_sizes[1] / D;

    float* ws   = (float*)d_ws;
    float* qp   = ws;                         // 16384
    float* qv   = qp + BQ * D;                // 16384 (unused slot kept)
    float* q2   = qv + BQ * D;                // 32
    float* qinv = q2 + BQ;                    // 32
    float* sinv = qinv + BQ;                  // 256 (unused slot kept)
    float* sums = sinv + BQ * NH;             // 256
    float* cosw = sums + BQ * NH;             // BQ*N
    float* eucw = cosw + (size_t)BQ * N;      // BQ*N
    float* fend = eucw + (size_t)BQ * N;

    _Float16* hb  = (_Float16*)fend;
    _Float16* W1m = hb;                       // 262144 each
    _Float16* W2m = W1m + D * D;
    _Float16* qph = W2m + D * D;              // 16384
    _Float16* Wt  = qph + BQ * D;             // 256*512
    _Float16* scw = Wt + BQ * NH * D;         // BQ*N*NH  ([b][n][h])

    wprep_kernel<<<(D * D + 255) / 256, 256, 0, stream>>>(kW1, kW2, W1m, W2m, sums);

    qproj_kernel<<<BQ, 512, 0, stream>>>(xq, qW1, qb1, qlg, qlb, qW2, qb2,
                                         qp, q2, qinv, qph);

    wtld_kernel<<<BQ * NH, 256, 0, stream>>>(qp, Wio, bio, Wt);

    const int nblk = (N + MT - 1) / MT;
    cand_kernel<<<nblk, NT, 0, stream>>>(xc, N, W1m, W2m,
                                         kb1, klg, klb, kb2,
                                         qph, Wt, q2, qinv, temp,
                                         cosw, eucw, scw, sums);

    const int total = BQ * N;
    final_kernel<<<(total + 255) / 256, 256, 0, stream>>>(cosw, eucw, scw, N, sums,
                                                          fW1, fb1, fW2, fb2,
                                                          (float*)d_out, total);
}

// Round 20
// 296.071 us; speedup vs baseline: 2.7574x; 1.0523x over previous
//
#include <hip/hip_runtime.h>
#include <math.h>

#define D    512
#define BQ   32
#define NH   8
#define MT   80
#define RB   5     // row fragments of 16
#define NT   512   // threads per cand block (8 waves)

typedef _Float16 h2  __attribute__((ext_vector_type(2)));
typedef _Float16 h4v __attribute__((ext_vector_type(4)));
typedef _Float16 h8  __attribute__((ext_vector_type(8)));
typedef float    f4  __attribute__((ext_vector_type(4)));

typedef const __attribute__((address_space(1))) void gas_void;
typedef __attribute__((address_space(3))) void las_void;

__device__ __forceinline__ f4 MF(h8 a, h8 b, f4 c) {
  return __builtin_amdgcn_mfma_f32_16x16x32_f16(a, b, c, 0, 0, 0);
}

__device__ __forceinline__ float erf_fast(float x) {
    float ax = fabsf(x);
    float tt = 1.0f / fmaf(0.3275911f, ax, 1.0f);
    float poly = tt * fmaf(tt, fmaf(tt, fmaf(tt, fmaf(tt, 1.061405429f, -1.453152027f),
                          1.421413741f), -0.284496736f), 0.254829592f);
    float r = 1.0f - poly * __expf(-ax * ax);
    return copysignf(r, x);
}
__device__ __forceinline__ float gelu_fast(float x) {
    return 0.5f * x * (1.0f + erf_fast(x * 0.7071067811865475f));
}
__device__ __forceinline__ float gelu_exact(float x) {
    return 0.5f * x * (1.0f + erff(x * 0.7071067811865475f));
}

// --------------------------------------------------------------------------
// Kernel 1: query proj block (h->LN->GELU->qp). 512 threads, 1 col each.
// --------------------------------------------------------------------------
__global__ __launch_bounds__(512) void qproj_kernel(
    const float* __restrict__ xq,
    const float* __restrict__ W1, const float* __restrict__ b1,
    const float* __restrict__ lng, const float* __restrict__ lnb,
    const float* __restrict__ W2, const float* __restrict__ b2,
    float* __restrict__ qp,
    float* __restrict__ q2o, float* __restrict__ qinvo,
    _Float16* __restrict__ qph)
{
    __shared__ float xs[D];
    __shared__ float hs[D];
    __shared__ float red[20];
    const int t = threadIdx.x;
    const int row = blockIdx.x;
    const int wave = t >> 6, lane = t & 63;

    xs[t] = xq[row * D + t];
    __syncthreads();

    float a0 = 0.f;
    for (int i = 0; i < D; i += 4) {
        float4 xv = *(const float4*)&xs[i];
        float4 w0 = *(const float4*)&W1[(size_t)t * D + i];
        a0 += xv.x*w0.x + xv.y*w0.y + xv.z*w0.z + xv.w*w0.w;
    }
    float h0 = a0 + b1[t];

    float s1 = h0, s2 = h0 * h0;
    for (int off = 32; off > 0; off >>= 1) { s1 += __shfl_down(s1, off); s2 += __shfl_down(s2, off); }
    if (lane == 0) { red[wave] = s1; red[8 + wave] = s2; }
    __syncthreads();
    if (t == 0) {
        float sa = 0.f, sb = 0.f;
        #pragma unroll
        for (int w = 0; w < 8; ++w) { sa += red[w]; sb += red[8 + w]; }
        float mu = sa / (float)D;
        red[16] = mu;
        red[17] = rsqrtf(sb / (float)D - mu * mu + 1e-5f);
    }
    __syncthreads();
    float mu = red[16], isd = red[17];
    hs[t] = gelu_exact((h0 - mu) * isd * lng[t] + lnb[t]);
    __syncthreads();

    a0 = 0.f;
    for (int i = 0; i < D; i += 4) {
        float4 gv = *(const float4*)&hs[i];
        float4 w0 = *(const float4*)&W2[(size_t)t * D + i];
        a0 += gv.x*w0.x + gv.y*w0.y + gv.z*w0.z + gv.w*w0.w;
    }
    float p0 = a0 + b2[t];
    qp[row * D + t]  = p0;
    qph[row * D + t] = (_Float16)p0;

    s1 = p0 * p0;
    for (int off = 32; off > 0; off >>= 1) s1 += __shfl_down(s1, off);
    if (lane == 0) red[wave] = s1;
    __syncthreads();
    if (t == 0) {
        float sa = 0.f;
        #pragma unroll
        for (int w = 0; w < 8; ++w) sa += red[w];
        q2o[row] = sa;
        qinvo[row] = 1.0f / sqrtf(sa);
    }
}

// --------------------------------------------------------------------------
// Weight prep: fp16 of W1, W2. Block 0 also zeroes sums.
// --------------------------------------------------------------------------
__global__ __launch_bounds__(256) void wprep_kernel(
    const float* __restrict__ W1, const float* __restrict__ W2,
    _Float16* __restrict__ W1m, _Float16* __restrict__ W2m,
    float* __restrict__ sums)
{
    int idx = blockIdx.x * 256 + threadIdx.x;
    if (blockIdx.x == 0) sums[threadIdx.x] = 0.0f;
    if (idx >= D * D) return;
    W1m[idx] = (_Float16)W1[idx];
    W2m[idx] = (_Float16)W2[idx];
}

// --------------------------------------------------------------------------
// W-tilde prep: q[b,h,d] = qp[b]·Wq[h*64+d] + bq, then
// Wt[b,h,:] = (1/8) * sum_d q[b,h,d] * Wk[h*64+d, :].
// --------------------------------------------------------------------------
__global__ __launch_bounds__(256) void wtld_kernel(
    const float* __restrict__ qp, const float* __restrict__ Wio,
    const float* __restrict__ bio,
    _Float16* __restrict__ Wt)
{
    __shared__ float qpb[D];
    __shared__ float qs[64];
    const int bh = blockIdx.x, b = bh >> 3, h = bh & 7;
    const int t = threadIdx.x;

    qpb[t]       = qp[b * D + t];
    qpb[t + 256] = qp[b * D + t + 256];
    __syncthreads();

    {
        const int d = t >> 2, part = t & 3;
        const float* Wq = Wio + (size_t)(h * 64 + d) * D + part * 128;
        const float* xp = qpb + part * 128;
        float a = 0.f;
        #pragma unroll 8
        for (int i = 0; i < 128; i += 4) {
            float4 xv = *(const float4*)&xp[i];
            float4 wv = *(const float4*)&Wq[i];
            a += xv.x*wv.x + xv.y*wv.y + xv.z*wv.z + xv.w*wv.w;
        }
        a += __shfl_xor(a, 1);
        a += __shfl_xor(a, 2);
        if (part == 0) qs[d] = (a + bio[h * 64 + d]) * 0.125f;
    }
    __syncthreads();

    const float* Wk = Wio + (size_t)D * D + (size_t)(h * 64) * D;
    float a0 = 0.f, a1 = 0.f;
    #pragma unroll 4
    for (int d = 0; d < 64; ++d) {
        float q = qs[d];
        a0 += q * Wk[(size_t)d * D + t];
        a1 += q * Wk[(size_t)d * D + t + 256];
    }
    Wt[(size_t)bh * D + t]       = (_Float16)a0;
    Wt[(size_t)bh * D + t + 256] = (_Float16)a1;
}

// --------------------------------------------------------------------------
// Kernel 2: candidate path. 80 rows/block, 512 threads (8 waves).
// acc[5][4] per wave; 2-buffer gll rotation; per-rb stats reduction to
// keep register demand under the allocator's 128 target.
// --------------------------------------------------------------------------
__global__ __launch_bounds__(NT) void cand_kernel(
    const float* __restrict__ xc, int N,
    const _Float16* __restrict__ W1m, const _Float16* __restrict__ W2m,
    const float* __restrict__ b1, const float* __restrict__ lng,
    const float* __restrict__ lnb, const float* __restrict__ b2,
    const _Float16* __restrict__ qph,
    const _Float16* __restrict__ Wt,
    const float* __restrict__ q2, const float* __restrict__ qinv,
    const float* __restrict__ tempp,
    float* __restrict__ cosw, float* __restrict__ eucw,
    _Float16* __restrict__ scw, float* __restrict__ sums)
{
    __shared__ _Float16 AH[MT * D];                      // 80 KB (swizzled); reused as SC
    __shared__ __align__(16) unsigned char WBUF[65536];  // 2 x 32 KB weight staging
    __shared__ __align__(16) float scr[MT * 33];         // dotp aliases lnred (10.5 KB)
    __shared__ float k2p_[8 * MT];                       // 2.5 KB
    __shared__ float k2s_[MT], kins_[MT];
    __shared__ float lnmu_[MT], lnisd_[MT];

    float*  dotp_  = scr;
    float2* lnred_ = (float2*)scr;

    const int t    = threadIdx.x;
    const int wave = t >> 6;
    const int lane = t & 63;
    const int l16  = lane & 15;
    const int lK   = lane >> 4;
    const int wcol = wave * 64;
    const int n0   = blockIdx.x * MT;
    const int nvalid = min(MT, N - n0);
    const float expT = expf(tempp[0]);
    const f4 fz = {0.f, 0.f, 0.f, 0.f};

    // ---- stage X (nt loads; fp16, swizzled) ----
    #pragma unroll
    for (int i = 0; i < 20; ++i) {
        int g = t + NT * i;                  // 0 .. 10239 (float4 index)
        int row = g >> 7;
        int c4 = (g & 127) * 4;
        f4 v = fz;
        if (n0 + row < N)
            v = __builtin_nontemporal_load((const f4*)(xc + (size_t)(n0 + row) * D + c4));
        h4v hi;
        #pragma unroll
        for (int e = 0; e < 4; ++e) hi[e] = (_Float16)v[e];
        *(h4v*)&AH[row * D + (c4 ^ ((row & 7) << 3))] = hi;
    }
    __syncthreads();                                           // #1

    const int sw = (l16 & 7) << 3;

    unsigned rdO[4];
    #pragma unroll
    for (int cb = 0; cb < 4; ++cb) {
        const int col = wcol + cb * 16 + l16;
        rdO[cb] = (unsigned)(col * 64 + ((lK ^ ((col >> 1) & 3)) << 4));
    }
    unsigned dstO[4];
    #pragma unroll
    for (int j = 0; j < 4; ++j) dstO[j] = (unsigned)(wave * 4096 + j * 1024);

    auto gemm = [&](const _Float16* __restrict__ Wm, f4 (&acc)[RB][4]) {
        const _Float16* srcB[4];
        #pragma unroll
        for (int j = 0; j < 4; ++j) {
            const int col  = (wave * 4 + j) * 16 + (lane >> 2);
            const int slot = (lane & 3) ^ ((col >> 1) & 3);
            srcB[j] = Wm + (size_t)col * D + slot * 8;
        }
        auto stage = [&](int c, int buf) {
            #pragma unroll
            for (int j = 0; j < 4; ++j)
                __builtin_amdgcn_global_load_lds((gas_void*)(srcB[j] + c * 32),
                    (las_void*)(WBUF + buf * 32768 + dstO[j]), 16, 0, 0);
        };
        auto compute = [&](int c, int buf) {
            const unsigned char* wb = WBUF + buf * 32768;
            h8 bh[4];
            #pragma unroll
            for (int cb = 0; cb < 4; ++cb) bh[cb] = *(const h8*)(wb + rdO[cb]);
            const int ksw = (c * 32 + lK * 8) ^ sw;
            h8 ah[RB];
            #pragma unroll
            for (int rb = 0; rb < RB; ++rb)
                ah[rb] = *(const h8*)&AH[(rb * 16 + l16) * D + ksw];
            #pragma unroll
            for (int rb = 0; rb < RB; ++rb)
                #pragma unroll
                for (int cb = 0; cb < 4; ++cb)
                    acc[rb][cb] = MF(ah[rb], bh[cb], acc[rb][cb]);
        };
        stage(0, 0); stage(1, 1);
        #pragma unroll 1
        for (int c = 0; c < 14; ++c) {
            const int buf = c & 1;
            asm volatile("s_waitcnt vmcnt(4)" ::: "memory");
            __builtin_amdgcn_sched_barrier(0);
            compute(c, buf);
            asm volatile("s_waitcnt lgkmcnt(0)" ::: "memory");
            __builtin_amdgcn_sched_barrier(0);
            stage(c + 2, buf);
            __builtin_amdgcn_sched_barrier(0);
        }
        asm volatile("s_waitcnt vmcnt(4)" ::: "memory");
        __builtin_amdgcn_sched_barrier(0);
        compute(14, 0);
        asm volatile("s_waitcnt vmcnt(0)" ::: "memory");
        __builtin_amdgcn_sched_barrier(0);
        compute(15, 1);
    };

    f4 acc[RB][4];
    #pragma unroll
    for (int rb = 0; rb < RB; ++rb)
        #pragma unroll
        for (int cb = 0; cb < 4; ++cb) acc[rb][cb] = fz;

    // ---- GEMM1: h = x @ W1.T + b1 ----
    gemm(W1m, acc);

    // per-rb stats (keeps live registers low)
    #pragma unroll
    for (int rb = 0; rb < RB; ++rb) {
        float s1a[4] = {0.f, 0.f, 0.f, 0.f};
        float s2a[4] = {0.f, 0.f, 0.f, 0.f};
        #pragma unroll
        for (int cb = 0; cb < 4; ++cb) {
            const float bb = b1[wcol + cb * 16 + l16];
            #pragma unroll
            for (int r = 0; r < 4; ++r) {
                float v = acc[rb][cb][r] + bb;
                acc[rb][cb][r] = v;
                s1a[r] += v;
                s2a[r] += v * v;
            }
        }
        #pragma unroll
        for (int mm = 1; mm < 16; mm <<= 1)
            #pragma unroll
            for (int r = 0; r < 4; ++r) {
                s1a[r] += __shfl_xor(s1a[r], mm);
                s2a[r] += __shfl_xor(s2a[r], mm);
            }
        if (l16 == 0) {
            #pragma unroll
            for (int r = 0; r < 4; ++r)
                lnred_[wave * MT + rb * 16 + lK * 4 + r] = make_float2(s1a[r], s2a[r]);
        }
    }
    __syncthreads();                                           // #2
    if (t < MT) {
        float sa = 0.f, sb = 0.f;
        #pragma unroll
        for (int w = 0; w < 8; ++w) { sa += lnred_[w * MT + t].x; sb += lnred_[w * MT + t].y; }
        float mu = sa * (1.0f / 512.0f);
        float var = sb * (1.0f / 512.0f) - mu * mu;
        lnmu_[t] = mu;
        lnisd_[t] = rsqrtf(var + 1e-5f);
    }
    __syncthreads();                                           // #3

    // ---- LN + GELU in regs, convert g -> AH ----
    #pragma unroll
    for (int rb = 0; rb < RB; ++rb)
        #pragma unroll
        for (int cb = 0; cb < 4; ++cb) {
            const int j = wcol + cb * 16 + l16;
            const float gg = lng[j], bb = lnb[j];
            #pragma unroll
            for (int r = 0; r < 4; ++r) {
                const int m = rb * 16 + lK * 4 + r;
                float v = (acc[rb][cb][r] - lnmu_[m]) * lnisd_[m] * gg + bb;
                AH[m * D + (j ^ ((m & 7) << 3))] = (_Float16)gelu_fast(v);
            }
        }
    __syncthreads();                                           // #4

    // ---- GEMM2: kp = g @ W2.T + b2 ----
    #pragma unroll
    for (int rb = 0; rb < RB; ++rb)
        #pragma unroll
        for (int cb = 0; cb < 4; ++cb) acc[rb][cb] = fz;
    gemm(W2m, acc);

    #pragma unroll
    for (int rb = 0; rb < RB; ++rb) {
        float ss[4] = {0.f, 0.f, 0.f, 0.f};
        #pragma unroll
        for (int cb = 0; cb < 4; ++cb) {
            const float bb = b2[wcol + cb * 16 + l16];
            #pragma unroll
            for (int r = 0; r < 4; ++r) {
                float v = acc[rb][cb][r] + bb;
                acc[rb][cb][r] = v;
                ss[r] += v * v;
            }
        }
        #pragma unroll
        for (int mm = 1; mm < 16; mm <<= 1)
            #pragma unroll
            for (int r = 0; r < 4; ++r)
                ss[r] += __shfl_xor(ss[r], mm);
        if (l16 == 0) {
            #pragma unroll
            for (int r = 0; r < 4; ++r)
                k2p_[wave * MT + rb * 16 + lK * 4 + r] = ss[r];
        }
    }
    __syncthreads();                                           // #5
    // convert kp (fp16) -> AH
    #pragma unroll
    for (int rb = 0; rb < RB; ++rb)
        #pragma unroll
        for (int cb = 0; cb < 4; ++cb) {
            const int j = wcol + cb * 16 + l16;
            #pragma unroll
            for (int r = 0; r < 4; ++r) {
                const int m = rb * 16 + lK * 4 + r;
                AH[m * D + (j ^ ((m & 7) << 3))] = (_Float16)acc[rb][cb][r];
            }
        }
    __syncthreads();                                           // #6

    if (t < MT) {
        float sa = 0.f;
        #pragma unroll
        for (int w = 0; w < 8; ++w) sa += k2p_[w * MT + t];
        k2s_[t] = sa;
        kins_[t] = rsqrtf(fmaxf(sa, 1e-30f));
    }

    // ---- scores: kp @ Wt.T via gll-staged Wt (4-buf rotation, 3-ahead) ----
    f4 as[RB][2];
    #pragma unroll
    for (int rb = 0; rb < RB; ++rb) { as[rb][0] = fz; as[rb][1] = fz; }
    {
        const _Float16* wsrcB[2];
        #pragma unroll
        for (int j = 0; j < 2; ++j) {
            const int rr   = j * 16 + (lane >> 2);
            const int slot = (lane & 3) ^ ((rr >> 1) & 3);
            wsrcB[j] = Wt + (size_t)(wave * 32 + rr) * D + slot * 8;
        }
        auto stageWT = [&](int c, int buf) {
            #pragma unroll
            for (int j = 0; j < 2; ++j)
                __builtin_amdgcn_global_load_lds((gas_void*)(wsrcB[j] + c * 32),
                    (las_void*)(WBUF + buf * 16384 + wave * 2048 + j * 1024), 16, 0, 0);
        };
        const unsigned wrd0 = (unsigned)(l16 * 64 + ((lK ^ ((l16 >> 1) & 3)) << 4));
        auto scoreChunk = [&](int c, int buf) {
            const unsigned char* wb = WBUF + buf * 16384 + wave * 2048;
            h8 w0 = *(const h8*)(wb + wrd0);
            h8 w1 = *(const h8*)(wb + 1024 + wrd0);
            const int ksw = (c * 32 + lK * 8) ^ sw;
            #pragma unroll
            for (int rb = 0; rb < RB; ++rb) {
                h8 a = *(const h8*)&AH[(rb * 16 + l16) * D + ksw];
                as[rb][0] = MF(a, w0, as[rb][0]);
                as[rb][1] = MF(a, w1, as[rb][1]);
            }
        };
        stageWT(0, 0); stageWT(1, 1); stageWT(2, 2);
        #pragma unroll 4
        for (int c = 0; c < 12; ++c) {
            asm volatile("s_waitcnt vmcnt(4)" ::: "memory");
            __builtin_amdgcn_sched_barrier(0);
            scoreChunk(c, c & 3);
            asm volatile("s_waitcnt lgkmcnt(0)" ::: "memory");
            __builtin_amdgcn_sched_barrier(0);
            stageWT(c + 3, (c + 3) & 3);
            __builtin_amdgcn_sched_barrier(0);
        }
        asm volatile("s_waitcnt vmcnt(4)" ::: "memory");
        __builtin_amdgcn_sched_barrier(0);
        scoreChunk(12, 0);
        asm volatile("s_waitcnt lgkmcnt(0)" ::: "memory");
        __builtin_amdgcn_sched_barrier(0);
        stageWT(15, 3);
        __builtin_amdgcn_sched_barrier(0);
        asm volatile("s_waitcnt vmcnt(4)" ::: "memory");
        __builtin_amdgcn_sched_barrier(0);
        scoreChunk(13, 1);
        asm volatile("s_waitcnt vmcnt(2)" ::: "memory");
        __builtin_amdgcn_sched_barrier(0);
        scoreChunk(14, 2);
        asm volatile("s_waitcnt vmcnt(0)" ::: "memory");
        __builtin_amdgcn_sched_barrier(0);
        scoreChunk(15, 3);
    }

    // ---- exp(scores) in place; fused softmax-denominator partial sums ----
    {
        #pragma unroll
        for (int cb = 0; cb < 2; ++cb)
            #pragma unroll
            for (int rb = 0; rb < RB; ++rb)
                #pragma unroll
                for (int r = 0; r < 4; ++r)
                    as[rb][cb][r] = __expf(as[rb][cb][r]);
        float part[2] = {0.f, 0.f};
        #pragma unroll
        for (int cb = 0; cb < 2; ++cb)
            #pragma unroll
            for (int rb = 0; rb < RB; ++rb)
                #pragma unroll
                for (int r = 0; r < 4; ++r) {
                    const int n = rb * 16 + lK * 4 + r;
                    if (n < nvalid) part[cb] += as[rb][cb][r];
                }
        #pragma unroll
        for (int cb = 0; cb < 2; ++cb) {
            part[cb] += __shfl_xor(part[cb], 16);
            part[cb] += __shfl_xor(part[cb], 32);
        }
        if (lK == 0) {
            atomicAdd(&sums[wave * 32 + l16], part[0]);
            atomicAdd(&sums[wave * 32 + 16 + l16], part[1]);
        }
    }

    // ---- dots = kp @ qp.T via MFMA (10 units = 5 rb x 2 cbq over 8 waves) ----
    {
        auto dot_unit = [&](int u) {
            const int rb = u % RB, cbq = u / RB;
            f4 ad = fz;
            const int ra = (rb * 16 + l16) * D;
            const int j = cbq * 16 + l16;
            #pragma unroll 2
            for (int ks = 0; ks < 16; ++ks) {
                const int k0 = ks * 32 + lK * 8;
                const int ksw = k0 ^ sw;
                h8 ah0 = *(const h8*)&AH[ra + ksw];
                h8 bh = *(const h8*)&qph[j * D + k0];
                ad = MF(ah0, bh, ad);
            }
            #pragma unroll
            for (int r = 0; r < 4; ++r)
                dotp_[(rb * 16 + lK * 4 + r) * 33 + cbq * 16 + l16] = ad[r];
        };
        dot_unit(wave);
        if (wave < 2) dot_unit(wave + 8);
    }
    __syncthreads();                                           // #7

    // ---- cos / euc outputs (nt stores) ----
    for (int p = t; p < BQ * MT; p += NT) {
        const int b = p / MT, m = p - b * MT;
        if (m < nvalid) {
            float dt = dotp_[m * 33 + b];
            __builtin_nontemporal_store(dt * qinv[b] * kins_[m] * expT,
                                        &cosw[(size_t)b * N + n0 + m]);
            float dd = q2[b] + k2s_[m] - 2.0f * dt;
            __builtin_nontemporal_store(1.0f / (1.0f + sqrtf(fmaxf(dd, 0.f))),
                                        &eucw[(size_t)b * N + n0 + m]);
        }
    }

    // ---- exp(scores) -> SC (overlay AH), then coalesced scw out ----
    _Float16* SC = AH;   // element layout: n*256 + (b ^ (n&31))*8 + h
    {
        const int bh0 = wave * 32 + l16;
        #pragma unroll
        for (int cb = 0; cb < 2; ++cb) {
            const int bhc = bh0 + cb * 16;
            const int b = bhc >> 3, h = bhc & 7;
            #pragma unroll
            for (int rb = 0; rb < RB; ++rb) {
                #pragma unroll
                for (int r = 0; r < 4; ++r) {
                    const int n = rb * 16 + lK * 4 + r;
                    SC[n * 256 + ((b ^ (n & 31)) * 8) + h] = (_Float16)as[rb][cb][r];
                }
            }
        }
    }
    __syncthreads();                                           // #8

    for (int p = t; p < BQ * MT; p += NT) {
        const int b = p / MT, n = p - b * MT;
        if (n < nvalid) {
            h8 v = *(const h8*)&SC[n * 256 + ((b ^ (n & 31)) * 8)];
            __builtin_nontemporal_store(v, (h8*)&scw[((size_t)b * N + n0 + n) * NH]);
        }
    }
}

// --------------------------------------------------------------------------
// Kernel 4: learned_sim + fused 3->64->1 MLP + sigmoid per (b,n).
// --------------------------------------------------------------------------
__global__ __launch_bounds__(256) void final_kernel(
    const float* __restrict__ cosw, const float* __restrict__ eucw,
    const _Float16* __restrict__ scw, int N,
    const float* __restrict__ sums,
    const float* __restrict__ fW1, const float* __restrict__ fb1,
    const float* __restrict__ fW2, const float* __restrict__ fb2,
    float* __restrict__ out, int total)
{
    __shared__ float w1s[192], b1s[64], w2s[64];
    __shared__ float sis[BQ * NH];
    __shared__ float b2s;
    const int t = threadIdx.x;
    if (t < 192) w1s[t] = fW1[t];
    else { b1s[t - 192] = fb1[t - 192]; w2s[t - 192] = fW2[t - 192]; }
    sis[t] = 0.125f / sums[t];
    if (t == 0) b2s = fb2[0];
    __syncthreads();

    const int idx = blockIdx.x * 256 + t;
    if (idx >= total) return;
    const int b = idx / N;

    float c = cosw[idx], e = eucw[idx];
    h8 v = *(const h8*)&scw[(size_t)idx * NH];
    float ls = 0.f;
    #pragma unroll
    for (int h = 0; h < NH; ++h)
        ls += (float)v[h] * sis[b * NH + h];

    float logit = b2s;
    #pragma unroll
    for (int j = 0; j < 64; ++j) {
        float hj = fmaf(w1s[j*3], c, fmaf(w1s[j*3+1], e, fmaf(w1s[j*3+2], ls, b1s[j])));
        logit = fmaf(w2s[j], fmaxf(hj, 0.f), logit);
    }
    out[idx] = 1.0f / (1.0f + expf(-logit));
}

// --------------------------------------------------------------------------
extern "C" void kernel_launch(void* const* d_in, const int* in_sizes, int n_in,
                              void* d_out, int out_size, void* d_ws, size_t ws_size,
                              hipStream_t stream)
{
    const float* xq   = (const float*)d_in[0];
    const float* xc   = (const float*)d_in[1];
    const float* temp = (const float*)d_in[2];
    const float* qW1  = (const float*)d_in[3];
    const float* qb1  = (const float*)d_in[4];
    const float* qlg  = (const float*)d_in[5];
    const float* qlb  = (const float*)d_in[6];
    const float* qW2  = (const float*)d_in[7];
    const float* qb2  = (const float*)d_in[8];
    const float* kW1  = (const float*)d_in[9];
    const float* kb1  = (const float*)d_in[10];
    const float* klg  = (const float*)d_in[11];
    const float* klb  = (const float*)d_in[12];
    const float* kW2  = (const float*)d_in[13];
    const float* kb2  = (const float*)d_in[14];
    const float* Wio  = (const float*)d_in[15];
    const float* bio  = (const float*)d_in[16];
    const float* fW1  = (const float*)d_in[17];
    const float* fb1  = (const float*)d_in[18];
    const float* fW2  = (const float*)d_in[19];
    const float* fb2  = (const float*)d_in[20];

    const int N = in_sizes[1] / D;

    float* ws   = (float*)d_ws;
    float* qp   = ws;                         // 16384
    float* qv   = qp + BQ * D;                // 16384 (unused slot kept)
    float* q2   = qv + BQ * D;                // 32
    float* qinv = q2 + BQ;                    // 32
    float* sinv = qinv + BQ;                  // 256 (unused slot kept)
    float* sums = sinv + BQ * NH;             // 256
    float* cosw = sums + BQ * NH;             // BQ*N
    float* eucw = cosw + (size_t)BQ * N;      // BQ*N
    float* fend = eucw + (size_t)BQ * N;

    _Float16* hb  = (_Float16*)fend;
    _Float16* W1m = hb;                       // 262144 each
    _Float16* W2m = W1m + D * D;
    _Float16* qph = W2m + D * D;              // 16384
    _Float16* Wt  = qph + BQ * D;             // 256*512
    _Float16* scw = Wt + BQ * NH * D;         // BQ*N*NH  ([b][n][h])

    wprep_kernel<<<(D * D + 255) / 256, 256, 0, stream>>>(kW1, kW2, W1m, W2m, sums);

    qproj_kernel<<<BQ, 512, 0, stream>>>(xq, qW1, qb1, qlg, qlb, qW2, qb2,
                                         qp, q2, qinv, qph);

    wtld_kernel<<<BQ * NH, 256, 0, stream>>>(qp, Wio, bio, Wt);

    const int nblk = (N + MT - 1) / MT;
    cand_kernel<<<nblk, NT, 0, stream>>>(xc, N, W1m, W2m,
                                         kb1, klg, klb, kb2,
                                         qph, Wt, q2, qinv, temp,
                                         cosw, eucw, scw, sums);

    const int total = BQ * N;
    final_kernel<<<(total + 255) / 256, 256, 0, stream>>>(cosw, eucw, scw, N, sums,
                                                          fW1, fb1, fW2, fb2,
                                                          (float*)d_out, total);
}

// Round 21
// 294.801 us; speedup vs baseline: 2.7693x; 1.0043x over previous
//
#include <hip/hip_runtime.h>
#include <math.h>

#define D    512
#define BQ   32
#define NH   8
#define MT   80
#define RB   5     // row fragments of 16
#define NT   512   // threads per cand block (8 waves)

typedef _Float16 h2  __attribute__((ext_vector_type(2)));
typedef _Float16 h4v __attribute__((ext_vector_type(4)));
typedef _Float16 h8  __attribute__((ext_vector_type(8)));
typedef float    f4  __attribute__((ext_vector_type(4)));

typedef const __attribute__((address_space(1))) void gas_void;
typedef __attribute__((address_space(3))) void las_void;

__device__ __forceinline__ f4 MF(h8 a, h8 b, f4 c) {
  return __builtin_amdgcn_mfma_f32_16x16x32_f16(a, b, c, 0, 0, 0);
}

__device__ __forceinline__ float erf_fast(float x) {
    float ax = fabsf(x);
    float tt = 1.0f / fmaf(0.3275911f, ax, 1.0f);
    float poly = tt * fmaf(tt, fmaf(tt, fmaf(tt, fmaf(tt, 1.061405429f, -1.453152027f),
                          1.421413741f), -0.284496736f), 0.254829592f);
    float r = 1.0f - poly * __expf(-ax * ax);
    return copysignf(r, x);
}
__device__ __forceinline__ float gelu_fast(float x) {
    return 0.5f * x * (1.0f + erf_fast(x * 0.7071067811865475f));
}
__device__ __forceinline__ float gelu_exact(float x) {
    return 0.5f * x * (1.0f + erff(x * 0.7071067811865475f));
}

// --------------------------------------------------------------------------
// Kernel 1: query proj block (h->LN->GELU->qp). 512 threads, 1 col each.
// --------------------------------------------------------------------------
__global__ __launch_bounds__(512) void qproj_kernel(
    const float* __restrict__ xq,
    const float* __restrict__ W1, const float* __restrict__ b1,
    const float* __restrict__ lng, const float* __restrict__ lnb,
    const float* __restrict__ W2, const float* __restrict__ b2,
    float* __restrict__ qp,
    float* __restrict__ q2o, float* __restrict__ qinvo,
    _Float16* __restrict__ qph)
{
    __shared__ float xs[D];
    __shared__ float hs[D];
    __shared__ float red[20];
    const int t = threadIdx.x;
    const int row = blockIdx.x;
    const int wave = t >> 6, lane = t & 63;

    xs[t] = xq[row * D + t];
    __syncthreads();

    float a0 = 0.f;
    for (int i = 0; i < D; i += 4) {
        float4 xv = *(const float4*)&xs[i];
        float4 w0 = *(const float4*)&W1[(size_t)t * D + i];
        a0 += xv.x*w0.x + xv.y*w0.y + xv.z*w0.z + xv.w*w0.w;
    }
    float h0 = a0 + b1[t];

    float s1 = h0, s2 = h0 * h0;
    for (int off = 32; off > 0; off >>= 1) { s1 += __shfl_down(s1, off); s2 += __shfl_down(s2, off); }
    if (lane == 0) { red[wave] = s1; red[8 + wave] = s2; }
    __syncthreads();
    if (t == 0) {
        float sa = 0.f, sb = 0.f;
        #pragma unroll
        for (int w = 0; w < 8; ++w) { sa += red[w]; sb += red[8 + w]; }
        float mu = sa / (float)D;
        red[16] = mu;
        red[17] = rsqrtf(sb / (float)D - mu * mu + 1e-5f);
    }
    __syncthreads();
    float mu = red[16], isd = red[17];
    hs[t] = gelu_exact((h0 - mu) * isd * lng[t] + lnb[t]);
    __syncthreads();

    a0 = 0.f;
    for (int i = 0; i < D; i += 4) {
        float4 gv = *(const float4*)&hs[i];
        float4 w0 = *(const float4*)&W2[(size_t)t * D + i];
        a0 += gv.x*w0.x + gv.y*w0.y + gv.z*w0.z + gv.w*w0.w;
    }
    float p0 = a0 + b2[t];
    qp[row * D + t]  = p0;
    qph[row * D + t] = (_Float16)p0;

    s1 = p0 * p0;
    for (int off = 32; off > 0; off >>= 1) s1 += __shfl_down(s1, off);
    if (lane == 0) red[wave] = s1;
    __syncthreads();
    if (t == 0) {
        float sa = 0.f;
        #pragma unroll
        for (int w = 0; w < 8; ++w) sa += red[w];
        q2o[row] = sa;
        qinvo[row] = 1.0f / sqrtf(sa);
    }
}

// --------------------------------------------------------------------------
// Weight prep: fp16 of W1, W2. Block 0 also zeroes sums.
// --------------------------------------------------------------------------
__global__ __launch_bounds__(256) void wprep_kernel(
    const float* __restrict__ W1, const float* __restrict__ W2,
    _Float16* __restrict__ W1m, _Float16* __restrict__ W2m,
    float* __restrict__ sums)
{
    int idx = blockIdx.x * 256 + threadIdx.x;
    if (blockIdx.x == 0) sums[threadIdx.x] = 0.0f;
    if (idx >= D * D) return;
    W1m[idx] = (_Float16)W1[idx];
    W2m[idx] = (_Float16)W2[idx];
}

// --------------------------------------------------------------------------
// W-tilde prep: q[b,h,d] = qp[b]·Wq[h*64+d] + bq, then
// Wt[b,h,:] = (1/8) * sum_d q[b,h,d] * Wk[h*64+d, :].
// --------------------------------------------------------------------------
__global__ __launch_bounds__(256) void wtld_kernel(
    const float* __restrict__ qp, const float* __restrict__ Wio,
    const float* __restrict__ bio,
    _Float16* __restrict__ Wt)
{
    __shared__ float qpb[D];
    __shared__ float qs[64];
    const int bh = blockIdx.x, b = bh >> 3, h = bh & 7;
    const int t = threadIdx.x;

    qpb[t]       = qp[b * D + t];
    qpb[t + 256] = qp[b * D + t + 256];
    __syncthreads();

    {
        const int d = t >> 2, part = t & 3;
        const float* Wq = Wio + (size_t)(h * 64 + d) * D + part * 128;
        const float* xp = qpb + part * 128;
        float a = 0.f;
        #pragma unroll 8
        for (int i = 0; i < 128; i += 4) {
            float4 xv = *(const float4*)&xp[i];
            float4 wv = *(const float4*)&Wq[i];
            a += xv.x*wv.x + xv.y*wv.y + xv.z*wv.z + xv.w*wv.w;
        }
        a += __shfl_xor(a, 1);
        a += __shfl_xor(a, 2);
        if (part == 0) qs[d] = (a + bio[h * 64 + d]) * 0.125f;
    }
    __syncthreads();

    const float* Wk = Wio + (size_t)D * D + (size_t)(h * 64) * D;
    float a0 = 0.f, a1 = 0.f;
    #pragma unroll 4
    for (int d = 0; d < 64; ++d) {
        float q = qs[d];
        a0 += q * Wk[(size_t)d * D + t];
        a1 += q * Wk[(size_t)d * D + t + 256];
    }
    Wt[(size_t)bh * D + t]       = (_Float16)a0;
    Wt[(size_t)bh * D + t + 256] = (_Float16)a1;
}

// --------------------------------------------------------------------------
// Kernel 2: candidate path. 80 rows/block, 512 threads (8 waves).
// acc[5][4] per wave; 2-buffer gll rotation. Spill-lean: per-rb A-fragment
// interleave in GEMM; dots phase runs before scores so as[] isn't held
// across it.
// --------------------------------------------------------------------------
__global__ __launch_bounds__(NT) void cand_kernel(
    const float* __restrict__ xc, int N,
    const _Float16* __restrict__ W1m, const _Float16* __restrict__ W2m,
    const float* __restrict__ b1, const float* __restrict__ lng,
    const float* __restrict__ lnb, const float* __restrict__ b2,
    const _Float16* __restrict__ qph,
    const _Float16* __restrict__ Wt,
    const float* __restrict__ q2, const float* __restrict__ qinv,
    const float* __restrict__ tempp,
    float* __restrict__ cosw, float* __restrict__ eucw,
    _Float16* __restrict__ scw, float* __restrict__ sums)
{
    __shared__ _Float16 AH[MT * D];                      // 80 KB (swizzled); reused as SC
    __shared__ __align__(16) unsigned char WBUF[65536];  // 2 x 32 KB weight staging
    __shared__ __align__(16) float scr[MT * 33];         // dotp aliases lnred (10.5 KB)
    __shared__ float k2p_[8 * MT];                       // 2.5 KB
    __shared__ float k2s_[MT], kins_[MT];
    __shared__ float lnmu_[MT], lnisd_[MT];

    float*  dotp_  = scr;
    float2* lnred_ = (float2*)scr;

    const int t    = threadIdx.x;
    const int wave = t >> 6;
    const int lane = t & 63;
    const int l16  = lane & 15;
    const int lK   = lane >> 4;
    const int wcol = wave * 64;
    const int n0   = blockIdx.x * MT;
    const int nvalid = min(MT, N - n0);
    const float expT = expf(tempp[0]);
    const f4 fz = {0.f, 0.f, 0.f, 0.f};

    // ---- stage X (nt loads; fp16, swizzled) ----
    #pragma unroll
    for (int i = 0; i < 20; ++i) {
        int g = t + NT * i;
        int row = g >> 7;
        int c4 = (g & 127) * 4;
        f4 v = fz;
        if (n0 + row < N)
            v = __builtin_nontemporal_load((const f4*)(xc + (size_t)(n0 + row) * D + c4));
        h4v hi;
        #pragma unroll
        for (int e = 0; e < 4; ++e) hi[e] = (_Float16)v[e];
        *(h4v*)&AH[row * D + (c4 ^ ((row & 7) << 3))] = hi;
    }
    __syncthreads();                                           // #1

    const int sw = (l16 & 7) << 3;

    unsigned rdO[4];
    #pragma unroll
    for (int cb = 0; cb < 4; ++cb) {
        const int col = wcol + cb * 16 + l16;
        rdO[cb] = (unsigned)(col * 64 + ((lK ^ ((col >> 1) & 3)) << 4));
    }
    unsigned dstO[4];
    #pragma unroll
    for (int j = 0; j < 4; ++j) dstO[j] = (unsigned)(wave * 4096 + j * 1024);

    auto gemm = [&](const _Float16* __restrict__ Wm, f4 (&acc)[RB][4]) {
        const _Float16* srcB[4];
        #pragma unroll
        for (int j = 0; j < 4; ++j) {
            const int col  = (wave * 4 + j) * 16 + (lane >> 2);
            const int slot = (lane & 3) ^ ((col >> 1) & 3);
            srcB[j] = Wm + (size_t)col * D + slot * 8;
        }
        auto stage = [&](int c, int buf) {
            #pragma unroll
            for (int j = 0; j < 4; ++j)
                __builtin_amdgcn_global_load_lds((gas_void*)(srcB[j] + c * 32),
                    (las_void*)(WBUF + buf * 32768 + dstO[j]), 16, 0, 0);
        };
        auto compute = [&](int c, int buf) {
            const unsigned char* wb = WBUF + buf * 32768;
            h8 bh[4];
            #pragma unroll
            for (int cb = 0; cb < 4; ++cb) bh[cb] = *(const h8*)(wb + rdO[cb]);
            const int ksw = (c * 32 + lK * 8) ^ sw;
            // per-rb A-fragment interleave: live ah = 1 (spill-lean)
            #pragma unroll
            for (int rb = 0; rb < RB; ++rb) {
                h8 ah = *(const h8*)&AH[(rb * 16 + l16) * D + ksw];
                #pragma unroll
                for (int cb = 0; cb < 4; ++cb)
                    acc[rb][cb] = MF(ah, bh[cb], acc[rb][cb]);
            }
        };
        stage(0, 0); stage(1, 1);
        #pragma unroll 1
        for (int c = 0; c < 14; ++c) {
            const int buf = c & 1;
            asm volatile("s_waitcnt vmcnt(4)" ::: "memory");
            __builtin_amdgcn_sched_barrier(0);
            compute(c, buf);
            asm volatile("s_waitcnt lgkmcnt(0)" ::: "memory");
            __builtin_amdgcn_sched_barrier(0);
            stage(c + 2, buf);
            __builtin_amdgcn_sched_barrier(0);
        }
        asm volatile("s_waitcnt vmcnt(4)" ::: "memory");
        __builtin_amdgcn_sched_barrier(0);
        compute(14, 0);
        asm volatile("s_waitcnt vmcnt(0)" ::: "memory");
        __builtin_amdgcn_sched_barrier(0);
        compute(15, 1);
    };

    f4 acc[RB][4];
    #pragma unroll
    for (int rb = 0; rb < RB; ++rb)
        #pragma unroll
        for (int cb = 0; cb < 4; ++cb) acc[rb][cb] = fz;

    // ---- GEMM1: h = x @ W1.T + b1 ----
    gemm(W1m, acc);

    #pragma unroll
    for (int rb = 0; rb < RB; ++rb) {
        float s1a[4] = {0.f, 0.f, 0.f, 0.f};
        float s2a[4] = {0.f, 0.f, 0.f, 0.f};
        #pragma unroll
        for (int cb = 0; cb < 4; ++cb) {
            const float bb = b1[wcol + cb * 16 + l16];
            #pragma unroll
            for (int r = 0; r < 4; ++r) {
                float v = acc[rb][cb][r] + bb;
                acc[rb][cb][r] = v;
                s1a[r] += v;
                s2a[r] += v * v;
            }
        }
        #pragma unroll
        for (int mm = 1; mm < 16; mm <<= 1)
            #pragma unroll
            for (int r = 0; r < 4; ++r) {
                s1a[r] += __shfl_xor(s1a[r], mm);
                s2a[r] += __shfl_xor(s2a[r], mm);
            }
        if (l16 == 0) {
            #pragma unroll
            for (int r = 0; r < 4; ++r)
                lnred_[wave * MT + rb * 16 + lK * 4 + r] = make_float2(s1a[r], s2a[r]);
        }
    }
    __syncthreads();                                           // #2
    if (t < MT) {
        float sa = 0.f, sb = 0.f;
        #pragma unroll
        for (int w = 0; w < 8; ++w) { sa += lnred_[w * MT + t].x; sb += lnred_[w * MT + t].y; }
        float mu = sa * (1.0f / 512.0f);
        float var = sb * (1.0f / 512.0f) - mu * mu;
        lnmu_[t] = mu;
        lnisd_[t] = rsqrtf(var + 1e-5f);
    }
    __syncthreads();                                           // #3

    // ---- LN + GELU in regs, convert g -> AH ----
    #pragma unroll
    for (int rb = 0; rb < RB; ++rb)
        #pragma unroll
        for (int cb = 0; cb < 4; ++cb) {
            const int j = wcol + cb * 16 + l16;
            const float gg = lng[j], bb = lnb[j];
            #pragma unroll
            for (int r = 0; r < 4; ++r) {
                const int m = rb * 16 + lK * 4 + r;
                float v = (acc[rb][cb][r] - lnmu_[m]) * lnisd_[m] * gg + bb;
                AH[m * D + (j ^ ((m & 7) << 3))] = (_Float16)gelu_fast(v);
            }
        }
    __syncthreads();                                           // #4

    // ---- GEMM2: kp = g @ W2.T + b2 ----
    #pragma unroll
    for (int rb = 0; rb < RB; ++rb)
        #pragma unroll
        for (int cb = 0; cb < 4; ++cb) acc[rb][cb] = fz;
    gemm(W2m, acc);

    #pragma unroll
    for (int rb = 0; rb < RB; ++rb) {
        float ss[4] = {0.f, 0.f, 0.f, 0.f};
        #pragma unroll
        for (int cb = 0; cb < 4; ++cb) {
            const float bb = b2[wcol + cb * 16 + l16];
            #pragma unroll
            for (int r = 0; r < 4; ++r) {
                float v = acc[rb][cb][r] + bb;
                acc[rb][cb][r] = v;
                ss[r] += v * v;
            }
        }
        #pragma unroll
        for (int mm = 1; mm < 16; mm <<= 1)
            #pragma unroll
            for (int r = 0; r < 4; ++r)
                ss[r] += __shfl_xor(ss[r], mm);
        if (l16 == 0) {
            #pragma unroll
            for (int r = 0; r < 4; ++r)
                k2p_[wave * MT + rb * 16 + lK * 4 + r] = ss[r];
        }
    }
    __syncthreads();                                           // #5
    // convert kp (fp16) -> AH
    #pragma unroll
    for (int rb = 0; rb < RB; ++rb)
        #pragma unroll
        for (int cb = 0; cb < 4; ++cb) {
            const int j = wcol + cb * 16 + l16;
            #pragma unroll
            for (int r = 0; r < 4; ++r) {
                const int m = rb * 16 + lK * 4 + r;
                AH[m * D + (j ^ ((m & 7) << 3))] = (_Float16)acc[rb][cb][r];
            }
        }
    __syncthreads();                                           // #6

    if (t < MT) {
        float sa = 0.f;
        #pragma unroll
        for (int w = 0; w < 8; ++w) sa += k2p_[w * MT + t];
        k2s_[t] = sa;
        kins_[t] = rsqrtf(fmaxf(sa, 1e-30f));
    }

    // ---- dots = kp @ qp.T via MFMA (10 units = 5 rb x 2 cbq over 8 waves) ----
    // (runs BEFORE scores so as[] isn't live here — spill-lean)
    {
        auto dot_unit = [&](int u) {
            const int rb = u % RB, cbq = u / RB;
            f4 ad = fz;
            const int ra = (rb * 16 + l16) * D;
            const int j = cbq * 16 + l16;
            #pragma unroll 2
            for (int ks = 0; ks < 16; ++ks) {
                const int k0 = ks * 32 + lK * 8;
                const int ksw = k0 ^ sw;
                h8 ah0 = *(const h8*)&AH[ra + ksw];
                h8 bh = *(const h8*)&qph[j * D + k0];
                ad = MF(ah0, bh, ad);
            }
            #pragma unroll
            for (int r = 0; r < 4; ++r)
                dotp_[(rb * 16 + lK * 4 + r) * 33 + cbq * 16 + l16] = ad[r];
        };
        dot_unit(wave);
        if (wave < 2) dot_unit(wave + 8);
    }

    // ---- scores: kp @ Wt.T via gll-staged Wt (4-buf rotation, 3-ahead) ----
    f4 as[RB][2];
    #pragma unroll
    for (int rb = 0; rb < RB; ++rb) { as[rb][0] = fz; as[rb][1] = fz; }
    {
        const _Float16* wsrcB[2];
        #pragma unroll
        for (int j = 0; j < 2; ++j) {
            const int rr   = j * 16 + (lane >> 2);
            const int slot = (lane & 3) ^ ((rr >> 1) & 3);
            wsrcB[j] = Wt + (size_t)(wave * 32 + rr) * D + slot * 8;
        }
        auto stageWT = [&](int c, int buf) {
            #pragma unroll
            for (int j = 0; j < 2; ++j)
                __builtin_amdgcn_global_load_lds((gas_void*)(wsrcB[j] + c * 32),
                    (las_void*)(WBUF + buf * 16384 + wave * 2048 + j * 1024), 16, 0, 0);
        };
        const unsigned wrd0 = (unsigned)(l16 * 64 + ((lK ^ ((l16 >> 1) & 3)) << 4));
        auto scoreChunk = [&](int c, int buf) {
            const unsigned char* wb = WBUF + buf * 16384 + wave * 2048;
            h8 w0 = *(const h8*)(wb + wrd0);
            h8 w1 = *(const h8*)(wb + 1024 + wrd0);
            const int ksw = (c * 32 + lK * 8) ^ sw;
            #pragma unroll
            for (int rb = 0; rb < RB; ++rb) {
                h8 a = *(const h8*)&AH[(rb * 16 + l16) * D + ksw];
                as[rb][0] = MF(a, w0, as[rb][0]);
                as[rb][1] = MF(a, w1, as[rb][1]);
            }
        };
        stageWT(0, 0); stageWT(1, 1); stageWT(2, 2);
        #pragma unroll 4
        for (int c = 0; c < 12; ++c) {
            asm volatile("s_waitcnt vmcnt(4)" ::: "memory");
            __builtin_amdgcn_sched_barrier(0);
            scoreChunk(c, c & 3);
            asm volatile("s_waitcnt lgkmcnt(0)" ::: "memory");
            __builtin_amdgcn_sched_barrier(0);
            stageWT(c + 3, (c + 3) & 3);
            __builtin_amdgcn_sched_barrier(0);
        }
        asm volatile("s_waitcnt vmcnt(4)" ::: "memory");
        __builtin_amdgcn_sched_barrier(0);
        scoreChunk(12, 0);
        asm volatile("s_waitcnt lgkmcnt(0)" ::: "memory");
        __builtin_amdgcn_sched_barrier(0);
        stageWT(15, 3);
        __builtin_amdgcn_sched_barrier(0);
        asm volatile("s_waitcnt vmcnt(4)" ::: "memory");
        __builtin_amdgcn_sched_barrier(0);
        scoreChunk(13, 1);
        asm volatile("s_waitcnt vmcnt(2)" ::: "memory");
        __builtin_amdgcn_sched_barrier(0);
        scoreChunk(14, 2);
        asm volatile("s_waitcnt vmcnt(0)" ::: "memory");
        __builtin_amdgcn_sched_barrier(0);
        scoreChunk(15, 3);
    }

    // ---- exp(scores) in place; fused softmax-denominator partial sums ----
    {
        #pragma unroll
        for (int cb = 0; cb < 2; ++cb)
            #pragma unroll
            for (int rb = 0; rb < RB; ++rb)
                #pragma unroll
                for (int r = 0; r < 4; ++r)
                    as[rb][cb][r] = __expf(as[rb][cb][r]);
        float part[2] = {0.f, 0.f};
        #pragma unroll
        for (int cb = 0; cb < 2; ++cb)
            #pragma unroll
            for (int rb = 0; rb < RB; ++rb)
                #pragma unroll
                for (int r = 0; r < 4; ++r) {
                    const int n = rb * 16 + lK * 4 + r;
                    if (n < nvalid) part[cb] += as[rb][cb][r];
                }
        #pragma unroll
        for (int cb = 0; cb < 2; ++cb) {
            part[cb] += __shfl_xor(part[cb], 16);
            part[cb] += __shfl_xor(part[cb], 32);
        }
        if (lK == 0) {
            atomicAdd(&sums[wave * 32 + l16], part[0]);
            atomicAdd(&sums[wave * 32 + 16 + l16], part[1]);
        }
    }
    __syncthreads();                                           // #7 (dotp/k2s ready; AH reads done)

    // ---- cos / euc outputs (nt stores) ----
    for (int p = t; p < BQ * MT; p += NT) {
        const int b = p / MT, m = p - b * MT;
        if (m < nvalid) {
            float dt = dotp_[m * 33 + b];
            __builtin_nontemporal_store(dt * qinv[b] * kins_[m] * expT,
                                        &cosw[(size_t)b * N + n0 + m]);
            float dd = q2[b] + k2s_[m] - 2.0f * dt;
            __builtin_nontemporal_store(1.0f / (1.0f + sqrtf(fmaxf(dd, 0.f))),
                                        &eucw[(size_t)b * N + n0 + m]);
        }
    }

    // ---- exp(scores) -> SC (overlay AH), then coalesced scw out ----
    _Float16* SC = AH;   // element layout: n*256 + (b ^ (n&31))*8 + h
    {
        const int bh0 = wave * 32 + l16;
        #pragma unroll
        for (int cb = 0; cb < 2; ++cb) {
            const int bhc = bh0 + cb * 16;
            const int b = bhc >> 3, h = bhc & 7;
            #pragma unroll
            for (int rb = 0; rb < RB; ++rb) {
                #pragma unroll
                for (int r = 0; r < 4; ++r) {
                    const int n = rb * 16 + lK * 4 + r;
                    SC[n * 256 + ((b ^ (n & 31)) * 8) + h] = (_Float16)as[rb][cb][r];
                }
            }
        }
    }
    __syncthreads();                                           // #8

    for (int p = t; p < BQ * MT; p += NT) {
        const int b = p / MT, n = p - b * MT;
        if (n < nvalid) {
            h8 v = *(const h8*)&SC[n * 256 + ((b ^ (n & 31)) * 8)];
            __builtin_nontemporal_store(v, (h8*)&scw[((size_t)b * N + n0 + n) * NH]);
        }
    }
}

// --------------------------------------------------------------------------
// Kernel 4: learned_sim + fused 3->64->1 MLP + sigmoid per (b,n).
// --------------------------------------------------------------------------
__global__ __launch_bounds__(256) void final_kernel(
    const float* __restrict__ cosw, const float* __restrict__ eucw,
    const _Float16* __restrict__ scw, int N,
    const float* __restrict__ sums,
    const float* __restrict__ fW1, const float* __restrict__ fb1,
    const float* __restrict__ fW2, const float* __restrict__ fb2,
    float* __restrict__ out, int total)
{
    __shared__ float w1s[192], b1s[64], w2s[64];
    __shared__ float sis[BQ * NH];
    __shared__ float b2s;
    const int t = threadIdx.x;
    if (t < 192) w1s[t] = fW1[t];
    else { b1s[t - 192] = fb1[t - 192]; w2s[t - 192] = fW2[t - 192]; }
    sis[t] = 0.125f / sums[t];
    if (t == 0) b2s = fb2[0];
    __syncthreads();

    const int idx = blockIdx.x * 256 + t;
    if (idx >= total) return;
    const int b = idx / N;

    float c = cosw[idx], e = eucw[idx];
    h8 v = *(const h8*)&scw[(size_t)idx * NH];
    float ls = 0.f;
    #pragma unroll
    for (int h = 0; h < NH; ++h)
        ls += (float)v[h] * sis[b * NH + h];

    float logit = b2s;
    #pragma unroll
    for (int j = 0; j < 64; ++j) {
        float hj = fmaf(w1s[j*3], c, fmaf(w1s[j*3+1], e, fmaf(w1s[j*3+2], ls, b1s[j])));
        logit = fmaf(w2s[j], fmaxf(hj, 0.f), logit);
    }
    out[idx] = 1.0f / (1.0f + expf(-logit));
}

// --------------------------------------------------------------------------
extern "C" void kernel_launch(void* const* d_in, const int* in_sizes, int n_in,
                              void* d_out, int out_size, void* d_ws, size_t ws_size,
                              hipStream_t stream)
{
    const float* xq   = (const float*)d_in[0];
    const float* xc   = (const float*)d_in[1];
    const float* temp = (const float*)d_in[2];
    const float* qW1  = (const float*)d_in[3];
    const float* qb1  = (const float*)d_in[4];
    const float* qlg  = (const float*)d_in[5];
    const float* qlb  = (const float*)d_in[6];
    const float* qW2  = (const float*)d_in[7];
    const float* qb2  = (const float*)d_in[8];
    const float* kW1  = (const float*)d_in[9];
    const float* kb1  = (const float*)d_in[10];
    const float* klg  = (const float*)d_in[11];
    const float* klb  = (const float*)d_in[12];
    const float* kW2  = (const float*)d_in[13];
    const float* kb2  = (const float*)d_in[14];
    const float* Wio  = (const float*)d_in[15];
    const float* bio  = (const float*)d_in[16];
    const float* fW1  = (const float*)d_in[17];
    const float* fb1  = (const float*)d_in[18];
    const float* fW2  = (const float*)d_in[19];
    const float* fb2  = (const float*)d_in[20];

    const int N = in_sizes[1] / D;

    float* ws   = (float*)d_ws;
    float* qp   = ws;                         // 16384
    float* qv   = qp + BQ * D;                // 16384 (unused slot kept)
    float* q2   = qv + BQ * D;                // 32
    float* qinv = q2 + BQ;                    // 32
    float* sinv = qinv + BQ;                  // 256 (unused slot kept)
    float* sums = sinv + BQ * NH;             // 256
    float* cosw = sums + BQ * NH;             // BQ*N
    float* eucw = cosw + (size_t)BQ * N;      // BQ*N
    float* fend = eucw + (size_t)BQ * N;

    _Float16* hb  = (_Float16*)fend;
    _Float16* W1m = hb;                       // 262144 each
    _Float16* W2m = W1m + D * D;
    _Float16* qph = W2m + D * D;              // 16384
    _Float16* Wt  = qph + BQ * D;             // 256*512
    _Float16* scw = Wt + BQ * NH * D;         // BQ*N*NH  ([b][n][h])

    wprep_kernel<<<(D * D + 255) / 256, 256, 0, stream>>>(kW1, kW2, W1m, W2m, sums);

    qproj_kernel<<<BQ, 512, 0, stream>>>(xq, qW1, qb1, qlg, qlb, qW2, qb2,
                                         qp, q2, qinv, qph);

    wtld_kernel<<<BQ * NH, 256, 0, stream>>>(qp, Wio, bio, Wt);

    const int nblk = (N + MT - 1) / MT;
    cand_kernel<<<nblk, NT, 0, stream>>>(xc, N, W1m, W2m,
                                         kb1, klg, klb, kb2,
                                         qph, Wt, q2, qinv, temp,
                                         cosw, eucw, scw, sums);

    const int total = BQ * N;
    final_kernel<<<(total + 255) / 256, 256, 0, stream>>>(cosw, eucw, scw, N, sums,
                                                          fW1, fb1, fW2, fb2,
                                                          (float*)d_out, total);
}

// Round 22
// 285.198 us; speedup vs baseline: 2.8625x; 1.0337x over previous
//
#include <hip/hip_runtime.h>
#include <math.h>

#define D    512
#define BQ   32
#define NH   8
#define MT   80
#define RB   5     // row fragments of 16
#define NT   512   // threads per cand block (8 waves)

typedef _Float16 h2  __attribute__((ext_vector_type(2)));
typedef _Float16 h4v __attribute__((ext_vector_type(4)));
typedef _Float16 h8  __attribute__((ext_vector_type(8)));
typedef float    f4  __attribute__((ext_vector_type(4)));

typedef const __attribute__((address_space(1))) void gas_void;
typedef __attribute__((address_space(3))) void las_void;

__device__ __forceinline__ f4 MF(h8 a, h8 b, f4 c) {
  return __builtin_amdgcn_mfma_f32_16x16x32_f16(a, b, c, 0, 0, 0);
}

__device__ __forceinline__ float erf_fast(float x) {
    float ax = fabsf(x);
    float tt = 1.0f / fmaf(0.3275911f, ax, 1.0f);
    float poly = tt * fmaf(tt, fmaf(tt, fmaf(tt, fmaf(tt, 1.061405429f, -1.453152027f),
                          1.421413741f), -0.284496736f), 0.254829592f);
    float r = 1.0f - poly * __expf(-ax * ax);
    return copysignf(r, x);
}
__device__ __forceinline__ float gelu_fast(float x) {
    return 0.5f * x * (1.0f + erf_fast(x * 0.7071067811865475f));
}
__device__ __forceinline__ float gelu_exact(float x) {
    return 0.5f * x * (1.0f + erff(x * 0.7071067811865475f));
}

// --------------------------------------------------------------------------
// Kernel 1 (merged): blocks 0..511 = weight fp16 prep; blocks 512..543 =
// query proj block (h->LN->GELU->qp), one row each, 512 threads.
// --------------------------------------------------------------------------
__global__ __launch_bounds__(512) void prep_kernel(
    const float* __restrict__ kW1, const float* __restrict__ kW2,
    _Float16* __restrict__ W1m, _Float16* __restrict__ W2m,
    float* __restrict__ sums,
    const float* __restrict__ xq,
    const float* __restrict__ W1, const float* __restrict__ b1,
    const float* __restrict__ lng, const float* __restrict__ lnb,
    const float* __restrict__ W2, const float* __restrict__ b2,
    float* __restrict__ qp,
    float* __restrict__ q2o, float* __restrict__ qinvo,
    _Float16* __restrict__ qph)
{
    const int bid = blockIdx.x;
    const int t = threadIdx.x;

    if (bid < 512) {                       // ---- weight prep part ----
        if (bid == 0 && t < 256) sums[t] = 0.0f;
        const int idx = bid * 512 + t;     // 512*512 = D*D exactly
        W1m[idx] = (_Float16)kW1[idx];
        W2m[idx] = (_Float16)kW2[idx];
        return;
    }

    // ---- query proj part (row = bid - 512) ----
    __shared__ float xs[D];
    __shared__ float hs[D];
    __shared__ float red[20];
    const int row = bid - 512;
    const int wave = t >> 6, lane = t & 63;

    xs[t] = xq[row * D + t];
    __syncthreads();

    float a0 = 0.f;
    for (int i = 0; i < D; i += 4) {
        float4 xv = *(const float4*)&xs[i];
        float4 w0 = *(const float4*)&W1[(size_t)t * D + i];
        a0 += xv.x*w0.x + xv.y*w0.y + xv.z*w0.z + xv.w*w0.w;
    }
    float h0 = a0 + b1[t];

    float s1 = h0, s2 = h0 * h0;
    for (int off = 32; off > 0; off >>= 1) { s1 += __shfl_down(s1, off); s2 += __shfl_down(s2, off); }
    if (lane == 0) { red[wave] = s1; red[8 + wave] = s2; }
    __syncthreads();
    if (t == 0) {
        float sa = 0.f, sb = 0.f;
        #pragma unroll
        for (int w = 0; w < 8; ++w) { sa += red[w]; sb += red[8 + w]; }
        float mu = sa / (float)D;
        red[16] = mu;
        red[17] = rsqrtf(sb / (float)D - mu * mu + 1e-5f);
    }
    __syncthreads();
    float mu = red[16], isd = red[17];
    hs[t] = gelu_exact((h0 - mu) * isd * lng[t] + lnb[t]);
    __syncthreads();

    a0 = 0.f;
    for (int i = 0; i < D; i += 4) {
        float4 gv = *(const float4*)&hs[i];
        float4 w0 = *(const float4*)&W2[(size_t)t * D + i];
        a0 += gv.x*w0.x + gv.y*w0.y + gv.z*w0.z + gv.w*w0.w;
    }
    float p0 = a0 + b2[t];
    qp[row * D + t]  = p0;
    qph[row * D + t] = (_Float16)p0;

    s1 = p0 * p0;
    for (int off = 32; off > 0; off >>= 1) s1 += __shfl_down(s1, off);
    if (lane == 0) red[wave] = s1;
    __syncthreads();
    if (t == 0) {
        float sa = 0.f;
        #pragma unroll
        for (int w = 0; w < 8; ++w) sa += red[w];
        q2o[row] = sa;
        qinvo[row] = 1.0f / sqrtf(sa);
    }
}

// --------------------------------------------------------------------------
// W-tilde prep: q[b,h,d] = qp[b]·Wq[h*64+d] + bq, then
// Wt[b,h,:] = (1/8) * sum_d q[b,h,d] * Wk[h*64+d, :].
// --------------------------------------------------------------------------
__global__ __launch_bounds__(256) void wtld_kernel(
    const float* __restrict__ qp, const float* __restrict__ Wio,
    const float* __restrict__ bio,
    _Float16* __restrict__ Wt)
{
    __shared__ float qpb[D];
    __shared__ float qs[64];
    const int bh = blockIdx.x, b = bh >> 3, h = bh & 7;
    const int t = threadIdx.x;

    qpb[t]       = qp[b * D + t];
    qpb[t + 256] = qp[b * D + t + 256];
    __syncthreads();

    {
        const int d = t >> 2, part = t & 3;
        const float* Wq = Wio + (size_t)(h * 64 + d) * D + part * 128;
        const float* xp = qpb + part * 128;
        float a = 0.f;
        #pragma unroll 8
        for (int i = 0; i < 128; i += 4) {
            float4 xv = *(const float4*)&xp[i];
            float4 wv = *(const float4*)&Wq[i];
            a += xv.x*wv.x + xv.y*wv.y + xv.z*wv.z + xv.w*wv.w;
        }
        a += __shfl_xor(a, 1);
        a += __shfl_xor(a, 2);
        if (part == 0) qs[d] = (a + bio[h * 64 + d]) * 0.125f;
    }
    __syncthreads();

    const float* Wk = Wio + (size_t)D * D + (size_t)(h * 64) * D;
    float a0 = 0.f, a1 = 0.f;
    #pragma unroll 4
    for (int d = 0; d < 64; ++d) {
        float q = qs[d];
        a0 += q * Wk[(size_t)d * D + t];
        a1 += q * Wk[(size_t)d * D + t + 256];
    }
    Wt[(size_t)bh * D + t]       = (_Float16)a0;
    Wt[(size_t)bh * D + t + 256] = (_Float16)a1;
}

// --------------------------------------------------------------------------
// Kernel 2: candidate path. 80 rows/block, 512 threads (8 waves).
// cos/euc outputs now fp16 (halved side-channel traffic).
// --------------------------------------------------------------------------
__global__ __launch_bounds__(NT) void cand_kernel(
    const float* __restrict__ xc, int N,
    const _Float16* __restrict__ W1m, const _Float16* __restrict__ W2m,
    const float* __restrict__ b1, const float* __restrict__ lng,
    const float* __restrict__ lnb, const float* __restrict__ b2,
    const _Float16* __restrict__ qph,
    const _Float16* __restrict__ Wt,
    const float* __restrict__ q2, const float* __restrict__ qinv,
    const float* __restrict__ tempp,
    _Float16* __restrict__ coswh, _Float16* __restrict__ eucwh,
    _Float16* __restrict__ scw, float* __restrict__ sums)
{
    __shared__ _Float16 AH[MT * D];                      // 80 KB (swizzled); reused as SC
    __shared__ __align__(16) unsigned char WBUF[65536];  // 2 x 32 KB weight staging
    __shared__ __align__(16) float scr[MT * 33];         // dotp aliases lnred (10.5 KB)
    __shared__ float k2p_[8 * MT];
    __shared__ float k2s_[MT], kins_[MT];
    __shared__ float lnmu_[MT], lnisd_[MT];

    float*  dotp_  = scr;
    float2* lnred_ = (float2*)scr;

    const int t    = threadIdx.x;
    const int wave = t >> 6;
    const int lane = t & 63;
    const int l16  = lane & 15;
    const int lK   = lane >> 4;
    const int wcol = wave * 64;
    const int n0   = blockIdx.x * MT;
    const int nvalid = min(MT, N - n0);
    const float expT = expf(tempp[0]);
    const f4 fz = {0.f, 0.f, 0.f, 0.f};

    // ---- stage X (nt loads; fp16, swizzled) ----
    #pragma unroll
    for (int i = 0; i < 20; ++i) {
        int g = t + NT * i;
        int row = g >> 7;
        int c4 = (g & 127) * 4;
        f4 v = fz;
        if (n0 + row < N)
            v = __builtin_nontemporal_load((const f4*)(xc + (size_t)(n0 + row) * D + c4));
        h4v hi;
        #pragma unroll
        for (int e = 0; e < 4; ++e) hi[e] = (_Float16)v[e];
        *(h4v*)&AH[row * D + (c4 ^ ((row & 7) << 3))] = hi;
    }
    __syncthreads();                                           // #1

    const int sw = (l16 & 7) << 3;

    unsigned rdO[4];
    #pragma unroll
    for (int cb = 0; cb < 4; ++cb) {
        const int col = wcol + cb * 16 + l16;
        rdO[cb] = (unsigned)(col * 64 + ((lK ^ ((col >> 1) & 3)) << 4));
    }
    unsigned dstO[4];
    #pragma unroll
    for (int j = 0; j < 4; ++j) dstO[j] = (unsigned)(wave * 4096 + j * 1024);

    auto gemm = [&](const _Float16* __restrict__ Wm, f4 (&acc)[RB][4]) {
        const _Float16* srcB[4];
        #pragma unroll
        for (int j = 0; j < 4; ++j) {
            const int col  = (wave * 4 + j) * 16 + (lane >> 2);
            const int slot = (lane & 3) ^ ((col >> 1) & 3);
            srcB[j] = Wm + (size_t)col * D + slot * 8;
        }
        auto stage = [&](int c, int buf) {
            #pragma unroll
            for (int j = 0; j < 4; ++j)
                __builtin_amdgcn_global_load_lds((gas_void*)(srcB[j] + c * 32),
                    (las_void*)(WBUF + buf * 32768 + dstO[j]), 16, 0, 0);
        };
        auto compute = [&](int c, int buf) {
            const unsigned char* wb = WBUF + buf * 32768;
            h8 bh[4];
            #pragma unroll
            for (int cb = 0; cb < 4; ++cb) bh[cb] = *(const h8*)(wb + rdO[cb]);
            const int ksw = (c * 32 + lK * 8) ^ sw;
            #pragma unroll
            for (int rb = 0; rb < RB; ++rb) {
                h8 ah = *(const h8*)&AH[(rb * 16 + l16) * D + ksw];
                #pragma unroll
                for (int cb = 0; cb < 4; ++cb)
                    acc[rb][cb] = MF(ah, bh[cb], acc[rb][cb]);
            }
        };
        stage(0, 0); stage(1, 1);
        #pragma unroll 1
        for (int c = 0; c < 14; ++c) {
            const int buf = c & 1;
            asm volatile("s_waitcnt vmcnt(4)" ::: "memory");
            __builtin_amdgcn_sched_barrier(0);
            compute(c, buf);
            asm volatile("s_waitcnt lgkmcnt(0)" ::: "memory");
            __builtin_amdgcn_sched_barrier(0);
            stage(c + 2, buf);
            __builtin_amdgcn_sched_barrier(0);
        }
        asm volatile("s_waitcnt vmcnt(4)" ::: "memory");
        __builtin_amdgcn_sched_barrier(0);
        compute(14, 0);
        asm volatile("s_waitcnt vmcnt(0)" ::: "memory");
        __builtin_amdgcn_sched_barrier(0);
        compute(15, 1);
    };

    f4 acc[RB][4];
    #pragma unroll
    for (int rb = 0; rb < RB; ++rb)
        #pragma unroll
        for (int cb = 0; cb < 4; ++cb) acc[rb][cb] = fz;

    // ---- GEMM1: h = x @ W1.T + b1 ----
    gemm(W1m, acc);

    #pragma unroll
    for (int rb = 0; rb < RB; ++rb) {
        float s1a[4] = {0.f, 0.f, 0.f, 0.f};
        float s2a[4] = {0.f, 0.f, 0.f, 0.f};
        #pragma unroll
        for (int cb = 0; cb < 4; ++cb) {
            const float bb = b1[wcol + cb * 16 + l16];
            #pragma unroll
            for (int r = 0; r < 4; ++r) {
                float v = acc[rb][cb][r] + bb;
                acc[rb][cb][r] = v;
                s1a[r] += v;
                s2a[r] += v * v;
            }
        }
        #pragma unroll
        for (int mm = 1; mm < 16; mm <<= 1)
            #pragma unroll
            for (int r = 0; r < 4; ++r) {
                s1a[r] += __shfl_xor(s1a[r], mm);
                s2a[r] += __shfl_xor(s2a[r], mm);
            }
        if (l16 == 0) {
            #pragma unroll
            for (int r = 0; r < 4; ++r)
                lnred_[wave * MT + rb * 16 + lK * 4 + r] = make_float2(s1a[r], s2a[r]);
        }
    }
    __syncthreads();                                           // #2
    if (t < MT) {
        float sa = 0.f, sb = 0.f;
        #pragma unroll
        for (int w = 0; w < 8; ++w) { sa += lnred_[w * MT + t].x; sb += lnred_[w * MT + t].y; }
        float mu = sa * (1.0f / 512.0f);
        float var = sb * (1.0f / 512.0f) - mu * mu;
        lnmu_[t] = mu;
        lnisd_[t] = rsqrtf(var + 1e-5f);
    }
    __syncthreads();                                           // #3

    // ---- LN + GELU in regs, convert g -> AH ----
    #pragma unroll
    for (int rb = 0; rb < RB; ++rb)
        #pragma unroll
        for (int cb = 0; cb < 4; ++cb) {
            const int j = wcol + cb * 16 + l16;
            const float gg = lng[j], bb = lnb[j];
            #pragma unroll
            for (int r = 0; r < 4; ++r) {
                const int m = rb * 16 + lK * 4 + r;
                float v = (acc[rb][cb][r] - lnmu_[m]) * lnisd_[m] * gg + bb;
                AH[m * D + (j ^ ((m & 7) << 3))] = (_Float16)gelu_fast(v);
            }
        }
    __syncthreads();                                           // #4

    // ---- GEMM2: kp = g @ W2.T + b2 ----
    #pragma unroll
    for (int rb = 0; rb < RB; ++rb)
        #pragma unroll
        for (int cb = 0; cb < 4; ++cb) acc[rb][cb] = fz;
    gemm(W2m, acc);

    #pragma unroll
    for (int rb = 0; rb < RB; ++rb) {
        float ss[4] = {0.f, 0.f, 0.f, 0.f};
        #pragma unroll
        for (int cb = 0; cb < 4; ++cb) {
            const float bb = b2[wcol + cb * 16 + l16];
            #pragma unroll
            for (int r = 0; r < 4; ++r) {
                float v = acc[rb][cb][r] + bb;
                acc[rb][cb][r] = v;
                ss[r] += v * v;
            }
        }
        #pragma unroll
        for (int mm = 1; mm < 16; mm <<= 1)
            #pragma unroll
            for (int r = 0; r < 4; ++r)
                ss[r] += __shfl_xor(ss[r], mm);
        if (l16 == 0) {
            #pragma unroll
            for (int r = 0; r < 4; ++r)
                k2p_[wave * MT + rb * 16 + lK * 4 + r] = ss[r];
        }
    }
    __syncthreads();                                           // #5
    // convert kp (fp16) -> AH
    #pragma unroll
    for (int rb = 0; rb < RB; ++rb)
        #pragma unroll
        for (int cb = 0; cb < 4; ++cb) {
            const int j = wcol + cb * 16 + l16;
            #pragma unroll
            for (int r = 0; r < 4; ++r) {
                const int m = rb * 16 + lK * 4 + r;
                AH[m * D + (j ^ ((m & 7) << 3))] = (_Float16)acc[rb][cb][r];
            }
        }
    __syncthreads();                                           // #6

    if (t < MT) {
        float sa = 0.f;
        #pragma unroll
        for (int w = 0; w < 8; ++w) sa += k2p_[w * MT + t];
        k2s_[t] = sa;
        kins_[t] = rsqrtf(fmaxf(sa, 1e-30f));
    }

    // ---- dots = kp @ qp.T via MFMA (10 units = 5 rb x 2 cbq over 8 waves) ----
    {
        auto dot_unit = [&](int u) {
            const int rb = u % RB, cbq = u / RB;
            f4 ad = fz;
            const int ra = (rb * 16 + l16) * D;
            const int j = cbq * 16 + l16;
            #pragma unroll 2
            for (int ks = 0; ks < 16; ++ks) {
                const int k0 = ks * 32 + lK * 8;
                const int ksw = k0 ^ sw;
                h8 ah0 = *(const h8*)&AH[ra + ksw];
                h8 bh = *(const h8*)&qph[j * D + k0];
                ad = MF(ah0, bh, ad);
            }
            #pragma unroll
            for (int r = 0; r < 4; ++r)
                dotp_[(rb * 16 + lK * 4 + r) * 33 + cbq * 16 + l16] = ad[r];
        };
        dot_unit(wave);
        if (wave < 2) dot_unit(wave + 8);
    }

    // ---- scores: kp @ Wt.T via gll-staged Wt (4-buf rotation, 3-ahead) ----
    f4 as[RB][2];
    #pragma unroll
    for (int rb = 0; rb < RB; ++rb) { as[rb][0] = fz; as[rb][1] = fz; }
    {
        const _Float16* wsrcB[2];
        #pragma unroll
        for (int j = 0; j < 2; ++j) {
            const int rr   = j * 16 + (lane >> 2);
            const int slot = (lane & 3) ^ ((rr >> 1) & 3);
            wsrcB[j] = Wt + (size_t)(wave * 32 + rr) * D + slot * 8;
        }
        auto stageWT = [&](int c, int buf) {
            #pragma unroll
            for (int j = 0; j < 2; ++j)
                __builtin_amdgcn_global_load_lds((gas_void*)(wsrcB[j] + c * 32),
                    (las_void*)(WBUF + buf * 16384 + wave * 2048 + j * 1024), 16, 0, 0);
        };
        const unsigned wrd0 = (unsigned)(l16 * 64 + ((lK ^ ((l16 >> 1) & 3)) << 4));
        auto scoreChunk = [&](int c, int buf) {
            const unsigned char* wb = WBUF + buf * 16384 + wave * 2048;
            h8 w0 = *(const h8*)(wb + wrd0);
            h8 w1 = *(const h8*)(wb + 1024 + wrd0);
            const int ksw = (c * 32 + lK * 8) ^ sw;
            #pragma unroll
            for (int rb = 0; rb < RB; ++rb) {
                h8 a = *(const h8*)&AH[(rb * 16 + l16) * D + ksw];
                as[rb][0] = MF(a, w0, as[rb][0]);
                as[rb][1] = MF(a, w1, as[rb][1]);
            }
        };
        stageWT(0, 0); stageWT(1, 1); stageWT(2, 2);
        #pragma unroll 4
        for (int c = 0; c < 12; ++c) {
            asm volatile("s_waitcnt vmcnt(4)" ::: "memory");
            __builtin_amdgcn_sched_barrier(0);
            scoreChunk(c, c & 3);
            asm volatile("s_waitcnt lgkmcnt(0)" ::: "memory");
            __builtin_amdgcn_sched_barrier(0);
            stageWT(c + 3, (c + 3) & 3);
            __builtin_amdgcn_sched_barrier(0);
        }
        asm volatile("s_waitcnt vmcnt(4)" ::: "memory");
        __builtin_amdgcn_sched_barrier(0);
        scoreChunk(12, 0);
        asm volatile("s_waitcnt lgkmcnt(0)" ::: "memory");
        __builtin_amdgcn_sched_barrier(0);
        stageWT(15, 3);
        __builtin_amdgcn_sched_barrier(0);
        asm volatile("s_waitcnt vmcnt(4)" ::: "memory");
        __builtin_amdgcn_sched_barrier(0);
        scoreChunk(13, 1);
        asm volatile("s_waitcnt vmcnt(2)" ::: "memory");
        __builtin_amdgcn_sched_barrier(0);
        scoreChunk(14, 2);
        asm volatile("s_waitcnt vmcnt(0)" ::: "memory");
        __builtin_amdgcn_sched_barrier(0);
        scoreChunk(15, 3);
    }

    // ---- exp(scores) in place; fused softmax-denominator partial sums ----
    {
        #pragma unroll
        for (int cb = 0; cb < 2; ++cb)
            #pragma unroll
            for (int rb = 0; rb < RB; ++rb)
                #pragma unroll
                for (int r = 0; r < 4; ++r)
                    as[rb][cb][r] = __expf(as[rb][cb][r]);
        float part[2] = {0.f, 0.f};
        #pragma unroll
        for (int cb = 0; cb < 2; ++cb)
            #pragma unroll
            for (int rb = 0; rb < RB; ++rb)
                #pragma unroll
                for (int r = 0; r < 4; ++r) {
                    const int n = rb * 16 + lK * 4 + r;
                    if (n < nvalid) part[cb] += as[rb][cb][r];
                }
        #pragma unroll
        for (int cb = 0; cb < 2; ++cb) {
            part[cb] += __shfl_xor(part[cb], 16);
            part[cb] += __shfl_xor(part[cb], 32);
        }
        if (lK == 0) {
            atomicAdd(&sums[wave * 32 + l16], part[0]);
            atomicAdd(&sums[wave * 32 + 16 + l16], part[1]);
        }
    }
    __syncthreads();                                           // #7 (dotp/k2s ready; AH reads done)

    // ---- cos / euc outputs (fp16 nt stores) ----
    for (int p = t; p < BQ * MT; p += NT) {
        const int b = p / MT, m = p - b * MT;
        if (m < nvalid) {
            float dt = dotp_[m * 33 + b];
            __builtin_nontemporal_store((_Float16)(dt * qinv[b] * kins_[m] * expT),
                                        &coswh[(size_t)b * N + n0 + m]);
            float dd = q2[b] + k2s_[m] - 2.0f * dt;
            __builtin_nontemporal_store((_Float16)(1.0f / (1.0f + sqrtf(fmaxf(dd, 0.f)))),
                                        &eucwh[(size_t)b * N + n0 + m]);
        }
    }

    // ---- exp(scores) -> SC (overlay AH), then coalesced scw out ----
    _Float16* SC = AH;   // element layout: n*256 + (b ^ (n&31))*8 + h
    {
        const int bh0 = wave * 32 + l16;
        #pragma unroll
        for (int cb = 0; cb < 2; ++cb) {
            const int bhc = bh0 + cb * 16;
            const int b = bhc >> 3, h = bhc & 7;
            #pragma unroll
            for (int rb = 0; rb < RB; ++rb) {
                #pragma unroll
                for (int r = 0; r < 4; ++r) {
                    const int n = rb * 16 + lK * 4 + r;
                    SC[n * 256 + ((b ^ (n & 31)) * 8) + h] = (_Float16)as[rb][cb][r];
                }
            }
        }
    }
    __syncthreads();                                           // #8

    for (int p = t; p < BQ * MT; p += NT) {
        const int b = p / MT, n = p - b * MT;
        if (n < nvalid) {
            h8 v = *(const h8*)&SC[n * 256 + ((b ^ (n & 31)) * 8)];
            __builtin_nontemporal_store(v, (h8*)&scw[((size_t)b * N + n0 + n) * NH]);
        }
    }
}

// --------------------------------------------------------------------------
// Kernel 4: learned_sim + fused 3->64->1 MLP + sigmoid per (b,n).
// --------------------------------------------------------------------------
__global__ __launch_bounds__(256) void final_kernel(
    const _Float16* __restrict__ coswh, const _Float16* __restrict__ eucwh,
    const _Float16* __restrict__ scw, int N,
    const float* __restrict__ sums,
    const float* __restrict__ fW1, const float* __restrict__ fb1,
    const float* __restrict__ fW2, const float* __restrict__ fb2,
    float* __restrict__ out, int total)
{
    __shared__ float w1s[192], b1s[64], w2s[64];
    __shared__ float sis[BQ * NH];
    __shared__ float b2s;
    const int t = threadIdx.x;
    if (t < 192) w1s[t] = fW1[t];
    else { b1s[t - 192] = fb1[t - 192]; w2s[t - 192] = fW2[t - 192]; }
    sis[t] = 0.125f / sums[t];
    if (t == 0) b2s = fb2[0];
    __syncthreads();

    const int idx = blockIdx.x * 256 + t;
    if (idx >= total) return;
    const int b = idx / N;

    float c = (float)coswh[idx], e = (float)eucwh[idx];
    h8 v = *(const h8*)&scw[(size_t)idx * NH];
    float ls = 0.f;
    #pragma unroll
    for (int h = 0; h < NH; ++h)
        ls += (float)v[h] * sis[b * NH + h];

    float logit = b2s;
    #pragma unroll
    for (int j = 0; j < 64; ++j) {
        float hj = fmaf(w1s[j*3], c, fmaf(w1s[j*3+1], e, fmaf(w1s[j*3+2], ls, b1s[j])));
        logit = fmaf(w2s[j], fmaxf(hj, 0.f), logit);
    }
    out[idx] = 1.0f / (1.0f + expf(-logit));
}

// --------------------------------------------------------------------------
extern "C" void kernel_launch(void* const* d_in, const int* in_sizes, int n_in,
                              void* d_out, int out_size, void* d_ws, size_t ws_size,
                              hipStream_t stream)
{
    const float* xq   = (const float*)d_in[0];
    const float* xc   = (const float*)d_in[1];
    const float* temp = (const float*)d_in[2];
    const float* qW1  = (const float*)d_in[3];
    const float* qb1  = (const float*)d_in[4];
    const float* qlg  = (const float*)d_in[5];
    const float* qlb  = (const float*)d_in[6];
    const float* qW2  = (const float*)d_in[7];
    const float* qb2  = (const float*)d_in[8];
    const float* kW1  = (const float*)d_in[9];
    const float* kb1  = (const float*)d_in[10];
    const float* klg  = (const float*)d_in[11];
    const float* klb  = (const float*)d_in[12];
    const float* kW2  = (const float*)d_in[13];
    const float* kb2  = (const float*)d_in[14];
    const float* Wio  = (const float*)d_in[15];
    const float* bio  = (const float*)d_in[16];
    const float* fW1  = (const float*)d_in[17];
    const float* fb1  = (const float*)d_in[18];
    const float* fW2  = (const float*)d_in[19];
    const float* fb2  = (const float*)d_in[20];

    const int N = in_sizes[1] / D;

    float* ws   = (float*)d_ws;
    float* qp   = ws;                         // 16384
    float* q2   = qp + BQ * D;                // 32
    float* qinv = q2 + BQ;                    // 32
    float* sums = qinv + BQ;                  // 256
    float* fend = sums + BQ * NH;

    _Float16* hb  = (_Float16*)fend;
    _Float16* W1m = hb;                       // 262144 each
    _Float16* W2m = W1m + D * D;
    _Float16* qph = W2m + D * D;              // 16384
    _Float16* Wt  = qph + BQ * D;             // 256*512
    _Float16* scw = Wt + BQ * NH * D;         // BQ*N*NH  ([b][n][h])
    _Float16* coswh = scw + (size_t)BQ * N * NH;  // BQ*N
    _Float16* eucwh = coswh + (size_t)BQ * N;     // BQ*N

    prep_kernel<<<544, 512, 0, stream>>>(kW1, kW2, W1m, W2m, sums,
                                         xq, qW1, qb1, qlg, qlb, qW2, qb2,
                                         qp, q2, qinv, qph);

    wtld_kernel<<<BQ * NH, 256, 0, stream>>>(qp, Wio, bio, Wt);

    const int nblk = (N + MT - 1) / MT;
    cand_kernel<<<nblk, NT, 0, stream>>>(xc, N, W1m, W2m,
                                         kb1, klg, klb, kb2,
                                         qph, Wt, q2, qinv, temp,
                                         coswh, eucwh, scw, sums);

    const int total = BQ * N;
    final_kernel<<<(total + 255) / 256, 256, 0, stream>>>(coswh, eucwh, scw, N, sums,
                                                          fW1, fb1, fW2, fb2,
                                                          (float*)d_out, total);
}